// Round 7
// baseline (327.363 us; speedup 1.0000x reference)
//
#include <hip/hip_runtime.h>
#include <math.h>

#define BATCH 4
#define SEQ 2048
#define FEAT 512
#define NHEADS 8
#define HD 64
#define NROWS (BATCH*SEQ)   // 8192

typedef __attribute__((ext_vector_type(4)))  float f32x4;
typedef __attribute__((ext_vector_type(16))) float f32x16;
typedef __attribute__((ext_vector_type(8)))  short s16x8;
typedef __attribute__((ext_vector_type(8)))  unsigned short u16x8;
typedef __attribute__((ext_vector_type(4)))  unsigned int u32x4;

static __device__ __forceinline__ unsigned short f2bf(float x) {
  unsigned int u = __builtin_bit_cast(unsigned int, x);
  unsigned int r = (u + 0x7FFFu + ((u >> 16) & 1u)) >> 16;
  return (unsigned short)r;
}
static __device__ __forceinline__ float bf2f(unsigned short h) {
  unsigned int u = ((unsigned int)h) << 16;
  return __builtin_bit_cast(float, u);
}
static __device__ __forceinline__ void split2(float x, unsigned short& h, unsigned short& l) {
  h = f2bf(x);
  l = f2bf(x - bf2f(h));
}

// ---------------------------------------------------------------------------
// Fused QKV projection. z=0: Q (scale 1/8) -> (B,H,T,Hd) hi/lo
//                       z=1: K            -> (B,H,T,Hd) hi/lo
//                       z=2: V            -> (B,H,Hd,T) hi/lo (LDS transpose)
// ---------------------------------------------------------------------------
__global__ __launch_bounds__(256) void qkv_proj(
    const float* __restrict__ xc, const float* __restrict__ xp,
    const float* __restrict__ wq, const float* __restrict__ bq,
    const float* __restrict__ wk, const float* __restrict__ bk,
    const float* __restrict__ wv, const float* __restrict__ bv,
    unsigned short* __restrict__ Qhi, unsigned short* __restrict__ Qlo,
    unsigned short* __restrict__ Khi, unsigned short* __restrict__ Klo,
    unsigned short* __restrict__ Vthi, unsigned short* __restrict__ Vtlo)
{
  __shared__ unsigned short Xhi[128 * 64], Xlo[128 * 64];
  __shared__ unsigned short Whi[64 * 64],  Wlo[64 * 64];

  const int z = blockIdx.z;
  const float* X  = (z == 0) ? xc : xp;
  const float* W  = (z == 0) ? wq : (z == 1) ? wk : wv;
  const float* Bp = (z == 0) ? bq : (z == 1) ? bk : bv;
  unsigned short* Ohi = (z == 0) ? Qhi : (z == 1) ? Khi : Vthi;
  unsigned short* Olo = (z == 0) ? Qlo : (z == 1) ? Klo : Vtlo;
  const float scale = (z == 0) ? 0.125f : 1.0f;

  const int tid  = threadIdx.x;
  const int lane = tid & 63;
  const int wave = tid >> 6;
  const int g = lane >> 4, j = lane & 15;
  const int wm = (wave >> 1) * 64;
  const int wn = (wave & 1) * 32;
  const int row0 = blockIdx.x * 128;
  const int col0 = blockIdx.y * 64;

  f32x4 acc[4][2];
#pragma unroll
  for (int mi = 0; mi < 4; ++mi)
#pragma unroll
    for (int ni = 0; ni < 2; ++ni) acc[mi][ni] = (f32x4)0.f;

  const int srow = tid >> 4;        // 0..15
  const int sk   = (tid & 15) * 4;  // 0..60

  for (int kt = 0; kt < FEAT; kt += 64) {
    f32x4 xr[8], wr[4];
#pragma unroll
    for (int p = 0; p < 8; ++p)
      xr[p] = *reinterpret_cast<const f32x4*>(&X[(size_t)(row0 + srow + p * 16) * FEAT + kt + sk]);
#pragma unroll
    for (int p = 0; p < 4; ++p)
      wr[p] = *reinterpret_cast<const f32x4*>(&W[(size_t)(col0 + srow + p * 16) * FEAT + kt + sk]);
    __syncthreads();
#pragma unroll
    for (int p = 0; p < 8; ++p) {
      const int r = srow + p * 16;
      const int el = r * 64 + (sk ^ ((r & 7) << 3));
#pragma unroll
      for (int i = 0; i < 4; ++i) { unsigned short hh, ll; split2(xr[p][i], hh, ll); Xhi[el + i] = hh; Xlo[el + i] = ll; }
    }
#pragma unroll
    for (int p = 0; p < 4; ++p) {
      const int r = srow + p * 16;
      const int el = r * 64 + (sk ^ ((r & 7) << 3));
#pragma unroll
      for (int i = 0; i < 4; ++i) { unsigned short hh, ll; split2(wr[p][i], hh, ll); Whi[el + i] = hh; Wlo[el + i] = ll; }
    }
    __syncthreads();

#pragma unroll
    for (int c = 0; c < 2; ++c) {
      const int koff = c * 32 + g * 8;
      s16x8 ah[4], al[4], bh[2], bl[2];
#pragma unroll
      for (int mi = 0; mi < 4; ++mi) {
        const int r = wm + mi * 16 + j;
        const int el = r * 64 + (koff ^ ((r & 7) << 3));
        ah[mi] = *reinterpret_cast<const s16x8*>(&Xhi[el]);
        al[mi] = *reinterpret_cast<const s16x8*>(&Xlo[el]);
      }
#pragma unroll
      for (int ni = 0; ni < 2; ++ni) {
        const int r = wn + ni * 16 + j;
        const int el = r * 64 + (koff ^ ((r & 7) << 3));
        bh[ni] = *reinterpret_cast<const s16x8*>(&Whi[el]);
        bl[ni] = *reinterpret_cast<const s16x8*>(&Wlo[el]);
      }
#pragma unroll
      for (int mi = 0; mi < 4; ++mi)
#pragma unroll
        for (int ni = 0; ni < 2; ++ni) {
          acc[mi][ni] = __builtin_amdgcn_mfma_f32_16x16x32_bf16(ah[mi], bh[ni], acc[mi][ni], 0, 0, 0);
          acc[mi][ni] = __builtin_amdgcn_mfma_f32_16x16x32_bf16(ah[mi], bl[ni], acc[mi][ni], 0, 0, 0);
          acc[mi][ni] = __builtin_amdgcn_mfma_f32_16x16x32_bf16(al[mi], bh[ni], acc[mi][ni], 0, 0, 0);
        }
    }
  }

  if (z < 2) {
#pragma unroll
    for (int ni = 0; ni < 2; ++ni) {
      const int colc = col0 + wn + ni * 16 + j;
      const float bj = Bp[colc];
      const int h = colc >> 6, hd = colc & 63;
#pragma unroll
      for (int mi = 0; mi < 4; ++mi)
#pragma unroll
        for (int r = 0; r < 4; ++r) {
          const int rowc = row0 + wm + mi * 16 + (g << 2) + r;
          const int b = rowc >> 11, t = rowc & 2047;
          const float v = (acc[mi][ni][r] + bj) * scale;
          unsigned short hh, ll; split2(v, hh, ll);
          const size_t off = (((size_t)b * NHEADS + h) * SEQ + t) * HD + hd;
          Ohi[off] = hh; Olo[off] = ll;
        }
    }
  } else {
    // V: transpose via LDS -> (B,H,Hd,T)
    __syncthreads();
#pragma unroll
    for (int ni = 0; ni < 2; ++ni) {
      const int hdl = wn + ni * 16 + j;
      const float bj = Bp[col0 + hdl];
#pragma unroll
      for (int mi = 0; mi < 4; ++mi)
#pragma unroll
        for (int r = 0; r < 4; ++r) {
          const int lt = wm + mi * 16 + (g << 2) + r;
          const float v = acc[mi][ni][r] + bj;
          unsigned short hh, ll; split2(v, hh, ll);
          const int el = lt * 64 + (hdl ^ ((lt & 7) << 3));
          Xhi[el] = hh; Xlo[el] = ll;
        }
    }
    __syncthreads();
    const int b = row0 >> 11, h = col0 >> 6;
    const int tbase = row0 & 2047;
#pragma unroll
    for (int c = 0; c < 4; ++c) {
      const int chunk = c * 256 + tid;
      const int hd = chunk >> 4;
      const int t0 = (chunk & 15) * 8;
      u16x8 vh, vl;
#pragma unroll
      for (int i = 0; i < 8; ++i) {
        const int lt = t0 + i;
        const int el = lt * 64 + (hd ^ ((lt & 7) << 3));
        vh[i] = Xhi[el]; vl[i] = Xlo[el];
      }
      const size_t off = (((size_t)b * NHEADS + h) * HD + hd) * SEQ + tbase + t0;
      *reinterpret_cast<u16x8*>(&Vthi[off]) = vh;
      *reinterpret_cast<u16x8*>(&Vtlo[off]) = vl;
    }
  }
}

// ---------------------------------------------------------------------------
// Output projection: out[r,j] = sum_k AO[r,k]*wo[j,k] + bo[j]
// ---------------------------------------------------------------------------
__global__ __launch_bounds__(256) void out_proj(
    const float* __restrict__ X, const float* __restrict__ W,
    const float* __restrict__ bias, float* __restrict__ out)
{
  __shared__ unsigned short Xhi[128 * 64], Xlo[128 * 64];
  __shared__ unsigned short Whi[64 * 64],  Wlo[64 * 64];

  const int tid  = threadIdx.x;
  const int lane = tid & 63;
  const int wave = tid >> 6;
  const int g = lane >> 4, j = lane & 15;
  const int wm = (wave >> 1) * 64;
  const int wn = (wave & 1) * 32;
  const int row0 = blockIdx.x * 128;
  const int col0 = blockIdx.y * 64;

  f32x4 acc[4][2];
#pragma unroll
  for (int mi = 0; mi < 4; ++mi)
#pragma unroll
    for (int ni = 0; ni < 2; ++ni) acc[mi][ni] = (f32x4)0.f;

  const int srow = tid >> 4;
  const int sk   = (tid & 15) * 4;

  for (int kt = 0; kt < FEAT; kt += 64) {
    f32x4 xr[8], wr[4];
#pragma unroll
    for (int p = 0; p < 8; ++p)
      xr[p] = *reinterpret_cast<const f32x4*>(&X[(size_t)(row0 + srow + p * 16) * FEAT + kt + sk]);
#pragma unroll
    for (int p = 0; p < 4; ++p)
      wr[p] = *reinterpret_cast<const f32x4*>(&W[(size_t)(col0 + srow + p * 16) * FEAT + kt + sk]);
    __syncthreads();
#pragma unroll
    for (int p = 0; p < 8; ++p) {
      const int r = srow + p * 16;
      const int el = r * 64 + (sk ^ ((r & 7) << 3));
#pragma unroll
      for (int i = 0; i < 4; ++i) { unsigned short hh, ll; split2(xr[p][i], hh, ll); Xhi[el + i] = hh; Xlo[el + i] = ll; }
    }
#pragma unroll
    for (int p = 0; p < 4; ++p) {
      const int r = srow + p * 16;
      const int el = r * 64 + (sk ^ ((r & 7) << 3));
#pragma unroll
      for (int i = 0; i < 4; ++i) { unsigned short hh, ll; split2(wr[p][i], hh, ll); Whi[el + i] = hh; Wlo[el + i] = ll; }
    }
    __syncthreads();

#pragma unroll
    for (int c = 0; c < 2; ++c) {
      const int koff = c * 32 + g * 8;
      s16x8 ah[4], al[4], bh[2], bl[2];
#pragma unroll
      for (int mi = 0; mi < 4; ++mi) {
        const int r = wm + mi * 16 + j;
        const int el = r * 64 + (koff ^ ((r & 7) << 3));
        ah[mi] = *reinterpret_cast<const s16x8*>(&Xhi[el]);
        al[mi] = *reinterpret_cast<const s16x8*>(&Xlo[el]);
      }
#pragma unroll
      for (int ni = 0; ni < 2; ++ni) {
        const int r = wn + ni * 16 + j;
        const int el = r * 64 + (koff ^ ((r & 7) << 3));
        bh[ni] = *reinterpret_cast<const s16x8*>(&Whi[el]);
        bl[ni] = *reinterpret_cast<const s16x8*>(&Wlo[el]);
      }
#pragma unroll
      for (int mi = 0; mi < 4; ++mi)
#pragma unroll
        for (int ni = 0; ni < 2; ++ni) {
          acc[mi][ni] = __builtin_amdgcn_mfma_f32_16x16x32_bf16(ah[mi], bh[ni], acc[mi][ni], 0, 0, 0);
          acc[mi][ni] = __builtin_amdgcn_mfma_f32_16x16x32_bf16(ah[mi], bl[ni], acc[mi][ni], 0, 0, 0);
          acc[mi][ni] = __builtin_amdgcn_mfma_f32_16x16x32_bf16(al[mi], bh[ni], acc[mi][ni], 0, 0, 0);
        }
    }
  }

#pragma unroll
  for (int ni = 0; ni < 2; ++ni) {
    const int colc = col0 + wn + ni * 16 + j;
    const float bj = bias[colc];
#pragma unroll
    for (int mi = 0; mi < 4; ++mi)
#pragma unroll
      for (int r = 0; r < 4; ++r) {
        const int rowc = row0 + wm + mi * 16 + (g << 2) + r;
        out[(size_t)rowc * FEAT + colc] = acc[mi][ni][r] + bj;
      }
  }
}

// ---------------------------------------------------------------------------
// Flash attention, swapped-operand 32x32x16 MFMA, direct-global K/V with
// register double-buffered prefetch PINNED by sched_barrier(0) so the
// compiler cannot sink the prefetch loads (r6: VGPR=124 proved sinking).
// Block = 4 waves x 32 q-rows = 128 q. Grid 512 (XCD-swizzled).
// ---------------------------------------------------------------------------
__global__ __launch_bounds__(256, 2) void attn_mfma32(
    const unsigned short* __restrict__ Qhi, const unsigned short* __restrict__ Qlo,
    const unsigned short* __restrict__ Khi, const unsigned short* __restrict__ Klo,
    const unsigned short* __restrict__ Vthi, const unsigned short* __restrict__ Vtlo,
    float* __restrict__ AO)
{
  __shared__ float bcast[4][32];

  const int tid = threadIdx.x, lane = tid & 63, wave = tid >> 6;
  const int hfl = lane >> 5;      // half of wave
  const int l31 = lane & 31;

  // XCD-chunked swizzle: 512 blocks = 8 XCDs x 64; each XCD gets 4 bh (4MB KV)
  const int bid = blockIdx.x;
  const int swz = (bid & 7) * 64 + (bid >> 3);
  const int qt  = swz & 15;
  const int bh  = swz >> 4;
  const int b = bh >> 3, h = bh & 7;

  const int q0 = qt * 128 + wave * 32;
  const size_t kvbase = (size_t)bh * SEQ * HD;

  // Q B-fragments (col=q=lane&31, k=hd=c*16+hfl*8+i), pre-scaled by 1/8
  s16x8 qh[4], ql[4];
  {
    const size_t qoff = kvbase + (size_t)(q0 + l31) * HD + hfl * 8;
#pragma unroll
    for (int c = 0; c < 4; ++c) {
      qh[c] = *reinterpret_cast<const s16x8*>(&Qhi[qoff + c * 16]);
      ql[c] = *reinterpret_cast<const s16x8*>(&Qlo[qoff + c * 16]);
    }
  }

  f32x16 oacc0 = (f32x16)0.f, oacc1 = (f32x16)0.f;
  float m = -INFINITY, l = 0.f;

  const unsigned short* kh_p = &Khi[kvbase + (size_t)l31 * HD + hfl * 8];
  const unsigned short* kl_p = &Klo[kvbase + (size_t)l31 * HD + hfl * 8];
  const size_t v0off = ((size_t)bh * HD + l31) * SEQ + hfl * 8;        // hd-tile 0
  const size_t v1off = ((size_t)bh * HD + 32 + l31) * SEQ + hfl * 8;   // hd-tile 1

  auto ldK = [&](int t, s16x8* KH, s16x8* KL) {
    const unsigned short* kh_t = kh_p + (size_t)t * HD;
    const unsigned short* kl_t = kl_p + (size_t)t * HD;
#pragma unroll
    for (int c = 0; c < 4; ++c) {
      KH[c] = *reinterpret_cast<const s16x8*>(&kh_t[c * 16]);
      KL[c] = *reinterpret_cast<const s16x8*>(&kl_t[c * 16]);
    }
  };
  auto ldV = [&](int t, s16x8* VH, s16x8* VL) {
    VH[0] = *reinterpret_cast<const s16x8*>(&Vthi[v0off + t]);
    VH[1] = *reinterpret_cast<const s16x8*>(&Vthi[v0off + t + 16]);
    VH[2] = *reinterpret_cast<const s16x8*>(&Vthi[v1off + t]);
    VH[3] = *reinterpret_cast<const s16x8*>(&Vthi[v1off + t + 16]);
    VL[0] = *reinterpret_cast<const s16x8*>(&Vtlo[v0off + t]);
    VL[1] = *reinterpret_cast<const s16x8*>(&Vtlo[v0off + t + 16]);
    VL[2] = *reinterpret_cast<const s16x8*>(&Vtlo[v1off + t]);
    VL[3] = *reinterpret_cast<const s16x8*>(&Vtlo[v1off + t + 16]);
  };

  auto tile = [&](const s16x8* KH, const s16x8* KL, const s16x8* VH, const s16x8* VL) {
    // ---- S^T = K Q^T ----
    f32x16 st = (f32x16)0.f;
    __builtin_amdgcn_s_setprio(1);
#pragma unroll
    for (int c = 0; c < 4; ++c) {
      st = __builtin_amdgcn_mfma_f32_32x32x16_bf16(KH[c], qh[c], st, 0, 0, 0);
      st = __builtin_amdgcn_mfma_f32_32x32x16_bf16(KH[c], ql[c], st, 0, 0, 0);
      st = __builtin_amdgcn_mfma_f32_32x32x16_bf16(KL[c], qh[c], st, 0, 0, 0);
    }
    __builtin_amdgcn_s_setprio(0);

    // ---- tile max over this lane's 16 keys + cross-half combine ----
    float pm = fmaxf(
        fmaxf(fmaxf(fmaxf(st[0], st[1]), fmaxf(st[2], st[3])),
              fmaxf(fmaxf(st[4], st[5]), fmaxf(st[6], st[7]))),
        fmaxf(fmaxf(fmaxf(st[8], st[9]), fmaxf(st[10], st[11])),
              fmaxf(fmaxf(st[12], st[13]), fmaxf(st[14], st[15]))));
    pm = fmaxf(pm, __shfl_xor(pm, 32));   // full 32-key row max, both halves

    // ---- defer-max rescale (rare; tile 0 always, corr=0 there) ----
    if (__any(pm > m + 8.f)) {
      const float mnew = fmaxf(m, pm);
      const float corr = __expf(m - mnew);
      m = mnew; l *= corr;
      if (lane < 32) bcast[wave][l31] = corr;
      f32x4 c4[4];
#pragma unroll
      for (int rq = 0; rq < 4; ++rq)
        c4[rq] = *reinterpret_cast<const f32x4*>(&bcast[wave][rq * 8 + hfl * 4]);
#pragma unroll
      for (int r = 0; r < 16; ++r) {
        const float cc = c4[r >> 2][r & 3];
        oacc0[r] *= cc; oacc1[r] *= cc;
      }
    }

    // ---- p = exp(s - m), row sum ----
    float rs = 0.f;
#pragma unroll
    for (int r = 0; r < 16; ++r) { st[r] = __expf(st[r] - m); rs += st[r]; }
    rs += __shfl_xor(rs, 32);
    l += rs;

    // ---- pack P hi/lo (proven split2), exchange halves via shfl_xor ----
    unsigned int wh[8], wl[8];
#pragma unroll
    for (int p = 0; p < 8; ++p) {
      unsigned short h0, l0, h1, l1;
      split2(st[2 * p], h0, l0);
      split2(st[2 * p + 1], h1, l1);
      wh[p] = (unsigned int)h0 | ((unsigned int)h1 << 16);
      wl[p] = (unsigned int)l0 | ((unsigned int)l1 << 16);
    }
    unsigned int sh[8], sl[8];
#pragma unroll
    for (int p = 0; p < 8; ++p) {
      sh[p] = (unsigned int)__shfl_xor((int)wh[p], 32);
      sl[p] = (unsigned int)__shfl_xor((int)wl[p], 32);
    }
    const bool lo = (hfl == 0);
    const unsigned int ah0 = lo ? wh[0] : sh[2];
    const unsigned int ah1 = lo ? wh[1] : sh[3];
    const unsigned int ah2 = lo ? sh[0] : wh[2];
    const unsigned int ah3 = lo ? sh[1] : wh[3];
    const unsigned int ah4 = lo ? wh[4] : sh[6];
    const unsigned int ah5 = lo ? wh[5] : sh[7];
    const unsigned int ah6 = lo ? sh[4] : wh[6];
    const unsigned int ah7 = lo ? sh[5] : wh[7];
    const unsigned int al0 = lo ? wl[0] : sl[2];
    const unsigned int al1 = lo ? wl[1] : sl[3];
    const unsigned int al2 = lo ? sl[0] : wl[2];
    const unsigned int al3 = lo ? sl[1] : wl[3];
    const unsigned int al4 = lo ? wl[4] : sl[6];
    const unsigned int al5 = lo ? wl[5] : sl[7];
    const unsigned int al6 = lo ? sl[4] : wl[6];
    const unsigned int al7 = lo ? sl[5] : wl[7];
    const s16x8 pa0h = __builtin_bit_cast(s16x8, (u32x4){ah0, ah1, ah2, ah3});
    const s16x8 pa1h = __builtin_bit_cast(s16x8, (u32x4){ah4, ah5, ah6, ah7});
    const s16x8 pa0l = __builtin_bit_cast(s16x8, (u32x4){al0, al1, al2, al3});
    const s16x8 pa1l = __builtin_bit_cast(s16x8, (u32x4){al4, al5, al6, al7});

    // ---- O += P V ----
    __builtin_amdgcn_s_setprio(1);
    oacc0 = __builtin_amdgcn_mfma_f32_32x32x16_bf16(pa0h, VH[0], oacc0, 0, 0, 0);
    oacc0 = __builtin_amdgcn_mfma_f32_32x32x16_bf16(pa0h, VL[0], oacc0, 0, 0, 0);
    oacc0 = __builtin_amdgcn_mfma_f32_32x32x16_bf16(pa0l, VH[0], oacc0, 0, 0, 0);
    oacc0 = __builtin_amdgcn_mfma_f32_32x32x16_bf16(pa1h, VH[1], oacc0, 0, 0, 0);
    oacc0 = __builtin_amdgcn_mfma_f32_32x32x16_bf16(pa1h, VL[1], oacc0, 0, 0, 0);
    oacc0 = __builtin_amdgcn_mfma_f32_32x32x16_bf16(pa1l, VH[1], oacc0, 0, 0, 0);
    oacc1 = __builtin_amdgcn_mfma_f32_32x32x16_bf16(pa0h, VH[2], oacc1, 0, 0, 0);
    oacc1 = __builtin_amdgcn_mfma_f32_32x32x16_bf16(pa0h, VL[2], oacc1, 0, 0, 0);
    oacc1 = __builtin_amdgcn_mfma_f32_32x32x16_bf16(pa0l, VH[2], oacc1, 0, 0, 0);
    oacc1 = __builtin_amdgcn_mfma_f32_32x32x16_bf16(pa1h, VH[3], oacc1, 0, 0, 0);
    oacc1 = __builtin_amdgcn_mfma_f32_32x32x16_bf16(pa1h, VL[3], oacc1, 0, 0, 0);
    oacc1 = __builtin_amdgcn_mfma_f32_32x32x16_bf16(pa1l, VH[3], oacc1, 0, 0, 0);
    __builtin_amdgcn_s_setprio(0);
  };

  // ---- main loop: A/B register double-buffer; prefetch issue PINNED ----
  s16x8 KHa[4], KLa[4], VHa[4], VLa[4];
  s16x8 KHb[4], KLb[4], VHb[4], VLb[4];
  ldK(0, KHa, KLa); ldV(0, VHa, VLa);
  for (int kt = 0; kt < SEQ; kt += 64) {
    ldK(kt + 32, KHb, KLb); ldV(kt + 32, VHb, VLb);
    __builtin_amdgcn_sched_barrier(0);   // prefetch b MUST issue before tile(a)
    tile(KHa, KLa, VHa, VLa);
    const int tn = (kt + 64) & (SEQ - 1);   // wrap on last iter (harmless)
    ldK(tn, KHa, KLa); ldV(tn, VHa, VLa);
    __builtin_amdgcn_sched_barrier(0);   // prefetch a MUST issue before tile(b)
    tile(KHb, KLb, VHb, VLb);
  }

  // ---- normalize (1/l broadcast via per-wave LDS) and store ----
  if (lane < 32) bcast[wave][l31] = 1.f / l;
  f32x4 i4[4];
#pragma unroll
  for (int rq = 0; rq < 4; ++rq)
    i4[rq] = *reinterpret_cast<const f32x4*>(&bcast[wave][rq * 8 + hfl * 4]);

#pragma unroll
  for (int r = 0; r < 16; ++r) {
    const int q = q0 + (r & 3) + 8 * (r >> 2) + 4 * hfl;
    const float inv = i4[r >> 2][r & 3];
    float* dst = &AO[((size_t)b * SEQ + q) * FEAT + h * HD + l31];
    dst[0]  = oacc0[r] * inv;
    dst[32] = oacc1[r] * inv;
  }
}

extern "C" void kernel_launch(void* const* d_in, const int* in_sizes, int n_in,
                              void* d_out, int out_size, void* d_ws, size_t ws_size,
                              hipStream_t stream) {
  const float* x_cur  = (const float*)d_in[0];
  const float* x_past = (const float*)d_in[1];
  const float* wq = (const float*)d_in[2];
  const float* bq = (const float*)d_in[3];
  const float* wk = (const float*)d_in[4];
  const float* bk = (const float*)d_in[5];
  const float* wv = (const float*)d_in[6];
  const float* bv = (const float*)d_in[7];
  const float* wo = (const float*)d_in[8];
  const float* bo = (const float*)d_in[9];
  float* out = (float*)d_out;

  const size_t n = (size_t)NROWS * FEAT;
  unsigned short* Qhi  = (unsigned short*)d_ws;
  unsigned short* Qlo  = Qhi + n;
  unsigned short* Khi  = Qhi + 2 * n;
  unsigned short* Klo  = Qhi + 3 * n;
  unsigned short* Vthi = Qhi + 4 * n;
  unsigned short* Vtlo = Qhi + 5 * n;
  float* AO = (float*)(Qhi + 6 * n);

  dim3 block(256);
  dim3 gqkv(NROWS / 128, FEAT / 64, 3);
  qkv_proj<<<gqkv, block, 0, stream>>>(x_cur, x_past, wq, bq, wk, bk, wv, bv,
                                       Qhi, Qlo, Khi, Klo, Vthi, Vtlo);

  attn_mfma32<<<dim3(512), block, 0, stream>>>(Qhi, Qlo, Khi, Klo, Vthi, Vtlo, AO);

  dim3 gout(NROWS / 128, FEAT / 64);
  out_proj<<<gout, block, 0, stream>>>(AO, wo, bo, out);
}

// Round 8
// 229.347 us; speedup vs baseline: 1.4274x; 1.4274x over previous
//
#include <hip/hip_runtime.h>
#include <math.h>

#define BATCH 4
#define SEQ 2048
#define FEAT 512
#define NHEADS 8
#define HD 64
#define NROWS (BATCH*SEQ)   // 8192

typedef __attribute__((ext_vector_type(4)))  float f32x4;
typedef __attribute__((ext_vector_type(16))) float f32x16;
typedef __attribute__((ext_vector_type(8)))  short s16x8;
typedef __attribute__((ext_vector_type(8)))  unsigned short u16x8;
typedef __attribute__((ext_vector_type(4)))  unsigned int u32x4;

static __device__ __forceinline__ unsigned short f2bf(float x) {
  unsigned int u = __builtin_bit_cast(unsigned int, x);
  unsigned int r = (u + 0x7FFFu + ((u >> 16) & 1u)) >> 16;
  return (unsigned short)r;
}
static __device__ __forceinline__ float bf2f(unsigned short h) {
  unsigned int u = ((unsigned int)h) << 16;
  return __builtin_bit_cast(float, u);
}
static __device__ __forceinline__ void split2(float x, unsigned short& h, unsigned short& l) {
  h = f2bf(x);
  l = f2bf(x - bf2f(h));
}

// async global->LDS, 16B per lane; dest = wave-uniform base + lane*16
static __device__ __forceinline__ void glds16(const unsigned short* g, unsigned short* l) {
  __builtin_amdgcn_global_load_lds(
      (const __attribute__((address_space(1))) unsigned int*)g,
      (__attribute__((address_space(3))) unsigned int*)l,
      16, 0, 0);
}

// ---------------------------------------------------------------------------
// Fused QKV projection. z=0: Q (scale 1/8) -> (B,H,T,Hd) hi/lo
//                       z=1: K            -> (B,H,T,Hd) hi/lo
//                       z=2: V            -> (B,H,Hd,T) hi/lo (LDS transpose)
// ---------------------------------------------------------------------------
__global__ __launch_bounds__(256) void qkv_proj(
    const float* __restrict__ xc, const float* __restrict__ xp,
    const float* __restrict__ wq, const float* __restrict__ bq,
    const float* __restrict__ wk, const float* __restrict__ bk,
    const float* __restrict__ wv, const float* __restrict__ bv,
    unsigned short* __restrict__ Qhi, unsigned short* __restrict__ Qlo,
    unsigned short* __restrict__ Khi, unsigned short* __restrict__ Klo,
    unsigned short* __restrict__ Vthi, unsigned short* __restrict__ Vtlo)
{
  __shared__ unsigned short Xhi[128 * 64], Xlo[128 * 64];
  __shared__ unsigned short Whi[64 * 64],  Wlo[64 * 64];

  const int z = blockIdx.z;
  const float* X  = (z == 0) ? xc : xp;
  const float* W  = (z == 0) ? wq : (z == 1) ? wk : wv;
  const float* Bp = (z == 0) ? bq : (z == 1) ? bk : bv;
  unsigned short* Ohi = (z == 0) ? Qhi : (z == 1) ? Khi : Vthi;
  unsigned short* Olo = (z == 0) ? Qlo : (z == 1) ? Klo : Vtlo;
  const float scale = (z == 0) ? 0.125f : 1.0f;

  const int tid  = threadIdx.x;
  const int lane = tid & 63;
  const int wave = tid >> 6;
  const int g = lane >> 4, j = lane & 15;
  const int wm = (wave >> 1) * 64;
  const int wn = (wave & 1) * 32;
  const int row0 = blockIdx.x * 128;
  const int col0 = blockIdx.y * 64;

  f32x4 acc[4][2];
#pragma unroll
  for (int mi = 0; mi < 4; ++mi)
#pragma unroll
    for (int ni = 0; ni < 2; ++ni) acc[mi][ni] = (f32x4)0.f;

  const int srow = tid >> 4;        // 0..15
  const int sk   = (tid & 15) * 4;  // 0..60

  for (int kt = 0; kt < FEAT; kt += 64) {
    f32x4 xr[8], wr[4];
#pragma unroll
    for (int p = 0; p < 8; ++p)
      xr[p] = *reinterpret_cast<const f32x4*>(&X[(size_t)(row0 + srow + p * 16) * FEAT + kt + sk]);
#pragma unroll
    for (int p = 0; p < 4; ++p)
      wr[p] = *reinterpret_cast<const f32x4*>(&W[(size_t)(col0 + srow + p * 16) * FEAT + kt + sk]);
    __syncthreads();
#pragma unroll
    for (int p = 0; p < 8; ++p) {
      const int r = srow + p * 16;
      const int el = r * 64 + (sk ^ ((r & 7) << 3));
#pragma unroll
      for (int i = 0; i < 4; ++i) { unsigned short hh, ll; split2(xr[p][i], hh, ll); Xhi[el + i] = hh; Xlo[el + i] = ll; }
    }
#pragma unroll
    for (int p = 0; p < 4; ++p) {
      const int r = srow + p * 16;
      const int el = r * 64 + (sk ^ ((r & 7) << 3));
#pragma unroll
      for (int i = 0; i < 4; ++i) { unsigned short hh, ll; split2(wr[p][i], hh, ll); Whi[el + i] = hh; Wlo[el + i] = ll; }
    }
    __syncthreads();

#pragma unroll
    for (int c = 0; c < 2; ++c) {
      const int koff = c * 32 + g * 8;
      s16x8 ah[4], al[4], bh[2], bl[2];
#pragma unroll
      for (int mi = 0; mi < 4; ++mi) {
        const int r = wm + mi * 16 + j;
        const int el = r * 64 + (koff ^ ((r & 7) << 3));
        ah[mi] = *reinterpret_cast<const s16x8*>(&Xhi[el]);
        al[mi] = *reinterpret_cast<const s16x8*>(&Xlo[el]);
      }
#pragma unroll
      for (int ni = 0; ni < 2; ++ni) {
        const int r = wn + ni * 16 + j;
        const int el = r * 64 + (koff ^ ((r & 7) << 3));
        bh[ni] = *reinterpret_cast<const s16x8*>(&Whi[el]);
        bl[ni] = *reinterpret_cast<const s16x8*>(&Wlo[el]);
      }
#pragma unroll
      for (int mi = 0; mi < 4; ++mi)
#pragma unroll
        for (int ni = 0; ni < 2; ++ni) {
          acc[mi][ni] = __builtin_amdgcn_mfma_f32_16x16x32_bf16(ah[mi], bh[ni], acc[mi][ni], 0, 0, 0);
          acc[mi][ni] = __builtin_amdgcn_mfma_f32_16x16x32_bf16(ah[mi], bl[ni], acc[mi][ni], 0, 0, 0);
          acc[mi][ni] = __builtin_amdgcn_mfma_f32_16x16x32_bf16(al[mi], bh[ni], acc[mi][ni], 0, 0, 0);
        }
    }
  }

  if (z < 2) {
#pragma unroll
    for (int ni = 0; ni < 2; ++ni) {
      const int colc = col0 + wn + ni * 16 + j;
      const float bj = Bp[colc];
      const int h = colc >> 6, hd = colc & 63;
#pragma unroll
      for (int mi = 0; mi < 4; ++mi)
#pragma unroll
        for (int r = 0; r < 4; ++r) {
          const int rowc = row0 + wm + mi * 16 + (g << 2) + r;
          const int b = rowc >> 11, t = rowc & 2047;
          const float v = (acc[mi][ni][r] + bj) * scale;
          unsigned short hh, ll; split2(v, hh, ll);
          const size_t off = (((size_t)b * NHEADS + h) * SEQ + t) * HD + hd;
          Ohi[off] = hh; Olo[off] = ll;
        }
    }
  } else {
    // V: transpose via LDS -> (B,H,Hd,T)
    __syncthreads();
#pragma unroll
    for (int ni = 0; ni < 2; ++ni) {
      const int hdl = wn + ni * 16 + j;
      const float bj = Bp[col0 + hdl];
#pragma unroll
      for (int mi = 0; mi < 4; ++mi)
#pragma unroll
        for (int r = 0; r < 4; ++r) {
          const int lt = wm + mi * 16 + (g << 2) + r;
          const float v = acc[mi][ni][r] + bj;
          unsigned short hh, ll; split2(v, hh, ll);
          const int el = lt * 64 + (hdl ^ ((lt & 7) << 3));
          Xhi[el] = hh; Xlo[el] = ll;
        }
    }
    __syncthreads();
    const int b = row0 >> 11, h = col0 >> 6;
    const int tbase = row0 & 2047;
#pragma unroll
    for (int c = 0; c < 4; ++c) {
      const int chunk = c * 256 + tid;
      const int hd = chunk >> 4;
      const int t0 = (chunk & 15) * 8;
      u16x8 vh, vl;
#pragma unroll
      for (int i = 0; i < 8; ++i) {
        const int lt = t0 + i;
        const int el = lt * 64 + (hd ^ ((lt & 7) << 3));
        vh[i] = Xhi[el]; vl[i] = Xlo[el];
      }
      const size_t off = (((size_t)b * NHEADS + h) * HD + hd) * SEQ + tbase + t0;
      *reinterpret_cast<u16x8*>(&Vthi[off]) = vh;
      *reinterpret_cast<u16x8*>(&Vtlo[off]) = vl;
    }
  }
}

// ---------------------------------------------------------------------------
// Output projection: out[r,j] = sum_k AO[r,k]*wo[j,k] + bo[j]
// ---------------------------------------------------------------------------
__global__ __launch_bounds__(256) void out_proj(
    const float* __restrict__ X, const float* __restrict__ W,
    const float* __restrict__ bias, float* __restrict__ out)
{
  __shared__ unsigned short Xhi[128 * 64], Xlo[128 * 64];
  __shared__ unsigned short Whi[64 * 64],  Wlo[64 * 64];

  const int tid  = threadIdx.x;
  const int lane = tid & 63;
  const int wave = tid >> 6;
  const int g = lane >> 4, j = lane & 15;
  const int wm = (wave >> 1) * 64;
  const int wn = (wave & 1) * 32;
  const int row0 = blockIdx.x * 128;
  const int col0 = blockIdx.y * 64;

  f32x4 acc[4][2];
#pragma unroll
  for (int mi = 0; mi < 4; ++mi)
#pragma unroll
    for (int ni = 0; ni < 2; ++ni) acc[mi][ni] = (f32x4)0.f;

  const int srow = tid >> 4;
  const int sk   = (tid & 15) * 4;

  for (int kt = 0; kt < FEAT; kt += 64) {
    f32x4 xr[8], wr[4];
#pragma unroll
    for (int p = 0; p < 8; ++p)
      xr[p] = *reinterpret_cast<const f32x4*>(&X[(size_t)(row0 + srow + p * 16) * FEAT + kt + sk]);
#pragma unroll
    for (int p = 0; p < 4; ++p)
      wr[p] = *reinterpret_cast<const f32x4*>(&W[(size_t)(col0 + srow + p * 16) * FEAT + kt + sk]);
    __syncthreads();
#pragma unroll
    for (int p = 0; p < 8; ++p) {
      const int r = srow + p * 16;
      const int el = r * 64 + (sk ^ ((r & 7) << 3));
#pragma unroll
      for (int i = 0; i < 4; ++i) { unsigned short hh, ll; split2(xr[p][i], hh, ll); Xhi[el + i] = hh; Xlo[el + i] = ll; }
    }
#pragma unroll
    for (int p = 0; p < 4; ++p) {
      const int r = srow + p * 16;
      const int el = r * 64 + (sk ^ ((r & 7) << 3));
#pragma unroll
      for (int i = 0; i < 4; ++i) { unsigned short hh, ll; split2(wr[p][i], hh, ll); Whi[el + i] = hh; Wlo[el + i] = ll; }
    }
    __syncthreads();

#pragma unroll
    for (int c = 0; c < 2; ++c) {
      const int koff = c * 32 + g * 8;
      s16x8 ah[4], al[4], bh[2], bl[2];
#pragma unroll
      for (int mi = 0; mi < 4; ++mi) {
        const int r = wm + mi * 16 + j;
        const int el = r * 64 + (koff ^ ((r & 7) << 3));
        ah[mi] = *reinterpret_cast<const s16x8*>(&Xhi[el]);
        al[mi] = *reinterpret_cast<const s16x8*>(&Xlo[el]);
      }
#pragma unroll
      for (int ni = 0; ni < 2; ++ni) {
        const int r = wn + ni * 16 + j;
        const int el = r * 64 + (koff ^ ((r & 7) << 3));
        bh[ni] = *reinterpret_cast<const s16x8*>(&Whi[el]);
        bl[ni] = *reinterpret_cast<const s16x8*>(&Wlo[el]);
      }
#pragma unroll
      for (int mi = 0; mi < 4; ++mi)
#pragma unroll
        for (int ni = 0; ni < 2; ++ni) {
          acc[mi][ni] = __builtin_amdgcn_mfma_f32_16x16x32_bf16(ah[mi], bh[ni], acc[mi][ni], 0, 0, 0);
          acc[mi][ni] = __builtin_amdgcn_mfma_f32_16x16x32_bf16(ah[mi], bl[ni], acc[mi][ni], 0, 0, 0);
          acc[mi][ni] = __builtin_amdgcn_mfma_f32_16x16x32_bf16(al[mi], bh[ni], acc[mi][ni], 0, 0, 0);
        }
    }
  }

#pragma unroll
  for (int ni = 0; ni < 2; ++ni) {
    const int colc = col0 + wn + ni * 16 + j;
    const float bj = bias[colc];
#pragma unroll
    for (int mi = 0; mi < 4; ++mi)
#pragma unroll
      for (int r = 0; r < 4; ++r) {
        const int rowc = row0 + wm + mi * 16 + (g << 2) + r;
        out[(size_t)rowc * FEAT + colc] = acc[mi][ni][r] + bj;
      }
  }
}

// ---------------------------------------------------------------------------
// Flash attention: 2-phase LDS pipeline via global_load_lds (unsinkable DMA),
// 32x32x16 swapped-operand MFMA, XOR-swizzled LDS tiles (linear dest +
// inverse-swizzled global source + swizzled read), deferred-l softmax,
// conditional pm swap, 8-bpermute payload-merged P redistribution.
// Block = 4 waves x 32 q = 128 q. Grid 512 (XCD-swizzled). KVBLK=32.
// ---------------------------------------------------------------------------
__global__ __launch_bounds__(256, 2) void attn_pipe(
    const unsigned short* __restrict__ Qhi, const unsigned short* __restrict__ Qlo,
    const unsigned short* __restrict__ Khi, const unsigned short* __restrict__ Klo,
    const unsigned short* __restrict__ Vthi, const unsigned short* __restrict__ Vtlo,
    float* __restrict__ AO)
{
  // K tile: [32 key][64 hd], slot16 = (hd/8) ^ (key&7)
  // V tile: [32 row][8 slots]: row r = hd&31; slots 0-3: hd=r keys 0..31,
  //         slots 4-7: hd=r+32 keys 0..31; stored slot = slot ^ (r&7)
  __shared__ unsigned short Kh_s[2][2048];
  __shared__ unsigned short Kl_s[2][2048];
  __shared__ unsigned short Vh_s[2][2048];
  __shared__ unsigned short Vl_s[2][2048];
  __shared__ float bcast[4][32];

  const int tid = threadIdx.x, lane = tid & 63, wave = tid >> 6;
  const int hfl = lane >> 5;
  const int l31 = lane & 31;
  const bool lo = (hfl == 0);

  const int bid = blockIdx.x;
  const int swz = (bid & 7) * 64 + (bid >> 3);
  const int qt  = swz & 15;
  const int bh  = swz >> 4;
  const int b = bh >> 3, h = bh & 7;

  const int q0 = qt * 128 + wave * 32;
  const size_t kvbase = (size_t)bh * SEQ * HD;

  // Q B-fragments (col=q=lane&31, k=hd), pre-scaled by 1/8
  s16x8 qh[4], ql[4];
  {
    const size_t qoff = kvbase + (size_t)(q0 + l31) * HD + hfl * 8;
#pragma unroll
    for (int c = 0; c < 4; ++c) {
      qh[c] = *reinterpret_cast<const s16x8*>(&Qhi[qoff + c * 16]);
      ql[c] = *reinterpret_cast<const s16x8*>(&Qlo[qoff + c * 16]);
    }
  }

  f32x16 oacc0 = (f32x16)0.f, oacc1 = (f32x16)0.f;
  float m = -INFINITY, lsum = 0.f;   // lsum = per-half partial denominator

  // ---- staging source addresses (inverse-swizzled global) ----
  const int ck  = tid >> 3;                   // K: key 0..31
  const int ksl = (tid & 7) ^ (ck & 7);       // K: logical slot16
  const unsigned short* sKh = Khi + kvbase + (size_t)ck * HD + ksl * 8;
  const unsigned short* sKl = Klo + kvbase + (size_t)ck * HD + ksl * 8;
  const int vr  = tid >> 3;                   // V: row 0..31
  const int vsl = (tid & 7) ^ (vr & 7);       // V: logical slot
  const int vhd = vr + (vsl >> 2) * 32;
  const int vk0 = (vsl & 3) * 8;
  const unsigned short* sVh = Vthi + kvbase + (size_t)vhd * SEQ + vk0;
  const unsigned short* sVl = Vtlo + kvbase + (size_t)vhd * SEQ + vk0;
  const int wq = wave * 512;                  // per-wave quarter (u16 elems)

  const int krow = l31 * 64;   // fragment-read row base
  const int ksw  = l31 & 7;    // fragment-read swizzle

  // prologue: stage tile 0
  glds16(sKh, &Kh_s[0][wq]);
  glds16(sKl, &Kl_s[0][wq]);
  glds16(sVh, &Vh_s[0][wq]);
  glds16(sVl, &Vl_s[0][wq]);
  asm volatile("s_waitcnt vmcnt(0)" ::: "memory");
  __syncthreads();

  int cur = 0;
  for (int t = 0; t < SEQ / 32; ++t) {
    // stage next tile into the other buffer (in flight across this compute)
    if (t + 1 < SEQ / 32) {
      const size_t ko = (size_t)(t + 1) * 32 * HD;
      const int    vo = (t + 1) * 32;
      glds16(sKh + ko, &Kh_s[cur ^ 1][wq]);
      glds16(sKl + ko, &Kl_s[cur ^ 1][wq]);
      glds16(sVh + vo, &Vh_s[cur ^ 1][wq]);
      glds16(sVl + vo, &Vl_s[cur ^ 1][wq]);
    }
    __builtin_amdgcn_sched_barrier(0);

    // ---- K fragments from LDS ----
    s16x8 KH[4], KL[4];
#pragma unroll
    for (int c = 0; c < 4; ++c) {
      const int idx = krow + ((((c << 1) | hfl)) ^ ksw) * 8;
      KH[c] = *reinterpret_cast<const s16x8*>(&Kh_s[cur][idx]);
      KL[c] = *reinterpret_cast<const s16x8*>(&Kl_s[cur][idx]);
    }

    // ---- S^T = K Q^T ----
    f32x16 st = (f32x16)0.f;
    __builtin_amdgcn_s_setprio(1);
#pragma unroll
    for (int c = 0; c < 4; ++c) {
      st = __builtin_amdgcn_mfma_f32_32x32x16_bf16(KH[c], qh[c], st, 0, 0, 0);
      st = __builtin_amdgcn_mfma_f32_32x32x16_bf16(KH[c], ql[c], st, 0, 0, 0);
      st = __builtin_amdgcn_mfma_f32_32x32x16_bf16(KL[c], qh[c], st, 0, 0, 0);
    }
    __builtin_amdgcn_s_setprio(0);

    // ---- V fragments (issue early; latency hides under softmax) ----
    s16x8 V0h[2], V0l[2], V1h[2], V1l[2];
#pragma unroll
    for (int c = 0; c < 2; ++c) {
      const int i0 = krow + ((((c << 1) | hfl)) ^ ksw) * 8;        // hd = l31
      const int i1 = krow + (((4 | (c << 1) | hfl)) ^ ksw) * 8;    // hd = l31+32
      V0h[c] = *reinterpret_cast<const s16x8*>(&Vh_s[cur][i0]);
      V0l[c] = *reinterpret_cast<const s16x8*>(&Vl_s[cur][i0]);
      V1h[c] = *reinterpret_cast<const s16x8*>(&Vh_s[cur][i1]);
      V1l[c] = *reinterpret_cast<const s16x8*>(&Vl_s[cur][i1]);
    }

    // ---- per-half tile max (tree); cross-half swap only on trigger ----
    float pm = fmaxf(
        fmaxf(fmaxf(fmaxf(st[0], st[1]), fmaxf(st[2], st[3])),
              fmaxf(fmaxf(st[4], st[5]), fmaxf(st[6], st[7]))),
        fmaxf(fmaxf(fmaxf(st[8], st[9]), fmaxf(st[10], st[11])),
              fmaxf(fmaxf(st[12], st[13]), fmaxf(st[14], st[15]))));

    if (__any(pm > m + 8.f)) {
      const float pmf  = fmaxf(pm, __shfl_xor(pm, 32));
      const float mnew = fmaxf(m, pmf);
      const float corr = __expf(m - mnew);
      m = mnew; lsum *= corr;
      if (lane < 32) bcast[wave][l31] = corr;
      f32x4 c4[4];
#pragma unroll
      for (int rq = 0; rq < 4; ++rq)
        c4[rq] = *reinterpret_cast<const f32x4*>(&bcast[wave][rq * 8 + hfl * 4]);
#pragma unroll
      for (int r = 0; r < 16; ++r) {
        const float cc = c4[r >> 2][r & 3];
        oacc0[r] *= cc; oacc1[r] *= cc;
      }
    }

    // ---- p = exp(s - m); per-half partial sum (deferred cross-half) ----
#pragma unroll
    for (int r = 0; r < 16; ++r) st[r] = __expf(st[r] - m);
    {
      float s0 = (st[0] + st[1]) + (st[2] + st[3]);
      float s1 = (st[4] + st[5]) + (st[6] + st[7]);
      float s2 = (st[8] + st[9]) + (st[10] + st[11]);
      float s3 = (st[12] + st[13]) + (st[14] + st[15]);
      lsum += (s0 + s1) + (s2 + s3);
    }

    // ---- pack P hi/lo; payload-merged half exchange (8 bpermutes) ----
    unsigned int wh[8], wl[8];
#pragma unroll
    for (int p = 0; p < 8; ++p) {
      unsigned short h0, l0, h1, l1;
      split2(st[2 * p], h0, l0);
      split2(st[2 * p + 1], h1, l1);
      wh[p] = (unsigned int)h0 | ((unsigned int)h1 << 16);
      wl[p] = (unsigned int)l0 | ((unsigned int)l1 << 16);
    }
    unsigned int xh[4], xl[4];
    xh[0] = (unsigned int)__shfl_xor((int)(lo ? wh[2] : wh[0]), 32);
    xh[1] = (unsigned int)__shfl_xor((int)(lo ? wh[3] : wh[1]), 32);
    xh[2] = (unsigned int)__shfl_xor((int)(lo ? wh[6] : wh[4]), 32);
    xh[3] = (unsigned int)__shfl_xor((int)(lo ? wh[7] : wh[5]), 32);
    xl[0] = (unsigned int)__shfl_xor((int)(lo ? wl[2] : wl[0]), 32);
    xl[1] = (unsigned int)__shfl_xor((int)(lo ? wl[3] : wl[1]), 32);
    xl[2] = (unsigned int)__shfl_xor((int)(lo ? wl[6] : wl[4]), 32);
    xl[3] = (unsigned int)__shfl_xor((int)(lo ? wl[7] : wl[5]), 32);
    const s16x8 pa0h = __builtin_bit_cast(s16x8, (u32x4){
        lo ? wh[0] : xh[0], lo ? wh[1] : xh[1], lo ? xh[0] : wh[2], lo ? xh[1] : wh[3]});
    const s16x8 pa1h = __builtin_bit_cast(s16x8, (u32x4){
        lo ? wh[4] : xh[2], lo ? wh[5] : xh[3], lo ? xh[2] : wh[6], lo ? xh[3] : wh[7]});
    const s16x8 pa0l = __builtin_bit_cast(s16x8, (u32x4){
        lo ? wl[0] : xl[0], lo ? wl[1] : xl[1], lo ? xl[0] : wl[2], lo ? xl[1] : wl[3]});
    const s16x8 pa1l = __builtin_bit_cast(s16x8, (u32x4){
        lo ? wl[4] : xl[2], lo ? wl[5] : xl[3], lo ? xl[2] : wl[6], lo ? xl[3] : wl[7]});

    // ---- O += P V ----
    __builtin_amdgcn_s_setprio(1);
    oacc0 = __builtin_amdgcn_mfma_f32_32x32x16_bf16(pa0h, V0h[0], oacc0, 0, 0, 0);
    oacc0 = __builtin_amdgcn_mfma_f32_32x32x16_bf16(pa0h, V0l[0], oacc0, 0, 0, 0);
    oacc0 = __builtin_amdgcn_mfma_f32_32x32x16_bf16(pa0l, V0h[0], oacc0, 0, 0, 0);
    oacc0 = __builtin_amdgcn_mfma_f32_32x32x16_bf16(pa1h, V0h[1], oacc0, 0, 0, 0);
    oacc0 = __builtin_amdgcn_mfma_f32_32x32x16_bf16(pa1h, V0l[1], oacc0, 0, 0, 0);
    oacc0 = __builtin_amdgcn_mfma_f32_32x32x16_bf16(pa1l, V0h[1], oacc0, 0, 0, 0);
    oacc1 = __builtin_amdgcn_mfma_f32_32x32x16_bf16(pa0h, V1h[0], oacc1, 0, 0, 0);
    oacc1 = __builtin_amdgcn_mfma_f32_32x32x16_bf16(pa0h, V1l[0], oacc1, 0, 0, 0);
    oacc1 = __builtin_amdgcn_mfma_f32_32x32x16_bf16(pa0l, V1h[0], oacc1, 0, 0, 0);
    oacc1 = __builtin_amdgcn_mfma_f32_32x32x16_bf16(pa1h, V1h[1], oacc1, 0, 0, 0);
    oacc1 = __builtin_amdgcn_mfma_f32_32x32x16_bf16(pa1h, V1l[1], oacc1, 0, 0, 0);
    oacc1 = __builtin_amdgcn_mfma_f32_32x32x16_bf16(pa1l, V1h[1], oacc1, 0, 0, 0);
    __builtin_amdgcn_s_setprio(0);

    // staged data for next tile must have landed; all waves done reading cur
    asm volatile("s_waitcnt vmcnt(0)" ::: "memory");
    __syncthreads();
    cur ^= 1;
  }

  // ---- combine half-denominators, normalize, store ----
  const float lf = lsum + __shfl_xor(lsum, 32);
  if (lane < 32) bcast[wave][l31] = 1.f / lf;
  f32x4 i4[4];
#pragma unroll
  for (int rq = 0; rq < 4; ++rq)
    i4[rq] = *reinterpret_cast<const f32x4*>(&bcast[wave][rq * 8 + hfl * 4]);

#pragma unroll
  for (int r = 0; r < 16; ++r) {
    const int q = q0 + (r & 3) + 8 * (r >> 2) + 4 * hfl;
    const float inv = i4[r >> 2][r & 3];
    float* dst = &AO[((size_t)b * SEQ + q) * FEAT + h * HD + l31];
    dst[0]  = oacc0[r] * inv;
    dst[32] = oacc1[r] * inv;
  }
}

extern "C" void kernel_launch(void* const* d_in, const int* in_sizes, int n_in,
                              void* d_out, int out_size, void* d_ws, size_t ws_size,
                              hipStream_t stream) {
  const float* x_cur  = (const float*)d_in[0];
  const float* x_past = (const float*)d_in[1];
  const float* wq = (const float*)d_in[2];
  const float* bq = (const float*)d_in[3];
  const float* wk = (const float*)d_in[4];
  const float* bk = (const float*)d_in[5];
  const float* wv = (const float*)d_in[6];
  const float* bv = (const float*)d_in[7];
  const float* wo = (const float*)d_in[8];
  const float* bo = (const float*)d_in[9];
  float* out = (float*)d_out;

  const size_t n = (size_t)NROWS * FEAT;
  unsigned short* Qhi  = (unsigned short*)d_ws;
  unsigned short* Qlo  = Qhi + n;
  unsigned short* Khi  = Qhi + 2 * n;
  unsigned short* Klo  = Qhi + 3 * n;
  unsigned short* Vthi = Qhi + 4 * n;
  unsigned short* Vtlo = Qhi + 5 * n;
  float* AO = (float*)(Qhi + 6 * n);

  dim3 block(256);
  dim3 gqkv(NROWS / 128, FEAT / 64, 3);
  qkv_proj<<<gqkv, block, 0, stream>>>(x_cur, x_past, wq, bq, wk, bk, wv, bv,
                                       Qhi, Qlo, Khi, Klo, Vthi, Vtlo);

  attn_pipe<<<dim3(512), block, 0, stream>>>(Qhi, Qlo, Khi, Klo, Vthi, Vtlo, AO);

  dim3 gout(NROWS / 128, FEAT / 64);
  out_proj<<<gout, block, 0, stream>>>(AO, wo, bo, out);
}

// Round 9
// 179.811 us; speedup vs baseline: 1.8206x; 1.2755x over previous
//
#include <hip/hip_runtime.h>
#include <math.h>

#define BATCH 4
#define SEQ 2048
#define FEAT 512
#define NHEADS 8
#define HD 64
#define NROWS (BATCH*SEQ)   // 8192

typedef __attribute__((ext_vector_type(4)))  float f32x4;
typedef __attribute__((ext_vector_type(16))) float f32x16;
typedef __attribute__((ext_vector_type(8)))  short s16x8;
typedef __attribute__((ext_vector_type(8)))  unsigned short u16x8;
typedef __attribute__((ext_vector_type(4)))  unsigned int u32x4;

static __device__ __forceinline__ unsigned short f2bf(float x) {
  unsigned int u = __builtin_bit_cast(unsigned int, x);
  unsigned int r = (u + 0x7FFFu + ((u >> 16) & 1u)) >> 16;
  return (unsigned short)r;
}
static __device__ __forceinline__ float bf2f(unsigned short h) {
  unsigned int u = ((unsigned int)h) << 16;
  return __builtin_bit_cast(float, u);
}
static __device__ __forceinline__ void split2(float x, unsigned short& h, unsigned short& l) {
  h = f2bf(x);
  l = f2bf(x - bf2f(h));
}

// async global->LDS, 16B per lane; dest = wave-uniform base + lane*16
static __device__ __forceinline__ void glds16(const unsigned short* g, unsigned short* l) {
  __builtin_amdgcn_global_load_lds(
      (const __attribute__((address_space(1))) unsigned int*)g,
      (__attribute__((address_space(3))) unsigned int*)l,
      16, 0, 0);
}

// ---------------------------------------------------------------------------
// Fused QKV projection. z=0: Q (scale 1/8) -> (B,H,T,Hd) hi/lo
//                       z=1: K            -> (B,H,T,Hd) hi/lo
//                       z=2: V            -> (B,H,Hd,T) hi ONLY (LDS transpose)
// ---------------------------------------------------------------------------
__global__ __launch_bounds__(256) void qkv_proj(
    const float* __restrict__ xc, const float* __restrict__ xp,
    const float* __restrict__ wq, const float* __restrict__ bq,
    const float* __restrict__ wk, const float* __restrict__ bk,
    const float* __restrict__ wv, const float* __restrict__ bv,
    unsigned short* __restrict__ Qhi, unsigned short* __restrict__ Qlo,
    unsigned short* __restrict__ Khi, unsigned short* __restrict__ Klo,
    unsigned short* __restrict__ Vthi)
{
  __shared__ unsigned short Xhi[128 * 64], Xlo[128 * 64];
  __shared__ unsigned short Whi[64 * 64],  Wlo[64 * 64];

  const int z = blockIdx.z;
  const float* X  = (z == 0) ? xc : xp;
  const float* W  = (z == 0) ? wq : (z == 1) ? wk : wv;
  const float* Bp = (z == 0) ? bq : (z == 1) ? bk : bv;
  unsigned short* Ohi = (z == 0) ? Qhi : (z == 1) ? Khi : Vthi;
  unsigned short* Olo = (z == 0) ? Qlo : Klo;   // unused for z==2
  const float scale = (z == 0) ? 0.125f : 1.0f;

  const int tid  = threadIdx.x;
  const int lane = tid & 63;
  const int wave = tid >> 6;
  const int g = lane >> 4, j = lane & 15;
  const int wm = (wave >> 1) * 64;
  const int wn = (wave & 1) * 32;
  const int row0 = blockIdx.x * 128;
  const int col0 = blockIdx.y * 64;

  f32x4 acc[4][2];
#pragma unroll
  for (int mi = 0; mi < 4; ++mi)
#pragma unroll
    for (int ni = 0; ni < 2; ++ni) acc[mi][ni] = (f32x4)0.f;

  const int srow = tid >> 4;        // 0..15
  const int sk   = (tid & 15) * 4;  // 0..60

  for (int kt = 0; kt < FEAT; kt += 64) {
    f32x4 xr[8], wr[4];
#pragma unroll
    for (int p = 0; p < 8; ++p)
      xr[p] = *reinterpret_cast<const f32x4*>(&X[(size_t)(row0 + srow + p * 16) * FEAT + kt + sk]);
#pragma unroll
    for (int p = 0; p < 4; ++p)
      wr[p] = *reinterpret_cast<const f32x4*>(&W[(size_t)(col0 + srow + p * 16) * FEAT + kt + sk]);
    __syncthreads();
#pragma unroll
    for (int p = 0; p < 8; ++p) {
      const int r = srow + p * 16;
      const int el = r * 64 + (sk ^ ((r & 7) << 3));
#pragma unroll
      for (int i = 0; i < 4; ++i) { unsigned short hh, ll; split2(xr[p][i], hh, ll); Xhi[el + i] = hh; Xlo[el + i] = ll; }
    }
#pragma unroll
    for (int p = 0; p < 4; ++p) {
      const int r = srow + p * 16;
      const int el = r * 64 + (sk ^ ((r & 7) << 3));
#pragma unroll
      for (int i = 0; i < 4; ++i) { unsigned short hh, ll; split2(wr[p][i], hh, ll); Whi[el + i] = hh; Wlo[el + i] = ll; }
    }
    __syncthreads();

#pragma unroll
    for (int c = 0; c < 2; ++c) {
      const int koff = c * 32 + g * 8;
      s16x8 ah[4], al[4], bh[2], bl[2];
#pragma unroll
      for (int mi = 0; mi < 4; ++mi) {
        const int r = wm + mi * 16 + j;
        const int el = r * 64 + (koff ^ ((r & 7) << 3));
        ah[mi] = *reinterpret_cast<const s16x8*>(&Xhi[el]);
        al[mi] = *reinterpret_cast<const s16x8*>(&Xlo[el]);
      }
#pragma unroll
      for (int ni = 0; ni < 2; ++ni) {
        const int r = wn + ni * 16 + j;
        const int el = r * 64 + (koff ^ ((r & 7) << 3));
        bh[ni] = *reinterpret_cast<const s16x8*>(&Whi[el]);
        bl[ni] = *reinterpret_cast<const s16x8*>(&Wlo[el]);
      }
#pragma unroll
      for (int mi = 0; mi < 4; ++mi)
#pragma unroll
        for (int ni = 0; ni < 2; ++ni) {
          acc[mi][ni] = __builtin_amdgcn_mfma_f32_16x16x32_bf16(ah[mi], bh[ni], acc[mi][ni], 0, 0, 0);
          acc[mi][ni] = __builtin_amdgcn_mfma_f32_16x16x32_bf16(ah[mi], bl[ni], acc[mi][ni], 0, 0, 0);
          acc[mi][ni] = __builtin_amdgcn_mfma_f32_16x16x32_bf16(al[mi], bh[ni], acc[mi][ni], 0, 0, 0);
        }
    }
  }

  if (z < 2) {
#pragma unroll
    for (int ni = 0; ni < 2; ++ni) {
      const int colc = col0 + wn + ni * 16 + j;
      const float bj = Bp[colc];
      const int h = colc >> 6, hd = colc & 63;
#pragma unroll
      for (int mi = 0; mi < 4; ++mi)
#pragma unroll
        for (int r = 0; r < 4; ++r) {
          const int rowc = row0 + wm + mi * 16 + (g << 2) + r;
          const int b = rowc >> 11, t = rowc & 2047;
          const float v = (acc[mi][ni][r] + bj) * scale;
          unsigned short hh, ll; split2(v, hh, ll);
          const size_t off = (((size_t)b * NHEADS + h) * SEQ + t) * HD + hd;
          Ohi[off] = hh; Olo[off] = ll;
        }
    }
  } else {
    // V: transpose via LDS -> (B,H,Hd,T), hi only
    __syncthreads();
#pragma unroll
    for (int ni = 0; ni < 2; ++ni) {
      const int hdl = wn + ni * 16 + j;
      const float bj = Bp[col0 + hdl];
#pragma unroll
      for (int mi = 0; mi < 4; ++mi)
#pragma unroll
        for (int r = 0; r < 4; ++r) {
          const int lt = wm + mi * 16 + (g << 2) + r;
          const float v = acc[mi][ni][r] + bj;
          const int el = lt * 64 + (hdl ^ ((lt & 7) << 3));
          Xhi[el] = f2bf(v);
        }
    }
    __syncthreads();
    const int b = row0 >> 11, h = col0 >> 6;
    const int tbase = row0 & 2047;
#pragma unroll
    for (int c = 0; c < 4; ++c) {
      const int chunk = c * 256 + tid;
      const int hd = chunk >> 4;
      const int t0 = (chunk & 15) * 8;
      u16x8 vh;
#pragma unroll
      for (int i = 0; i < 8; ++i) {
        const int lt = t0 + i;
        const int el = lt * 64 + (hd ^ ((lt & 7) << 3));
        vh[i] = Xhi[el];
      }
      const size_t off = (((size_t)b * NHEADS + h) * HD + hd) * SEQ + tbase + t0;
      *reinterpret_cast<u16x8*>(&Vthi[off]) = vh;
    }
  }
}

// ---------------------------------------------------------------------------
// Output projection: out[r,j] = sum_k AO[r,k]*wo[j,k] + bo[j]
// ---------------------------------------------------------------------------
__global__ __launch_bounds__(256) void out_proj(
    const float* __restrict__ X, const float* __restrict__ W,
    const float* __restrict__ bias, float* __restrict__ out)
{
  __shared__ unsigned short Xhi[128 * 64], Xlo[128 * 64];
  __shared__ unsigned short Whi[64 * 64],  Wlo[64 * 64];

  const int tid  = threadIdx.x;
  const int lane = tid & 63;
  const int wave = tid >> 6;
  const int g = lane >> 4, j = lane & 15;
  const int wm = (wave >> 1) * 64;
  const int wn = (wave & 1) * 32;
  const int row0 = blockIdx.x * 128;
  const int col0 = blockIdx.y * 64;

  f32x4 acc[4][2];
#pragma unroll
  for (int mi = 0; mi < 4; ++mi)
#pragma unroll
    for (int ni = 0; ni < 2; ++ni) acc[mi][ni] = (f32x4)0.f;

  const int srow = tid >> 4;
  const int sk   = (tid & 15) * 4;

  for (int kt = 0; kt < FEAT; kt += 64) {
    f32x4 xr[8], wr[4];
#pragma unroll
    for (int p = 0; p < 8; ++p)
      xr[p] = *reinterpret_cast<const f32x4*>(&X[(size_t)(row0 + srow + p * 16) * FEAT + kt + sk]);
#pragma unroll
    for (int p = 0; p < 4; ++p)
      wr[p] = *reinterpret_cast<const f32x4*>(&W[(size_t)(col0 + srow + p * 16) * FEAT + kt + sk]);
    __syncthreads();
#pragma unroll
    for (int p = 0; p < 8; ++p) {
      const int r = srow + p * 16;
      const int el = r * 64 + (sk ^ ((r & 7) << 3));
#pragma unroll
      for (int i = 0; i < 4; ++i) { unsigned short hh, ll; split2(xr[p][i], hh, ll); Xhi[el + i] = hh; Xlo[el + i] = ll; }
    }
#pragma unroll
    for (int p = 0; p < 4; ++p) {
      const int r = srow + p * 16;
      const int el = r * 64 + (sk ^ ((r & 7) << 3));
#pragma unroll
      for (int i = 0; i < 4; ++i) { unsigned short hh, ll; split2(wr[p][i], hh, ll); Whi[el + i] = hh; Wlo[el + i] = ll; }
    }
    __syncthreads();

#pragma unroll
    for (int c = 0; c < 2; ++c) {
      const int koff = c * 32 + g * 8;
      s16x8 ah[4], al[4], bh[2], bl[2];
#pragma unroll
      for (int mi = 0; mi < 4; ++mi) {
        const int r = wm + mi * 16 + j;
        const int el = r * 64 + (koff ^ ((r & 7) << 3));
        ah[mi] = *reinterpret_cast<const s16x8*>(&Xhi[el]);
        al[mi] = *reinterpret_cast<const s16x8*>(&Xlo[el]);
      }
#pragma unroll
      for (int ni = 0; ni < 2; ++ni) {
        const int r = wn + ni * 16 + j;
        const int el = r * 64 + (koff ^ ((r & 7) << 3));
        bh[ni] = *reinterpret_cast<const s16x8*>(&Whi[el]);
        bl[ni] = *reinterpret_cast<const s16x8*>(&Wlo[el]);
      }
#pragma unroll
      for (int mi = 0; mi < 4; ++mi)
#pragma unroll
        for (int ni = 0; ni < 2; ++ni) {
          acc[mi][ni] = __builtin_amdgcn_mfma_f32_16x16x32_bf16(ah[mi], bh[ni], acc[mi][ni], 0, 0, 0);
          acc[mi][ni] = __builtin_amdgcn_mfma_f32_16x16x32_bf16(ah[mi], bl[ni], acc[mi][ni], 0, 0, 0);
          acc[mi][ni] = __builtin_amdgcn_mfma_f32_16x16x32_bf16(al[mi], bh[ni], acc[mi][ni], 0, 0, 0);
        }
    }
  }

#pragma unroll
  for (int ni = 0; ni < 2; ++ni) {
    const int colc = col0 + wn + ni * 16 + j;
    const float bj = bias[colc];
#pragma unroll
    for (int mi = 0; mi < 4; ++mi)
#pragma unroll
      for (int r = 0; r < 4; ++r) {
        const int rowc = row0 + wm + mi * 16 + (g << 2) + r;
        out[(size_t)rowc * FEAT + colc] = acc[mi][ni][r] + bj;
      }
  }
}

// ---------------------------------------------------------------------------
// Flash attention: 2-phase LDS pipeline (global_load_lds), KVBLK=64 staged as
// two stacked 32-key sub-tiles. QK^T = 3-MFMA split; PV = hi-only P and V
// (diffuse-attention error ~1e-4, within budget). Deferred-l softmax,
// conditional pm swap, 4-bpermute P exchange.
// Block = 4 waves x 32 q = 128 q. Grid 512 (XCD-swizzled).
// ---------------------------------------------------------------------------
__global__ __launch_bounds__(256, 2) void attn_pipe(
    const unsigned short* __restrict__ Qhi, const unsigned short* __restrict__ Qlo,
    const unsigned short* __restrict__ Khi, const unsigned short* __restrict__ Klo,
    const unsigned short* __restrict__ Vthi,
    float* __restrict__ AO)
{
  // per sub-tile (2048 u16): K [32 key][8 slot16], slot = s ^ (key&7)
  //                          V [32 row][8 slot16]: hd = row + (s>>2)*32,
  //                            keys = (s&3)*8..+8; stored s ^= (row&7)
  __shared__ unsigned short Kh_s[2][4096];
  __shared__ unsigned short Kl_s[2][4096];
  __shared__ unsigned short Vh_s[2][4096];
  __shared__ float bcast[4][32];

  const int tid = threadIdx.x, lane = tid & 63, wave = tid >> 6;
  const int hfl = lane >> 5;
  const int l31 = lane & 31;
  const bool lo = (hfl == 0);

  const int bid = blockIdx.x;
  const int swz = (bid & 7) * 64 + (bid >> 3);
  const int qt  = swz & 15;
  const int bh  = swz >> 4;
  const int b = bh >> 3, h = bh & 7;

  const int q0 = qt * 128 + wave * 32;
  const size_t kvbase = (size_t)bh * SEQ * HD;

  // Q B-fragments (col=q=lane&31, k=hd), pre-scaled by 1/8
  s16x8 qh[4], ql[4];
  {
    const size_t qoff = kvbase + (size_t)(q0 + l31) * HD + hfl * 8;
#pragma unroll
    for (int c = 0; c < 4; ++c) {
      qh[c] = *reinterpret_cast<const s16x8*>(&Qhi[qoff + c * 16]);
      ql[c] = *reinterpret_cast<const s16x8*>(&Qlo[qoff + c * 16]);
    }
  }

  f32x16 oacc0 = (f32x16)0.f, oacc1 = (f32x16)0.f;
  float m = -INFINITY, lsum = 0.f;

  // ---- staging source addresses (inverse-swizzled global) ----
  const int ck  = tid >> 3;
  const int ksl = (tid & 7) ^ (ck & 7);
  const unsigned short* sKh = Khi + kvbase + (size_t)ck * HD + ksl * 8;
  const unsigned short* sKl = Klo + kvbase + (size_t)ck * HD + ksl * 8;
  const int vr  = tid >> 3;
  const int vsl = (tid & 7) ^ (vr & 7);
  const int vhd = vr + (vsl >> 2) * 32;
  const int vk0 = (vsl & 3) * 8;
  const unsigned short* sVh = Vthi + kvbase + (size_t)vhd * SEQ + vk0;
  const int wq = wave * 512;

  const int krow = l31 * 64;
  const int ksw  = l31 & 7;

  // prologue: stage tile 0 (keys 0..63 = two 32-key sub-tiles)
  glds16(sKh,            &Kh_s[0][wq]);
  glds16(sKh + 32 * HD,  &Kh_s[0][2048 + wq]);
  glds16(sKl,            &Kl_s[0][wq]);
  glds16(sKl + 32 * HD,  &Kl_s[0][2048 + wq]);
  glds16(sVh,            &Vh_s[0][wq]);
  glds16(sVh + 32,       &Vh_s[0][2048 + wq]);
  asm volatile("s_waitcnt vmcnt(0)" ::: "memory");
  __syncthreads();

  int cur = 0;
  for (int t = 0; t < SEQ / 64; ++t) {
    if (t + 1 < SEQ / 64) {
      const size_t ko = (size_t)(t + 1) * 64 * HD;
      const int    vo = (t + 1) * 64;
      glds16(sKh + ko,           &Kh_s[cur ^ 1][wq]);
      glds16(sKh + ko + 32 * HD, &Kh_s[cur ^ 1][2048 + wq]);
      glds16(sKl + ko,           &Kl_s[cur ^ 1][wq]);
      glds16(sKl + ko + 32 * HD, &Kl_s[cur ^ 1][2048 + wq]);
      glds16(sVh + vo,           &Vh_s[cur ^ 1][wq]);
      glds16(sVh + vo + 32,      &Vh_s[cur ^ 1][2048 + wq]);
    }
    __builtin_amdgcn_sched_barrier(0);

#pragma unroll
    for (int sub = 0; sub < 2; ++sub) {
      const int sb = sub * 2048;

      // ---- K fragments ----
      s16x8 KH[4], KL[4];
#pragma unroll
      for (int c = 0; c < 4; ++c) {
        const int idx = sb + krow + ((((c << 1) | hfl)) ^ ksw) * 8;
        KH[c] = *reinterpret_cast<const s16x8*>(&Kh_s[cur][idx]);
        KL[c] = *reinterpret_cast<const s16x8*>(&Kl_s[cur][idx]);
      }

      // ---- S^T = K Q^T (3-MFMA split) ----
      f32x16 st = (f32x16)0.f;
      __builtin_amdgcn_s_setprio(1);
#pragma unroll
      for (int c = 0; c < 4; ++c) {
        st = __builtin_amdgcn_mfma_f32_32x32x16_bf16(KH[c], qh[c], st, 0, 0, 0);
        st = __builtin_amdgcn_mfma_f32_32x32x16_bf16(KH[c], ql[c], st, 0, 0, 0);
        st = __builtin_amdgcn_mfma_f32_32x32x16_bf16(KL[c], qh[c], st, 0, 0, 0);
      }
      __builtin_amdgcn_s_setprio(0);

      // ---- V fragments (hi only) ----
      s16x8 V0h[2], V1h[2];
#pragma unroll
      for (int c = 0; c < 2; ++c) {
        const int i0 = sb + krow + ((((c << 1) | hfl)) ^ ksw) * 8;       // hd=l31
        const int i1 = sb + krow + (((4 | (c << 1) | hfl)) ^ ksw) * 8;   // hd=l31+32
        V0h[c] = *reinterpret_cast<const s16x8*>(&Vh_s[cur][i0]);
        V1h[c] = *reinterpret_cast<const s16x8*>(&Vh_s[cur][i1]);
      }

      // ---- per-half tile max; cross-half swap only on trigger ----
      float pm = fmaxf(
          fmaxf(fmaxf(fmaxf(st[0], st[1]), fmaxf(st[2], st[3])),
                fmaxf(fmaxf(st[4], st[5]), fmaxf(st[6], st[7]))),
          fmaxf(fmaxf(fmaxf(st[8], st[9]), fmaxf(st[10], st[11])),
                fmaxf(fmaxf(st[12], st[13]), fmaxf(st[14], st[15]))));

      if (__any(pm > m + 8.f)) {
        const float pmf  = fmaxf(pm, __shfl_xor(pm, 32));
        const float mnew = fmaxf(m, pmf);
        const float corr = __expf(m - mnew);
        m = mnew; lsum *= corr;
        if (lane < 32) bcast[wave][l31] = corr;
        f32x4 c4[4];
#pragma unroll
        for (int rq = 0; rq < 4; ++rq)
          c4[rq] = *reinterpret_cast<const f32x4*>(&bcast[wave][rq * 8 + hfl * 4]);
#pragma unroll
        for (int r = 0; r < 16; ++r) {
          const float cc = c4[r >> 2][r & 3];
          oacc0[r] *= cc; oacc1[r] *= cc;
        }
      }

      // ---- p = exp(s - m); per-half partial denominator ----
#pragma unroll
      for (int r = 0; r < 16; ++r) st[r] = __expf(st[r] - m);
      {
        float s0 = (st[0] + st[1]) + (st[2] + st[3]);
        float s1 = (st[4] + st[5]) + (st[6] + st[7]);
        float s2 = (st[8] + st[9]) + (st[10] + st[11]);
        float s3 = (st[12] + st[13]) + (st[14] + st[15]);
        lsum += (s0 + s1) + (s2 + s3);
      }

      // ---- pack P hi only; 4-bpermute payload-merged exchange ----
      unsigned int wh[8];
#pragma unroll
      for (int p = 0; p < 8; ++p) {
        const unsigned int h0 = f2bf(st[2 * p]);
        const unsigned int h1 = f2bf(st[2 * p + 1]);
        wh[p] = h0 | (h1 << 16);
      }
      unsigned int xh[4];
      xh[0] = (unsigned int)__shfl_xor((int)(lo ? wh[2] : wh[0]), 32);
      xh[1] = (unsigned int)__shfl_xor((int)(lo ? wh[3] : wh[1]), 32);
      xh[2] = (unsigned int)__shfl_xor((int)(lo ? wh[6] : wh[4]), 32);
      xh[3] = (unsigned int)__shfl_xor((int)(lo ? wh[7] : wh[5]), 32);
      const s16x8 pa0h = __builtin_bit_cast(s16x8, (u32x4){
          lo ? wh[0] : xh[0], lo ? wh[1] : xh[1], lo ? xh[0] : wh[2], lo ? xh[1] : wh[3]});
      const s16x8 pa1h = __builtin_bit_cast(s16x8, (u32x4){
          lo ? wh[4] : xh[2], lo ? wh[5] : xh[3], lo ? xh[2] : wh[6], lo ? xh[3] : wh[7]});

      // ---- O += P V (hi-only) ----
      __builtin_amdgcn_s_setprio(1);
      oacc0 = __builtin_amdgcn_mfma_f32_32x32x16_bf16(pa0h, V0h[0], oacc0, 0, 0, 0);
      oacc0 = __builtin_amdgcn_mfma_f32_32x32x16_bf16(pa1h, V0h[1], oacc0, 0, 0, 0);
      oacc1 = __builtin_amdgcn_mfma_f32_32x32x16_bf16(pa0h, V1h[0], oacc1, 0, 0, 0);
      oacc1 = __builtin_amdgcn_mfma_f32_32x32x16_bf16(pa1h, V1h[1], oacc1, 0, 0, 0);
      __builtin_amdgcn_s_setprio(0);
    }

    // staged next tile must land; all waves done reading cur
    asm volatile("s_waitcnt vmcnt(0)" ::: "memory");
    __syncthreads();
    cur ^= 1;
  }

  // ---- combine half-denominators, normalize, store ----
  const float lf = lsum + __shfl_xor(lsum, 32);
  if (lane < 32) bcast[wave][l31] = 1.f / lf;
  f32x4 i4[4];
#pragma unroll
  for (int rq = 0; rq < 4; ++rq)
    i4[rq] = *reinterpret_cast<const f32x4*>(&bcast[wave][rq * 8 + hfl * 4]);

#pragma unroll
  for (int r = 0; r < 16; ++r) {
    const int q = q0 + (r & 3) + 8 * (r >> 2) + 4 * hfl;
    const float inv = i4[r >> 2][r & 3];
    float* dst = &AO[((size_t)b * SEQ + q) * FEAT + h * HD + l31];
    dst[0]  = oacc0[r] * inv;
    dst[32] = oacc1[r] * inv;
  }
}

extern "C" void kernel_launch(void* const* d_in, const int* in_sizes, int n_in,
                              void* d_out, int out_size, void* d_ws, size_t ws_size,
                              hipStream_t stream) {
  const float* x_cur  = (const float*)d_in[0];
  const float* x_past = (const float*)d_in[1];
  const float* wq = (const float*)d_in[2];
  const float* bq = (const float*)d_in[3];
  const float* wk = (const float*)d_in[4];
  const float* bk = (const float*)d_in[5];
  const float* wv = (const float*)d_in[6];
  const float* bv = (const float*)d_in[7];
  const float* wo = (const float*)d_in[8];
  const float* bo = (const float*)d_in[9];
  float* out = (float*)d_out;

  const size_t n = (size_t)NROWS * FEAT;
  unsigned short* Qhi  = (unsigned short*)d_ws;
  unsigned short* Qlo  = Qhi + n;
  unsigned short* Khi  = Qhi + 2 * n;
  unsigned short* Klo  = Qhi + 3 * n;
  unsigned short* Vthi = Qhi + 4 * n;
  float* AO = (float*)(Qhi + 6 * n);

  dim3 block(256);
  dim3 gqkv(NROWS / 128, FEAT / 64, 3);
  qkv_proj<<<gqkv, block, 0, stream>>>(x_cur, x_past, wq, bq, wk, bk, wv, bv,
                                       Qhi, Qlo, Khi, Klo, Vthi);

  attn_pipe<<<dim3(512), block, 0, stream>>>(Qhi, Qlo, Khi, Klo, Vthi, AO);

  dim3 gout(NROWS / 128, FEAT / 64);
  out_proj<<<gout, block, 0, stream>>>(AO, wo, bo, out);
}

// Round 10
// 166.849 us; speedup vs baseline: 1.9620x; 1.0777x over previous
//
#include <hip/hip_runtime.h>
#include <math.h>

#define BATCH 4
#define SEQ 2048
#define FEAT 512
#define NHEADS 8
#define HD 64
#define NROWS (BATCH*SEQ)   // 8192
#define QSCALE 0.18033688011112042f   // log2(e)/8

typedef __attribute__((ext_vector_type(4)))  float f32x4;
typedef __attribute__((ext_vector_type(16))) float f32x16;
typedef __attribute__((ext_vector_type(8)))  short s16x8;
typedef __attribute__((ext_vector_type(8)))  unsigned short u16x8;
typedef __attribute__((ext_vector_type(4)))  unsigned int u32x4;
typedef __attribute__((ext_vector_type(2)))  unsigned int u32x2;

static __device__ __forceinline__ unsigned short f2bf(float x) {
  unsigned int u = __builtin_bit_cast(unsigned int, x);
  unsigned int r = (u + 0x7FFFu + ((u >> 16) & 1u)) >> 16;
  return (unsigned short)r;
}
static __device__ __forceinline__ float bf2f(unsigned short h) {
  unsigned int u = ((unsigned int)h) << 16;
  return __builtin_bit_cast(float, u);
}
static __device__ __forceinline__ void split2(float x, unsigned short& h, unsigned short& l) {
  h = f2bf(x);
  l = f2bf(x - bf2f(h));
}

// async global->LDS, 16B per lane; dest = wave-uniform base + lane*16
static __device__ __forceinline__ void glds16(const unsigned short* g, unsigned short* l) {
  __builtin_amdgcn_global_load_lds(
      (const __attribute__((address_space(1))) unsigned int*)g,
      (__attribute__((address_space(3))) unsigned int*)l,
      16, 0, 0);
}

// split f32x4 -> packed hi pair / lo pair u32s (cvt_pk RNE, same math as split2)
static __device__ __forceinline__ void split4_pk(f32x4 x, unsigned int& hp0, unsigned int& hp1,
                                                 unsigned int& lp0, unsigned int& lp1) {
  asm("v_cvt_pk_bf16_f32 %0, %1, %2" : "=v"(hp0) : "v"(x.x), "v"(x.y));
  asm("v_cvt_pk_bf16_f32 %0, %1, %2" : "=v"(hp1) : "v"(x.z), "v"(x.w));
  const float l0 = x.x - __builtin_bit_cast(float, hp0 << 16);
  const float l1 = x.y - __builtin_bit_cast(float, hp0 & 0xFFFF0000u);
  const float l2 = x.z - __builtin_bit_cast(float, hp1 << 16);
  const float l3 = x.w - __builtin_bit_cast(float, hp1 & 0xFFFF0000u);
  asm("v_cvt_pk_bf16_f32 %0, %1, %2" : "=v"(lp0) : "v"(l0), "v"(l1));
  asm("v_cvt_pk_bf16_f32 %0, %1, %2" : "=v"(lp1) : "v"(l2), "v"(l3));
}

// ---------------------------------------------------------------------------
// Pre-split the four weight matrices into bf16 hi/lo. Wsp layout per matrix m:
// hi at m*524288, lo at m*524288+262144. 512 blocks x 256 thr x 8 elems.
// ---------------------------------------------------------------------------
__global__ __launch_bounds__(256) void presplit_w(
    const float* __restrict__ wq, const float* __restrict__ wk,
    const float* __restrict__ wv, const float* __restrict__ wo,
    unsigned short* __restrict__ Wsp)
{
  const int mat = blockIdx.x >> 7;
  const int chunk = ((blockIdx.x & 127) * 256 + threadIdx.x) * 8;
  const float* src = (mat == 0) ? wq : (mat == 1) ? wk : (mat == 2) ? wv : wo;
  unsigned short* hi = Wsp + (size_t)mat * 524288;
  unsigned short* lo = hi + 262144;
  const f32x4 a = *reinterpret_cast<const f32x4*>(&src[chunk]);
  const f32x4 b = *reinterpret_cast<const f32x4*>(&src[chunk + 4]);
  u16x8 h8, l8;
#pragma unroll
  for (int i = 0; i < 4; ++i) { unsigned short hh, ll; split2(a[i], hh, ll); h8[i] = hh; l8[i] = ll; }
#pragma unroll
  for (int i = 0; i < 4; ++i) { unsigned short hh, ll; split2(b[i], hh, ll); h8[4 + i] = hh; l8[4 + i] = ll; }
  *reinterpret_cast<u16x8*>(&hi[chunk]) = h8;
  *reinterpret_cast<u16x8*>(&lo[chunk]) = l8;
}

// ---------------------------------------------------------------------------
// Fused QKV projection (W pre-split, staged via global_load_lds; X f32 split
// in-kernel with cvt_pk + vector LDS stores).
// z=0: Q (scale log2e/8) -> (B,H,T,Hd) hi/lo
// z=1: K -> (B,H,T,Hd) hi/lo ;  z=2: V -> (B,H,Hd,T) hi only (LDS transpose)
// ---------------------------------------------------------------------------
__global__ __launch_bounds__(256, 3) void qkv_proj(
    const float* __restrict__ xc, const float* __restrict__ xp,
    const unsigned short* __restrict__ Wsp,
    const float* __restrict__ bq, const float* __restrict__ bk,
    const float* __restrict__ bv,
    unsigned short* __restrict__ Qhi, unsigned short* __restrict__ Qlo,
    unsigned short* __restrict__ Khi, unsigned short* __restrict__ Klo,
    unsigned short* __restrict__ Vthi)
{
  __shared__ unsigned short Xhi[128 * 64], Xlo[128 * 64];
  __shared__ unsigned short Whi[64 * 64],  Wlo[64 * 64];

  const int z = blockIdx.z;
  const float* X = (z == 0) ? xc : xp;
  const unsigned short* Wh_g = Wsp + (size_t)z * 524288;
  const unsigned short* Wl_g = Wh_g + 262144;
  const float* Bp = (z == 0) ? bq : (z == 1) ? bk : bv;
  unsigned short* Ohi = (z == 0) ? Qhi : (z == 1) ? Khi : Vthi;
  unsigned short* Olo = (z == 0) ? Qlo : Klo;
  const float scale = (z == 0) ? QSCALE : 1.0f;

  const int tid  = threadIdx.x;
  const int lane = tid & 63;
  const int wave = tid >> 6;
  const int g = lane >> 4, j = lane & 15;
  const int wm = (wave >> 1) * 64;
  const int wn = (wave & 1) * 32;
  const int row0 = blockIdx.x * 128;
  const int col0 = blockIdx.y * 64;

  f32x4 acc[4][2];
#pragma unroll
  for (int mi = 0; mi < 4; ++mi)
#pragma unroll
    for (int ni = 0; ni < 2; ++ni) acc[mi][ni] = (f32x4)0.f;

  const int srow = tid >> 4;        // 0..15
  const int sk   = (tid & 15) * 4;  // 0..60

  // W glds source (per lane): row = wave*16 + c*8 + (lane>>3), slot p=lane&7,
  // logical kgroup = p ^ ((lane>>3)&7)
  const int wrow = wave * 16 + (lane >> 3);
  const int wkg  = (lane & 7) ^ ((lane >> 3) & 7);
  const unsigned short* srcWh = Wh_g + (size_t)(col0 + wrow) * FEAT + wkg * 8;
  const unsigned short* srcWl = Wl_g + (size_t)(col0 + wrow) * FEAT + wkg * 8;

  for (int kt = 0; kt < FEAT; kt += 64) {
    f32x4 xr[8];
#pragma unroll
    for (int p = 0; p < 8; ++p)
      xr[p] = *reinterpret_cast<const f32x4*>(&X[(size_t)(row0 + srow + p * 16) * FEAT + kt + sk]);
    __syncthreads();   // previous iteration's LDS reads done
    // W: 4 async DMA calls (hi c=0,1 ; lo c=0,1)
    glds16(srcWh + kt,        &Whi[(wave * 16) * 64]);
    glds16(srcWh + kt + 4096, &Whi[(wave * 16 + 8) * 64]);
    glds16(srcWl + kt,        &Wlo[(wave * 16) * 64]);
    glds16(srcWl + kt + 4096, &Wlo[(wave * 16 + 8) * 64]);
    // X: split + vector stores (overlaps W DMA latency)
#pragma unroll
    for (int p = 0; p < 8; ++p) {
      const int r = srow + p * 16;
      const int el = r * 64 + (sk ^ ((r & 7) << 3));
      unsigned int hp0, hp1, lp0, lp1;
      split4_pk(xr[p], hp0, hp1, lp0, lp1);
      *reinterpret_cast<u32x2*>(&Xhi[el]) = (u32x2){hp0, hp1};
      *reinterpret_cast<u32x2*>(&Xlo[el]) = (u32x2){lp0, lp1};
    }
    asm volatile("s_waitcnt vmcnt(0)" ::: "memory");
    __syncthreads();

#pragma unroll
    for (int c = 0; c < 2; ++c) {
      const int koff = c * 32 + g * 8;
      s16x8 ah[4], al[4], bh[2], bl[2];
#pragma unroll
      for (int mi = 0; mi < 4; ++mi) {
        const int r = wm + mi * 16 + j;
        const int el = r * 64 + (koff ^ ((r & 7) << 3));
        ah[mi] = *reinterpret_cast<const s16x8*>(&Xhi[el]);
        al[mi] = *reinterpret_cast<const s16x8*>(&Xlo[el]);
      }
#pragma unroll
      for (int ni = 0; ni < 2; ++ni) {
        const int r = wn + ni * 16 + j;
        const int el = r * 64 + (koff ^ ((r & 7) << 3));
        bh[ni] = *reinterpret_cast<const s16x8*>(&Whi[el]);
        bl[ni] = *reinterpret_cast<const s16x8*>(&Wlo[el]);
      }
#pragma unroll
      for (int mi = 0; mi < 4; ++mi)
#pragma unroll
        for (int ni = 0; ni < 2; ++ni) {
          acc[mi][ni] = __builtin_amdgcn_mfma_f32_16x16x32_bf16(ah[mi], bh[ni], acc[mi][ni], 0, 0, 0);
          acc[mi][ni] = __builtin_amdgcn_mfma_f32_16x16x32_bf16(ah[mi], bl[ni], acc[mi][ni], 0, 0, 0);
          acc[mi][ni] = __builtin_amdgcn_mfma_f32_16x16x32_bf16(al[mi], bh[ni], acc[mi][ni], 0, 0, 0);
        }
    }
  }

  if (z < 2) {
#pragma unroll
    for (int ni = 0; ni < 2; ++ni) {
      const int colc = col0 + wn + ni * 16 + j;
      const float bj = Bp[colc];
      const int h = colc >> 6, hd = colc & 63;
#pragma unroll
      for (int mi = 0; mi < 4; ++mi)
#pragma unroll
        for (int r = 0; r < 4; ++r) {
          const int rowc = row0 + wm + mi * 16 + (g << 2) + r;
          const int b = rowc >> 11, t = rowc & 2047;
          const float v = (acc[mi][ni][r] + bj) * scale;
          unsigned short hh, ll; split2(v, hh, ll);
          const size_t off = (((size_t)b * NHEADS + h) * SEQ + t) * HD + hd;
          Ohi[off] = hh; Olo[off] = ll;
        }
    }
  } else {
    // V: transpose via LDS -> (B,H,Hd,T), hi only
    __syncthreads();
#pragma unroll
    for (int ni = 0; ni < 2; ++ni) {
      const int hdl = wn + ni * 16 + j;
      const float bj = Bp[col0 + hdl];
#pragma unroll
      for (int mi = 0; mi < 4; ++mi)
#pragma unroll
        for (int r = 0; r < 4; ++r) {
          const int lt = wm + mi * 16 + (g << 2) + r;
          const float v = acc[mi][ni][r] + bj;
          const int el = lt * 64 + (hdl ^ ((lt & 7) << 3));
          Xhi[el] = f2bf(v);
        }
    }
    __syncthreads();
    const int b = row0 >> 11, h = col0 >> 6;
    const int tbase = row0 & 2047;
#pragma unroll
    for (int c = 0; c < 4; ++c) {
      const int chunk = c * 256 + tid;
      const int hd = chunk >> 4;
      const int t0 = (chunk & 15) * 8;
      u16x8 vh;
#pragma unroll
      for (int i = 0; i < 8; ++i) {
        const int lt = t0 + i;
        const int el = lt * 64 + (hd ^ ((lt & 7) << 3));
        vh[i] = Xhi[el];
      }
      const size_t off = (((size_t)b * NHEADS + h) * HD + hd) * SEQ + tbase + t0;
      *reinterpret_cast<u16x8*>(&Vthi[off]) = vh;
    }
  }
}

// ---------------------------------------------------------------------------
// Output projection: A = AO (pre-split bf16 hi/lo, from attn), W = wo
// (pre-split). 100% global_load_lds staging - zero staging VALU.
// ---------------------------------------------------------------------------
__global__ __launch_bounds__(256, 3) void out_proj(
    const unsigned short* __restrict__ AOhi, const unsigned short* __restrict__ AOlo,
    const unsigned short* __restrict__ Woh,  const unsigned short* __restrict__ Wol,
    const float* __restrict__ bias, float* __restrict__ out)
{
  __shared__ unsigned short Xhi[128 * 64], Xlo[128 * 64];
  __shared__ unsigned short Whi[64 * 64],  Wlo[64 * 64];

  const int tid  = threadIdx.x;
  const int lane = tid & 63;
  const int wave = tid >> 6;
  const int g = lane >> 4, j = lane & 15;
  const int wm = (wave >> 1) * 64;
  const int wn = (wave & 1) * 32;
  const int row0 = blockIdx.x * 128;
  const int col0 = blockIdx.y * 64;

  f32x4 acc[4][2];
#pragma unroll
  for (int mi = 0; mi < 4; ++mi)
#pragma unroll
    for (int ni = 0; ni < 2; ++ni) acc[mi][ni] = (f32x4)0.f;

  const int arow = wave * 32 + (lane >> 3);
  const int akg  = (lane & 7) ^ ((lane >> 3) & 7);
  const unsigned short* srcAh = AOhi + (size_t)(row0 + arow) * FEAT + akg * 8;
  const unsigned short* srcAl = AOlo + (size_t)(row0 + arow) * FEAT + akg * 8;
  const int wrow = wave * 16 + (lane >> 3);
  const unsigned short* srcWh = Woh + (size_t)(col0 + wrow) * FEAT + akg * 8;
  const unsigned short* srcWl = Wol + (size_t)(col0 + wrow) * FEAT + akg * 8;

  for (int kt = 0; kt < FEAT; kt += 64) {
    __syncthreads();   // previous iteration's LDS reads done
#pragma unroll
    for (int c = 0; c < 4; ++c) {
      glds16(srcAh + kt + c * 4096, &Xhi[(wave * 32 + c * 8) * 64]);
      glds16(srcAl + kt + c * 4096, &Xlo[(wave * 32 + c * 8) * 64]);
    }
    glds16(srcWh + kt,        &Whi[(wave * 16) * 64]);
    glds16(srcWh + kt + 4096, &Whi[(wave * 16 + 8) * 64]);
    glds16(srcWl + kt,        &Wlo[(wave * 16) * 64]);
    glds16(srcWl + kt + 4096, &Wlo[(wave * 16 + 8) * 64]);
    asm volatile("s_waitcnt vmcnt(0)" ::: "memory");
    __syncthreads();

#pragma unroll
    for (int c = 0; c < 2; ++c) {
      const int koff = c * 32 + g * 8;
      s16x8 ah[4], al[4], bh[2], bl[2];
#pragma unroll
      for (int mi = 0; mi < 4; ++mi) {
        const int r = wm + mi * 16 + j;
        const int el = r * 64 + (koff ^ ((r & 7) << 3));
        ah[mi] = *reinterpret_cast<const s16x8*>(&Xhi[el]);
        al[mi] = *reinterpret_cast<const s16x8*>(&Xlo[el]);
      }
#pragma unroll
      for (int ni = 0; ni < 2; ++ni) {
        const int r = wn + ni * 16 + j;
        const int el = r * 64 + (koff ^ ((r & 7) << 3));
        bh[ni] = *reinterpret_cast<const s16x8*>(&Whi[el]);
        bl[ni] = *reinterpret_cast<const s16x8*>(&Wlo[el]);
      }
#pragma unroll
      for (int mi = 0; mi < 4; ++mi)
#pragma unroll
        for (int ni = 0; ni < 2; ++ni) {
          acc[mi][ni] = __builtin_amdgcn_mfma_f32_16x16x32_bf16(ah[mi], bh[ni], acc[mi][ni], 0, 0, 0);
          acc[mi][ni] = __builtin_amdgcn_mfma_f32_16x16x32_bf16(ah[mi], bl[ni], acc[mi][ni], 0, 0, 0);
          acc[mi][ni] = __builtin_amdgcn_mfma_f32_16x16x32_bf16(al[mi], bh[ni], acc[mi][ni], 0, 0, 0);
        }
    }
  }

#pragma unroll
  for (int ni = 0; ni < 2; ++ni) {
    const int colc = col0 + wn + ni * 16 + j;
    const float bj = bias[colc];
#pragma unroll
    for (int mi = 0; mi < 4; ++mi)
#pragma unroll
      for (int r = 0; r < 4; ++r) {
        const int rowc = row0 + wm + mi * 16 + (g << 2) + r;
        out[(size_t)rowc * FEAT + colc] = acc[mi][ni][r] + bj;
      }
  }
}

// ---------------------------------------------------------------------------
// Flash attention (r9 structure, exp2-domain softmax + cvt_pk pack, AO->bf16):
// 2-phase LDS pipeline (global_load_lds), KVBLK=64 as two 32-key sub-tiles,
// QK^T 3-MFMA split, PV hi-only, deferred-l, conditional pm swap.
// Block = 4 waves x 32 q = 128 q. Grid 512 (XCD-swizzled).
// ---------------------------------------------------------------------------
__global__ __launch_bounds__(256, 2) void attn_pipe(
    const unsigned short* __restrict__ Qhi, const unsigned short* __restrict__ Qlo,
    const unsigned short* __restrict__ Khi, const unsigned short* __restrict__ Klo,
    const unsigned short* __restrict__ Vthi,
    unsigned short* __restrict__ AOhi, unsigned short* __restrict__ AOlo)
{
  __shared__ unsigned short Kh_s[2][4096];
  __shared__ unsigned short Kl_s[2][4096];
  __shared__ unsigned short Vh_s[2][4096];
  __shared__ float bcast[4][32];

  const int tid = threadIdx.x, lane = tid & 63, wave = tid >> 6;
  const int hfl = lane >> 5;
  const int l31 = lane & 31;
  const bool lo = (hfl == 0);

  const int bid = blockIdx.x;
  const int swz = (bid & 7) * 64 + (bid >> 3);
  const int qt  = swz & 15;
  const int bh  = swz >> 4;
  const int b = bh >> 3, h = bh & 7;

  const int q0 = qt * 128 + wave * 32;
  const size_t kvbase = (size_t)bh * SEQ * HD;

  // Q B-fragments (pre-scaled by log2e/8 in proj)
  s16x8 qh[4], ql[4];
  {
    const size_t qoff = kvbase + (size_t)(q0 + l31) * HD + hfl * 8;
#pragma unroll
    for (int c = 0; c < 4; ++c) {
      qh[c] = *reinterpret_cast<const s16x8*>(&Qhi[qoff + c * 16]);
      ql[c] = *reinterpret_cast<const s16x8*>(&Qlo[qoff + c * 16]);
    }
  }

  f32x16 oacc0 = (f32x16)0.f, oacc1 = (f32x16)0.f;
  float m = -INFINITY, lsum = 0.f;

  const int ck  = tid >> 3;
  const int ksl = (tid & 7) ^ (ck & 7);
  const unsigned short* sKh = Khi + kvbase + (size_t)ck * HD + ksl * 8;
  const unsigned short* sKl = Klo + kvbase + (size_t)ck * HD + ksl * 8;
  const int vr  = tid >> 3;
  const int vsl = (tid & 7) ^ (vr & 7);
  const int vhd = vr + (vsl >> 2) * 32;
  const int vk0 = (vsl & 3) * 8;
  const unsigned short* sVh = Vthi + kvbase + (size_t)vhd * SEQ + vk0;
  const int wq = wave * 512;

  const int krow = l31 * 64;
  const int ksw  = l31 & 7;

  glds16(sKh,            &Kh_s[0][wq]);
  glds16(sKh + 32 * HD,  &Kh_s[0][2048 + wq]);
  glds16(sKl,            &Kl_s[0][wq]);
  glds16(sKl + 32 * HD,  &Kl_s[0][2048 + wq]);
  glds16(sVh,            &Vh_s[0][wq]);
  glds16(sVh + 32,       &Vh_s[0][2048 + wq]);
  asm volatile("s_waitcnt vmcnt(0)" ::: "memory");
  __syncthreads();

  int cur = 0;
  for (int t = 0; t < SEQ / 64; ++t) {
    if (t + 1 < SEQ / 64) {
      const size_t ko = (size_t)(t + 1) * 64 * HD;
      const int    vo = (t + 1) * 64;
      glds16(sKh + ko,           &Kh_s[cur ^ 1][wq]);
      glds16(sKh + ko + 32 * HD, &Kh_s[cur ^ 1][2048 + wq]);
      glds16(sKl + ko,           &Kl_s[cur ^ 1][wq]);
      glds16(sKl + ko + 32 * HD, &Kl_s[cur ^ 1][2048 + wq]);
      glds16(sVh + vo,           &Vh_s[cur ^ 1][wq]);
      glds16(sVh + vo + 32,      &Vh_s[cur ^ 1][2048 + wq]);
    }
    __builtin_amdgcn_sched_barrier(0);

#pragma unroll
    for (int sub = 0; sub < 2; ++sub) {
      const int sb = sub * 2048;

      s16x8 KH[4], KL[4];
#pragma unroll
      for (int c = 0; c < 4; ++c) {
        const int idx = sb + krow + ((((c << 1) | hfl)) ^ ksw) * 8;
        KH[c] = *reinterpret_cast<const s16x8*>(&Kh_s[cur][idx]);
        KL[c] = *reinterpret_cast<const s16x8*>(&Kl_s[cur][idx]);
      }

      f32x16 st = (f32x16)0.f;
      __builtin_amdgcn_s_setprio(1);
#pragma unroll
      for (int c = 0; c < 4; ++c) {
        st = __builtin_amdgcn_mfma_f32_32x32x16_bf16(KH[c], qh[c], st, 0, 0, 0);
        st = __builtin_amdgcn_mfma_f32_32x32x16_bf16(KH[c], ql[c], st, 0, 0, 0);
        st = __builtin_amdgcn_mfma_f32_32x32x16_bf16(KL[c], qh[c], st, 0, 0, 0);
      }
      __builtin_amdgcn_s_setprio(0);

      s16x8 V0h[2], V1h[2];
#pragma unroll
      for (int c = 0; c < 2; ++c) {
        const int i0 = sb + krow + ((((c << 1) | hfl)) ^ ksw) * 8;
        const int i1 = sb + krow + (((4 | (c << 1) | hfl)) ^ ksw) * 8;
        V0h[c] = *reinterpret_cast<const s16x8*>(&Vh_s[cur][i0]);
        V1h[c] = *reinterpret_cast<const s16x8*>(&Vh_s[cur][i1]);
      }

      float pm = fmaxf(
          fmaxf(fmaxf(fmaxf(st[0], st[1]), fmaxf(st[2], st[3])),
                fmaxf(fmaxf(st[4], st[5]), fmaxf(st[6], st[7]))),
          fmaxf(fmaxf(fmaxf(st[8], st[9]), fmaxf(st[10], st[11])),
                fmaxf(fmaxf(st[12], st[13]), fmaxf(st[14], st[15]))));

      if (__any(pm > m + 8.f)) {
        const float pmf  = fmaxf(pm, __shfl_xor(pm, 32));
        const float mnew = fmaxf(m, pmf);
        const float corr = exp2f(m - mnew);
        m = mnew; lsum *= corr;
        if (lane < 32) bcast[wave][l31] = corr;
        f32x4 c4[4];
#pragma unroll
        for (int rq = 0; rq < 4; ++rq)
          c4[rq] = *reinterpret_cast<const f32x4*>(&bcast[wave][rq * 8 + hfl * 4]);
#pragma unroll
        for (int r = 0; r < 16; ++r) {
          const float cc = c4[r >> 2][r & 3];
          oacc0[r] *= cc; oacc1[r] *= cc;
        }
      }

#pragma unroll
      for (int r = 0; r < 16; ++r) st[r] = exp2f(st[r] - m);
      {
        float s0 = (st[0] + st[1]) + (st[2] + st[3]);
        float s1 = (st[4] + st[5]) + (st[6] + st[7]);
        float s2 = (st[8] + st[9]) + (st[10] + st[11]);
        float s3 = (st[12] + st[13]) + (st[14] + st[15]);
        lsum += (s0 + s1) + (s2 + s3);
      }

      // ---- pack P hi via cvt_pk (1 instr / 2 vals); verified exchange ----
      unsigned int wh[8];
#pragma unroll
      for (int p = 0; p < 8; ++p)
        asm("v_cvt_pk_bf16_f32 %0, %1, %2" : "=v"(wh[p]) : "v"(st[2 * p]), "v"(st[2 * p + 1]));
      unsigned int xh[4];
      xh[0] = (unsigned int)__shfl_xor((int)(lo ? wh[2] : wh[0]), 32);
      xh[1] = (unsigned int)__shfl_xor((int)(lo ? wh[3] : wh[1]), 32);
      xh[2] = (unsigned int)__shfl_xor((int)(lo ? wh[6] : wh[4]), 32);
      xh[3] = (unsigned int)__shfl_xor((int)(lo ? wh[7] : wh[5]), 32);
      const s16x8 pa0h = __builtin_bit_cast(s16x8, (u32x4){
          lo ? wh[0] : xh[0], lo ? wh[1] : xh[1], lo ? xh[0] : wh[2], lo ? xh[1] : wh[3]});
      const s16x8 pa1h = __builtin_bit_cast(s16x8, (u32x4){
          lo ? wh[4] : xh[2], lo ? wh[5] : xh[3], lo ? xh[2] : wh[6], lo ? xh[3] : wh[7]});

      __builtin_amdgcn_s_setprio(1);
      oacc0 = __builtin_amdgcn_mfma_f32_32x32x16_bf16(pa0h, V0h[0], oacc0, 0, 0, 0);
      oacc0 = __builtin_amdgcn_mfma_f32_32x32x16_bf16(pa1h, V0h[1], oacc0, 0, 0, 0);
      oacc1 = __builtin_amdgcn_mfma_f32_32x32x16_bf16(pa0h, V1h[0], oacc1, 0, 0, 0);
      oacc1 = __builtin_amdgcn_mfma_f32_32x32x16_bf16(pa1h, V1h[1], oacc1, 0, 0, 0);
      __builtin_amdgcn_s_setprio(0);
    }

    asm volatile("s_waitcnt vmcnt(0)" ::: "memory");
    __syncthreads();
    cur ^= 1;
  }

  // ---- combine half-denominators, normalize, store AO as bf16 hi/lo ----
  const float lf = lsum + __shfl_xor(lsum, 32);
  if (lane < 32) bcast[wave][l31] = 1.f / lf;
  f32x4 i4[4];
#pragma unroll
  for (int rq = 0; rq < 4; ++rq)
    i4[rq] = *reinterpret_cast<const f32x4*>(&bcast[wave][rq * 8 + hfl * 4]);

#pragma unroll
  for (int r = 0; r < 16; ++r) {
    const int q = q0 + (r & 3) + 8 * (r >> 2) + 4 * hfl;
    const float inv = i4[r >> 2][r & 3];
    const size_t idx = ((size_t)b * SEQ + q) * FEAT + h * HD + l31;
    unsigned short hh, ll;
    split2(oacc0[r] * inv, hh, ll);
    AOhi[idx] = hh; AOlo[idx] = ll;
    split2(oacc1[r] * inv, hh, ll);
    AOhi[idx + 32] = hh; AOlo[idx + 32] = ll;
  }
}

extern "C" void kernel_launch(void* const* d_in, const int* in_sizes, int n_in,
                              void* d_out, int out_size, void* d_ws, size_t ws_size,
                              hipStream_t stream) {
  const float* x_cur  = (const float*)d_in[0];
  const float* x_past = (const float*)d_in[1];
  const float* wq = (const float*)d_in[2];
  const float* bq = (const float*)d_in[3];
  const float* wk = (const float*)d_in[4];
  const float* bk = (const float*)d_in[5];
  const float* wv = (const float*)d_in[6];
  const float* bv = (const float*)d_in[7];
  const float* wo = (const float*)d_in[8];
  const float* bo = (const float*)d_in[9];
  float* out = (float*)d_out;

  const size_t n = (size_t)NROWS * FEAT;   // 4,194,304
  unsigned short* Qhi  = (unsigned short*)d_ws;
  unsigned short* Qlo  = Qhi + n;
  unsigned short* Khi  = Qhi + 2 * n;
  unsigned short* Klo  = Qhi + 3 * n;
  unsigned short* Vthi = Qhi + 4 * n;
  unsigned short* Wsp  = Qhi + 5 * n;      // 2,097,152 u16 used (fits gap)
  unsigned short* AOhi = Qhi + 6 * n;
  unsigned short* AOlo = Qhi + 7 * n;      // ends at 8n u16 = 16n bytes

  dim3 block(256);
  presplit_w<<<dim3(512), block, 0, stream>>>(wq, wk, wv, wo, Wsp);

  dim3 gqkv(NROWS / 128, FEAT / 64, 3);
  qkv_proj<<<gqkv, block, 0, stream>>>(x_cur, x_past, Wsp, bq, bk, bv,
                                       Qhi, Qlo, Khi, Klo, Vthi);

  attn_pipe<<<dim3(512), block, 0, stream>>>(Qhi, Qlo, Khi, Klo, Vthi, AOhi, AOlo);

  dim3 gout(NROWS / 128, FEAT / 64);
  out_proj<<<gout, block, 0, stream>>>(AOhi, AOlo, Wsp + 3 * 524288,
                                       Wsp + 3 * 524288 + 262144, bo, out);
}

// Round 11
// 149.016 us; speedup vs baseline: 2.1968x; 1.1197x over previous
//
#include <hip/hip_runtime.h>
#include <math.h>

#define BATCH 4
#define SEQ 2048
#define FEAT 512
#define NHEADS 8
#define HD 64
#define NROWS (BATCH*SEQ)   // 8192
#define QSCALE 0.18033688011112042f   // log2(e)/8

typedef __attribute__((ext_vector_type(4)))  float f32x4;
typedef __attribute__((ext_vector_type(16))) float f32x16;
typedef __attribute__((ext_vector_type(8)))  short s16x8;
typedef __attribute__((ext_vector_type(8)))  unsigned short u16x8;
typedef __attribute__((ext_vector_type(4)))  unsigned int u32x4;
typedef __attribute__((ext_vector_type(2)))  unsigned int u32x2;

#if __has_builtin(__builtin_amdgcn_exp2f)
#define EX2(x) __builtin_amdgcn_exp2f(x)
#else
#define EX2(x) __expf((x) * 0.6931471805599453f)
#endif

static __device__ __forceinline__ unsigned short f2bf(float x) {
  unsigned int u = __builtin_bit_cast(unsigned int, x);
  unsigned int r = (u + 0x7FFFu + ((u >> 16) & 1u)) >> 16;
  return (unsigned short)r;
}
static __device__ __forceinline__ float bf2f(unsigned short h) {
  unsigned int u = ((unsigned int)h) << 16;
  return __builtin_bit_cast(float, u);
}
static __device__ __forceinline__ void split2(float x, unsigned short& h, unsigned short& l) {
  h = f2bf(x);
  l = f2bf(x - bf2f(h));
}

// async global->LDS, 16B per lane; dest = wave-uniform base + lane*16
static __device__ __forceinline__ void glds16(const unsigned short* g, unsigned short* l) {
  __builtin_amdgcn_global_load_lds(
      (const __attribute__((address_space(1))) unsigned int*)g,
      (__attribute__((address_space(3))) unsigned int*)l,
      16, 0, 0);
}

// split f32x4 -> packed hi pair / lo pair u32s (cvt_pk RNE, same math as split2)
static __device__ __forceinline__ void split4_pk(f32x4 x, unsigned int& hp0, unsigned int& hp1,
                                                 unsigned int& lp0, unsigned int& lp1) {
  asm("v_cvt_pk_bf16_f32 %0, %1, %2" : "=v"(hp0) : "v"(x.x), "v"(x.y));
  asm("v_cvt_pk_bf16_f32 %0, %1, %2" : "=v"(hp1) : "v"(x.z), "v"(x.w));
  const float l0 = x.x - __builtin_bit_cast(float, hp0 << 16);
  const float l1 = x.y - __builtin_bit_cast(float, hp0 & 0xFFFF0000u);
  const float l2 = x.z - __builtin_bit_cast(float, hp1 << 16);
  const float l3 = x.w - __builtin_bit_cast(float, hp1 & 0xFFFF0000u);
  asm("v_cvt_pk_bf16_f32 %0, %1, %2" : "=v"(lp0) : "v"(l0), "v"(l1));
  asm("v_cvt_pk_bf16_f32 %0, %1, %2" : "=v"(lp1) : "v"(l2), "v"(l3));
}

// ---------------------------------------------------------------------------
// Pre-split the four weight matrices into bf16 hi/lo.
// ---------------------------------------------------------------------------
__global__ __launch_bounds__(256) void presplit_w(
    const float* __restrict__ wq, const float* __restrict__ wk,
    const float* __restrict__ wv, const float* __restrict__ wo,
    unsigned short* __restrict__ Wsp)
{
  const int mat = blockIdx.x >> 7;
  const int chunk = ((blockIdx.x & 127) * 256 + threadIdx.x) * 8;
  const float* src = (mat == 0) ? wq : (mat == 1) ? wk : (mat == 2) ? wv : wo;
  unsigned short* hi = Wsp + (size_t)mat * 524288;
  unsigned short* lo = hi + 262144;
  const f32x4 a = *reinterpret_cast<const f32x4*>(&src[chunk]);
  const f32x4 b = *reinterpret_cast<const f32x4*>(&src[chunk + 4]);
  u16x8 h8, l8;
#pragma unroll
  for (int i = 0; i < 4; ++i) { unsigned short hh, ll; split2(a[i], hh, ll); h8[i] = hh; l8[i] = ll; }
#pragma unroll
  for (int i = 0; i < 4; ++i) { unsigned short hh, ll; split2(b[i], hh, ll); h8[4 + i] = hh; l8[4 + i] = ll; }
  *reinterpret_cast<u16x8*>(&hi[chunk]) = h8;
  *reinterpret_cast<u16x8*>(&lo[chunk]) = l8;
}

// ---------------------------------------------------------------------------
// Fused QKV projection. z=0: Q (scale log2e/8) -> (B,H,T,Hd) hi/lo
// z=1: K -> (B,H,T,Hd) hi/lo
// z=2: V -> (B,H,Hd,T') hi only, T' permuted per 16-group by
//      tau(p) = (p&~15) | ((p&3) + ((p>>2)&1)*8 + ((p>>3)&1)*4)
//      so attn's PV B-fragments match lane-local P order (no exchange).
// ---------------------------------------------------------------------------
__global__ __launch_bounds__(256, 3) void qkv_proj(
    const float* __restrict__ xc, const float* __restrict__ xp,
    const unsigned short* __restrict__ Wsp,
    const float* __restrict__ bq, const float* __restrict__ bk,
    const float* __restrict__ bv,
    unsigned short* __restrict__ Qhi, unsigned short* __restrict__ Qlo,
    unsigned short* __restrict__ Khi, unsigned short* __restrict__ Klo,
    unsigned short* __restrict__ Vthi)
{
  __shared__ unsigned short Xhi[128 * 64], Xlo[128 * 64];
  __shared__ unsigned short Whi[64 * 64],  Wlo[64 * 64];

  const int z = blockIdx.z;
  const float* X = (z == 0) ? xc : xp;
  const unsigned short* Wh_g = Wsp + (size_t)z * 524288;
  const unsigned short* Wl_g = Wh_g + 262144;
  const float* Bp = (z == 0) ? bq : (z == 1) ? bk : bv;
  unsigned short* Ohi = (z == 0) ? Qhi : (z == 1) ? Khi : Vthi;
  unsigned short* Olo = (z == 0) ? Qlo : Klo;
  const float scale = (z == 0) ? QSCALE : 1.0f;

  const int tid  = threadIdx.x;
  const int lane = tid & 63;
  const int wave = tid >> 6;
  const int g = lane >> 4, j = lane & 15;
  const int wm = (wave >> 1) * 64;
  const int wn = (wave & 1) * 32;
  const int row0 = blockIdx.x * 128;
  const int col0 = blockIdx.y * 64;

  f32x4 acc[4][2];
#pragma unroll
  for (int mi = 0; mi < 4; ++mi)
#pragma unroll
    for (int ni = 0; ni < 2; ++ni) acc[mi][ni] = (f32x4)0.f;

  const int srow = tid >> 4;        // 0..15
  const int sk   = (tid & 15) * 4;  // 0..60

  const int wrow = wave * 16 + (lane >> 3);
  const int wkg  = (lane & 7) ^ ((lane >> 3) & 7);
  const unsigned short* srcWh = Wh_g + (size_t)(col0 + wrow) * FEAT + wkg * 8;
  const unsigned short* srcWl = Wl_g + (size_t)(col0 + wrow) * FEAT + wkg * 8;

  for (int kt = 0; kt < FEAT; kt += 64) {
    f32x4 xr[8];
#pragma unroll
    for (int p = 0; p < 8; ++p)
      xr[p] = *reinterpret_cast<const f32x4*>(&X[(size_t)(row0 + srow + p * 16) * FEAT + kt + sk]);
    __syncthreads();   // previous iteration's LDS reads done
    glds16(srcWh + kt,        &Whi[(wave * 16) * 64]);
    glds16(srcWh + kt + 4096, &Whi[(wave * 16 + 8) * 64]);
    glds16(srcWl + kt,        &Wlo[(wave * 16) * 64]);
    glds16(srcWl + kt + 4096, &Wlo[(wave * 16 + 8) * 64]);
#pragma unroll
    for (int p = 0; p < 8; ++p) {
      const int r = srow + p * 16;
      const int el = r * 64 + (sk ^ ((r & 7) << 3));
      unsigned int hp0, hp1, lp0, lp1;
      split4_pk(xr[p], hp0, hp1, lp0, lp1);
      *reinterpret_cast<u32x2*>(&Xhi[el]) = (u32x2){hp0, hp1};
      *reinterpret_cast<u32x2*>(&Xlo[el]) = (u32x2){lp0, lp1};
    }
    asm volatile("s_waitcnt vmcnt(0)" ::: "memory");
    __syncthreads();

#pragma unroll
    for (int c = 0; c < 2; ++c) {
      const int koff = c * 32 + g * 8;
      s16x8 ah[4], al[4], bh[2], bl[2];
#pragma unroll
      for (int mi = 0; mi < 4; ++mi) {
        const int r = wm + mi * 16 + j;
        const int el = r * 64 + (koff ^ ((r & 7) << 3));
        ah[mi] = *reinterpret_cast<const s16x8*>(&Xhi[el]);
        al[mi] = *reinterpret_cast<const s16x8*>(&Xlo[el]);
      }
#pragma unroll
      for (int ni = 0; ni < 2; ++ni) {
        const int r = wn + ni * 16 + j;
        const int el = r * 64 + (koff ^ ((r & 7) << 3));
        bh[ni] = *reinterpret_cast<const s16x8*>(&Whi[el]);
        bl[ni] = *reinterpret_cast<const s16x8*>(&Wlo[el]);
      }
#pragma unroll
      for (int mi = 0; mi < 4; ++mi)
#pragma unroll
        for (int ni = 0; ni < 2; ++ni) {
          acc[mi][ni] = __builtin_amdgcn_mfma_f32_16x16x32_bf16(ah[mi], bh[ni], acc[mi][ni], 0, 0, 0);
          acc[mi][ni] = __builtin_amdgcn_mfma_f32_16x16x32_bf16(ah[mi], bl[ni], acc[mi][ni], 0, 0, 0);
          acc[mi][ni] = __builtin_amdgcn_mfma_f32_16x16x32_bf16(al[mi], bh[ni], acc[mi][ni], 0, 0, 0);
        }
    }
  }

  if (z < 2) {
#pragma unroll
    for (int ni = 0; ni < 2; ++ni) {
      const int colc = col0 + wn + ni * 16 + j;
      const float bj = Bp[colc];
      const int h = colc >> 6, hd = colc & 63;
#pragma unroll
      for (int mi = 0; mi < 4; ++mi)
#pragma unroll
        for (int r = 0; r < 4; ++r) {
          const int rowc = row0 + wm + mi * 16 + (g << 2) + r;
          const int b = rowc >> 11, t = rowc & 2047;
          const float v = (acc[mi][ni][r] + bj) * scale;
          unsigned short hh, ll; split2(v, hh, ll);
          const size_t off = (((size_t)b * NHEADS + h) * SEQ + t) * HD + hd;
          Ohi[off] = hh; Olo[off] = ll;
        }
    }
  } else {
    // V: transpose via LDS -> (B,H,Hd,T'), hi only, T-permuted
    __syncthreads();
#pragma unroll
    for (int ni = 0; ni < 2; ++ni) {
      const int hdl = wn + ni * 16 + j;
      const float bj = Bp[col0 + hdl];
#pragma unroll
      for (int mi = 0; mi < 4; ++mi)
#pragma unroll
        for (int r = 0; r < 4; ++r) {
          const int lt = wm + mi * 16 + (g << 2) + r;
          const float v = acc[mi][ni][r] + bj;
          const int el = lt * 64 + (hdl ^ ((lt & 7) << 3));
          Xhi[el] = f2bf(v);
        }
    }
    __syncthreads();
    const int b = row0 >> 11, h = col0 >> 6;
    const int tbase = row0 & 2047;
#pragma unroll
    for (int c = 0; c < 4; ++c) {
      const int chunk = c * 256 + tid;
      const int hd = chunk >> 4;
      const int t0 = (chunk & 15) * 8;
      u16x8 vh;
#pragma unroll
      for (int i = 0; i < 8; ++i) {
        const int p = t0 + i;
        const int lt = (p & ~15) | ((p & 3) + (((p >> 2) & 1) << 3) + (((p >> 3) & 1) << 2));
        const int el = lt * 64 + (hd ^ ((lt & 7) << 3));
        vh[i] = Xhi[el];
      }
      const size_t off = (((size_t)b * NHEADS + h) * HD + hd) * SEQ + tbase + t0;
      *reinterpret_cast<u16x8*>(&Vthi[off]) = vh;
    }
  }
}

// ---------------------------------------------------------------------------
// Output projection: 100% global_load_lds staging.
// ---------------------------------------------------------------------------
__global__ __launch_bounds__(256, 3) void out_proj(
    const unsigned short* __restrict__ AOhi, const unsigned short* __restrict__ AOlo,
    const unsigned short* __restrict__ Woh,  const unsigned short* __restrict__ Wol,
    const float* __restrict__ bias, float* __restrict__ out)
{
  __shared__ unsigned short Xhi[128 * 64], Xlo[128 * 64];
  __shared__ unsigned short Whi[64 * 64],  Wlo[64 * 64];

  const int tid  = threadIdx.x;
  const int lane = tid & 63;
  const int wave = tid >> 6;
  const int g = lane >> 4, j = lane & 15;
  const int wm = (wave >> 1) * 64;
  const int wn = (wave & 1) * 32;
  const int row0 = blockIdx.x * 128;
  const int col0 = blockIdx.y * 64;

  f32x4 acc[4][2];
#pragma unroll
  for (int mi = 0; mi < 4; ++mi)
#pragma unroll
    for (int ni = 0; ni < 2; ++ni) acc[mi][ni] = (f32x4)0.f;

  const int arow = wave * 32 + (lane >> 3);
  const int akg  = (lane & 7) ^ ((lane >> 3) & 7);
  const unsigned short* srcAh = AOhi + (size_t)(row0 + arow) * FEAT + akg * 8;
  const unsigned short* srcAl = AOlo + (size_t)(row0 + arow) * FEAT + akg * 8;
  const int wrow = wave * 16 + (lane >> 3);
  const unsigned short* srcWh = Woh + (size_t)(col0 + wrow) * FEAT + akg * 8;
  const unsigned short* srcWl = Wol + (size_t)(col0 + wrow) * FEAT + akg * 8;

  for (int kt = 0; kt < FEAT; kt += 64) {
    __syncthreads();
#pragma unroll
    for (int c = 0; c < 4; ++c) {
      glds16(srcAh + kt + c * 4096, &Xhi[(wave * 32 + c * 8) * 64]);
      glds16(srcAl + kt + c * 4096, &Xlo[(wave * 32 + c * 8) * 64]);
    }
    glds16(srcWh + kt,        &Whi[(wave * 16) * 64]);
    glds16(srcWh + kt + 4096, &Whi[(wave * 16 + 8) * 64]);
    glds16(srcWl + kt,        &Wlo[(wave * 16) * 64]);
    glds16(srcWl + kt + 4096, &Wlo[(wave * 16 + 8) * 64]);
    asm volatile("s_waitcnt vmcnt(0)" ::: "memory");
    __syncthreads();

#pragma unroll
    for (int c = 0; c < 2; ++c) {
      const int koff = c * 32 + g * 8;
      s16x8 ah[4], al[4], bh[2], bl[2];
#pragma unroll
      for (int mi = 0; mi < 4; ++mi) {
        const int r = wm + mi * 16 + j;
        const int el = r * 64 + (koff ^ ((r & 7) << 3));
        ah[mi] = *reinterpret_cast<const s16x8*>(&Xhi[el]);
        al[mi] = *reinterpret_cast<const s16x8*>(&Xlo[el]);
      }
#pragma unroll
      for (int ni = 0; ni < 2; ++ni) {
        const int r = wn + ni * 16 + j;
        const int el = r * 64 + (koff ^ ((r & 7) << 3));
        bh[ni] = *reinterpret_cast<const s16x8*>(&Whi[el]);
        bl[ni] = *reinterpret_cast<const s16x8*>(&Wlo[el]);
      }
#pragma unroll
      for (int mi = 0; mi < 4; ++mi)
#pragma unroll
        for (int ni = 0; ni < 2; ++ni) {
          acc[mi][ni] = __builtin_amdgcn_mfma_f32_16x16x32_bf16(ah[mi], bh[ni], acc[mi][ni], 0, 0, 0);
          acc[mi][ni] = __builtin_amdgcn_mfma_f32_16x16x32_bf16(ah[mi], bl[ni], acc[mi][ni], 0, 0, 0);
          acc[mi][ni] = __builtin_amdgcn_mfma_f32_16x16x32_bf16(al[mi], bh[ni], acc[mi][ni], 0, 0, 0);
        }
    }
  }

#pragma unroll
  for (int ni = 0; ni < 2; ++ni) {
    const int colc = col0 + wn + ni * 16 + j;
    const float bj = bias[colc];
#pragma unroll
    for (int mi = 0; mi < 4; ++mi)
#pragma unroll
      for (int r = 0; r < 4; ++r) {
        const int rowc = row0 + wm + mi * 16 + (g << 2) + r;
        out[(size_t)rowc * FEAT + colc] = acc[mi][ni][r] + bj;
      }
  }
}

// ---------------------------------------------------------------------------
// Flash attention: 2-phase LDS pipeline, KVBLK=64 (two 32-key sub-tiles),
// QK^T 3-MFMA split in TWO accumulator chains, PV hi-only with permuted-V
// (zero cross-lane in PV path), native exp2, deferred-l, conditional pm swap.
// ---------------------------------------------------------------------------
__global__ __launch_bounds__(256, 2) void attn_pipe(
    const unsigned short* __restrict__ Qhi, const unsigned short* __restrict__ Qlo,
    const unsigned short* __restrict__ Khi, const unsigned short* __restrict__ Klo,
    const unsigned short* __restrict__ Vthi,
    unsigned short* __restrict__ AOhi, unsigned short* __restrict__ AOlo)
{
  __shared__ unsigned short Kh_s[2][4096];
  __shared__ unsigned short Kl_s[2][4096];
  __shared__ unsigned short Vh_s[2][4096];
  __shared__ float bcast[4][32];

  const int tid = threadIdx.x, lane = tid & 63, wave = tid >> 6;
  const int hfl = lane >> 5;
  const int l31 = lane & 31;

  const int bid = blockIdx.x;
  const int swz = (bid & 7) * 64 + (bid >> 3);
  const int qt  = swz & 15;
  const int bh  = swz >> 4;
  const int b = bh >> 3, h = bh & 7;

  const int q0 = qt * 128 + wave * 32;
  const size_t kvbase = (size_t)bh * SEQ * HD;

  // Q B-fragments (pre-scaled by log2e/8 in proj)
  s16x8 qh[4], ql[4];
  {
    const size_t qoff = kvbase + (size_t)(q0 + l31) * HD + hfl * 8;
#pragma unroll
    for (int c = 0; c < 4; ++c) {
      qh[c] = *reinterpret_cast<const s16x8*>(&Qhi[qoff + c * 16]);
      ql[c] = *reinterpret_cast<const s16x8*>(&Qlo[qoff + c * 16]);
    }
  }

  f32x16 oacc0 = (f32x16)0.f, oacc1 = (f32x16)0.f;
  float m = -INFINITY, lsum = 0.f;

  const int ck  = tid >> 3;
  const int ksl = (tid & 7) ^ (ck & 7);
  const unsigned short* sKh = Khi + kvbase + (size_t)ck * HD + ksl * 8;
  const unsigned short* sKl = Klo + kvbase + (size_t)ck * HD + ksl * 8;
  const int vr  = tid >> 3;
  const int vsl = (tid & 7) ^ (vr & 7);
  const int vhd = vr + (vsl >> 2) * 32;
  const int vk0 = (vsl & 3) * 8;
  const unsigned short* sVh = Vthi + kvbase + (size_t)vhd * SEQ + vk0;
  const int wq = wave * 512;

  const int krow = l31 * 64;
  const int ksw  = l31 & 7;

  glds16(sKh,            &Kh_s[0][wq]);
  glds16(sKh + 32 * HD,  &Kh_s[0][2048 + wq]);
  glds16(sKl,            &Kl_s[0][wq]);
  glds16(sKl + 32 * HD,  &Kl_s[0][2048 + wq]);
  glds16(sVh,            &Vh_s[0][wq]);
  glds16(sVh + 32,       &Vh_s[0][2048 + wq]);
  asm volatile("s_waitcnt vmcnt(0)" ::: "memory");
  __syncthreads();

  int cur = 0;
  for (int t = 0; t < SEQ / 64; ++t) {
    if (t + 1 < SEQ / 64) {
      const size_t ko = (size_t)(t + 1) * 64 * HD;
      const int    vo = (t + 1) * 64;
      glds16(sKh + ko,           &Kh_s[cur ^ 1][wq]);
      glds16(sKh + ko + 32 * HD, &Kh_s[cur ^ 1][2048 + wq]);
      glds16(sKl + ko,           &Kl_s[cur ^ 1][wq]);
      glds16(sKl + ko + 32 * HD, &Kl_s[cur ^ 1][2048 + wq]);
      glds16(sVh + vo,           &Vh_s[cur ^ 1][wq]);
      glds16(sVh + vo + 32,      &Vh_s[cur ^ 1][2048 + wq]);
    }
    __builtin_amdgcn_sched_barrier(0);

#pragma unroll
    for (int sub = 0; sub < 2; ++sub) {
      const int sb = sub * 2048;

      s16x8 KH[4], KL[4];
#pragma unroll
      for (int c = 0; c < 4; ++c) {
        const int idx = sb + krow + ((((c << 1) | hfl)) ^ ksw) * 8;
        KH[c] = *reinterpret_cast<const s16x8*>(&Kh_s[cur][idx]);
        KL[c] = *reinterpret_cast<const s16x8*>(&Kl_s[cur][idx]);
      }

      // ---- S^T = K Q^T, two independent accumulator chains ----
      f32x16 stA = (f32x16)0.f, stB = (f32x16)0.f;
      __builtin_amdgcn_s_setprio(1);
#pragma unroll
      for (int c = 0; c < 2; ++c) {
        stA = __builtin_amdgcn_mfma_f32_32x32x16_bf16(KH[c], qh[c], stA, 0, 0, 0);
        stA = __builtin_amdgcn_mfma_f32_32x32x16_bf16(KH[c], ql[c], stA, 0, 0, 0);
        stA = __builtin_amdgcn_mfma_f32_32x32x16_bf16(KL[c], qh[c], stA, 0, 0, 0);
        stB = __builtin_amdgcn_mfma_f32_32x32x16_bf16(KH[2 + c], qh[2 + c], stB, 0, 0, 0);
        stB = __builtin_amdgcn_mfma_f32_32x32x16_bf16(KH[2 + c], ql[2 + c], stB, 0, 0, 0);
        stB = __builtin_amdgcn_mfma_f32_32x32x16_bf16(KL[2 + c], qh[2 + c], stB, 0, 0, 0);
      }
      __builtin_amdgcn_s_setprio(0);
      f32x16 st;
#pragma unroll
      for (int r = 0; r < 16; ++r) st[r] = stA[r] + stB[r];

      // ---- V fragments (hi only, permuted layout) ----
      s16x8 V0h[2], V1h[2];
#pragma unroll
      for (int c = 0; c < 2; ++c) {
        const int i0 = sb + krow + ((((c << 1) | hfl)) ^ ksw) * 8;
        const int i1 = sb + krow + (((4 | (c << 1) | hfl)) ^ ksw) * 8;
        V0h[c] = *reinterpret_cast<const s16x8*>(&Vh_s[cur][i0]);
        V1h[c] = *reinterpret_cast<const s16x8*>(&Vh_s[cur][i1]);
      }

      // ---- per-half tile max (max3-shaped tree) ----
      const float a0 = fmaxf(fmaxf(st[0], st[1]), st[2]);
      const float a1 = fmaxf(fmaxf(st[3], st[4]), st[5]);
      const float a2 = fmaxf(fmaxf(st[6], st[7]), st[8]);
      const float a3 = fmaxf(fmaxf(st[9], st[10]), st[11]);
      const float a4 = fmaxf(fmaxf(st[12], st[13]), st[14]);
      const float pm = fmaxf(fmaxf(fmaxf(a0, a1), a2),
                             fmaxf(fmaxf(a3, a4), st[15]));

      if (__any(pm > m + 8.f)) {
        const float pmf  = fmaxf(pm, __shfl_xor(pm, 32));
        const float mnew = fmaxf(m, pmf);
        const float corr = EX2(m - mnew);
        m = mnew; lsum *= corr;
        if (lane < 32) bcast[wave][l31] = corr;
        f32x4 c4[4];
#pragma unroll
        for (int rq = 0; rq < 4; ++rq)
          c4[rq] = *reinterpret_cast<const f32x4*>(&bcast[wave][rq * 8 + hfl * 4]);
#pragma unroll
        for (int r = 0; r < 16; ++r) {
          const float cc = c4[r >> 2][r & 3];
          oacc0[r] *= cc; oacc1[r] *= cc;
        }
      }

#pragma unroll
      for (int r = 0; r < 16; ++r) st[r] = EX2(st[r] - m);
      {
        float s0 = (st[0] + st[1]) + (st[2] + st[3]);
        float s1 = (st[4] + st[5]) + (st[6] + st[7]);
        float s2 = (st[8] + st[9]) + (st[10] + st[11]);
        float s3 = (st[12] + st[13]) + (st[14] + st[15]);
        lsum += (s0 + s1) + (s2 + s3);
      }

      // ---- pack P (lane-local order; permuted-V makes this the A-frag) ----
      unsigned int wh[8];
#pragma unroll
      for (int p = 0; p < 8; ++p)
        asm("v_cvt_pk_bf16_f32 %0, %1, %2" : "=v"(wh[p]) : "v"(st[2 * p]), "v"(st[2 * p + 1]));
      const s16x8 pa0h = __builtin_bit_cast(s16x8, (u32x4){wh[0], wh[1], wh[2], wh[3]});
      const s16x8 pa1h = __builtin_bit_cast(s16x8, (u32x4){wh[4], wh[5], wh[6], wh[7]});

      __builtin_amdgcn_s_setprio(1);
      oacc0 = __builtin_amdgcn_mfma_f32_32x32x16_bf16(pa0h, V0h[0], oacc0, 0, 0, 0);
      oacc0 = __builtin_amdgcn_mfma_f32_32x32x16_bf16(pa1h, V0h[1], oacc0, 0, 0, 0);
      oacc1 = __builtin_amdgcn_mfma_f32_32x32x16_bf16(pa0h, V1h[0], oacc1, 0, 0, 0);
      oacc1 = __builtin_amdgcn_mfma_f32_32x32x16_bf16(pa1h, V1h[1], oacc1, 0, 0, 0);
      __builtin_amdgcn_s_setprio(0);
    }

    asm volatile("s_waitcnt vmcnt(0)" ::: "memory");
    __syncthreads();
    cur ^= 1;
  }

  // ---- combine half-denominators, normalize, store AO as bf16 hi/lo ----
  const float lf = lsum + __shfl_xor(lsum, 32);
  if (lane < 32) bcast[wave][l31] = 1.f / lf;
  f32x4 i4[4];
#pragma unroll
  for (int rq = 0; rq < 4; ++rq)
    i4[rq] = *reinterpret_cast<const f32x4*>(&bcast[wave][rq * 8 + hfl * 4]);

#pragma unroll
  for (int r = 0; r < 16; ++r) {
    const int q = q0 + (r & 3) + 8 * (r >> 2) + 4 * hfl;
    const float inv = i4[r >> 2][r & 3];
    const size_t idx = ((size_t)b * SEQ + q) * FEAT + h * HD + l31;
    unsigned short hh, ll;
    split2(oacc0[r] * inv, hh, ll);
    AOhi[idx] = hh; AOlo[idx] = ll;
    split2(oacc1[r] * inv, hh, ll);
    AOhi[idx + 32] = hh; AOlo[idx + 32] = ll;
  }
}

extern "C" void kernel_launch(void* const* d_in, const int* in_sizes, int n_in,
                              void* d_out, int out_size, void* d_ws, size_t ws_size,
                              hipStream_t stream) {
  const float* x_cur  = (const float*)d_in[0];
  const float* x_past = (const float*)d_in[1];
  const float* wq = (const float*)d_in[2];
  const float* bq = (const float*)d_in[3];
  const float* wk = (const float*)d_in[4];
  const float* bk = (const float*)d_in[5];
  const float* wv = (const float*)d_in[6];
  const float* bv = (const float*)d_in[7];
  const float* wo = (const float*)d_in[8];
  const float* bo = (const float*)d_in[9];
  float* out = (float*)d_out;

  const size_t n = (size_t)NROWS * FEAT;   // 4,194,304
  unsigned short* Qhi  = (unsigned short*)d_ws;
  unsigned short* Qlo  = Qhi + n;
  unsigned short* Khi  = Qhi + 2 * n;
  unsigned short* Klo  = Qhi + 3 * n;
  unsigned short* Vthi = Qhi + 4 * n;
  unsigned short* Wsp  = Qhi + 5 * n;
  unsigned short* AOhi = Qhi + 6 * n;
  unsigned short* AOlo = Qhi + 7 * n;

  dim3 block(256);
  presplit_w<<<dim3(512), block, 0, stream>>>(wq, wk, wv, wo, Wsp);

  dim3 gqkv(NROWS / 128, FEAT / 64, 3);
  qkv_proj<<<gqkv, block, 0, stream>>>(x_cur, x_past, Wsp, bq, bk, bv,
                                       Qhi, Qlo, Khi, Klo, Vthi);

  attn_pipe<<<dim3(512), block, 0, stream>>>(Qhi, Qlo, Khi, Klo, Vthi, AOhi, AOlo);

  dim3 gout(NROWS / 128, FEAT / 64);
  out_proj<<<gout, block, 0, stream>>>(AOhi, AOlo, Wsp + 3 * 524288,
                                       Wsp + 3 * 524288 + 262144, bo, out);
}

// Round 12
// 148.624 us; speedup vs baseline: 2.2026x; 1.0026x over previous
//
#include <hip/hip_runtime.h>
#include <math.h>

#define BATCH 4
#define SEQ 2048
#define FEAT 512
#define NHEADS 8
#define HD 64
#define NROWS (BATCH*SEQ)   // 8192
#define QSCALE 0.18033688011112042f   // log2(e)/8

typedef __attribute__((ext_vector_type(4)))  float f32x4;
typedef __attribute__((ext_vector_type(16))) float f32x16;
typedef __attribute__((ext_vector_type(8)))  short s16x8;
typedef __attribute__((ext_vector_type(8)))  unsigned short u16x8;
typedef __attribute__((ext_vector_type(4)))  unsigned int u32x4;
typedef __attribute__((ext_vector_type(2)))  unsigned int u32x2;

#if __has_builtin(__builtin_amdgcn_exp2f)
#define EX2(x) __builtin_amdgcn_exp2f(x)
#else
#define EX2(x) __expf((x) * 0.6931471805599453f)
#endif

static __device__ __forceinline__ unsigned short f2bf(float x) {
  unsigned int u = __builtin_bit_cast(unsigned int, x);
  unsigned int r = (u + 0x7FFFu + ((u >> 16) & 1u)) >> 16;
  return (unsigned short)r;
}
static __device__ __forceinline__ float bf2f(unsigned short h) {
  unsigned int u = ((unsigned int)h) << 16;
  return __builtin_bit_cast(float, u);
}
static __device__ __forceinline__ void split2(float x, unsigned short& h, unsigned short& l) {
  h = f2bf(x);
  l = f2bf(x - bf2f(h));
}

// async global->LDS, 16B per lane; dest = wave-uniform base + lane*16
static __device__ __forceinline__ void glds16(const unsigned short* g, unsigned short* l) {
  __builtin_amdgcn_global_load_lds(
      (const __attribute__((address_space(1))) unsigned int*)g,
      (__attribute__((address_space(3))) unsigned int*)l,
      16, 0, 0);
}

// split f32x4 -> packed hi pair / lo pair u32s (cvt_pk RNE, same math as split2)
static __device__ __forceinline__ void split4_pk(f32x4 x, unsigned int& hp0, unsigned int& hp1,
                                                 unsigned int& lp0, unsigned int& lp1) {
  asm("v_cvt_pk_bf16_f32 %0, %1, %2" : "=v"(hp0) : "v"(x.x), "v"(x.y));
  asm("v_cvt_pk_bf16_f32 %0, %1, %2" : "=v"(hp1) : "v"(x.z), "v"(x.w));
  const float l0 = x.x - __builtin_bit_cast(float, hp0 << 16);
  const float l1 = x.y - __builtin_bit_cast(float, hp0 & 0xFFFF0000u);
  const float l2 = x.z - __builtin_bit_cast(float, hp1 << 16);
  const float l3 = x.w - __builtin_bit_cast(float, hp1 & 0xFFFF0000u);
  asm("v_cvt_pk_bf16_f32 %0, %1, %2" : "=v"(lp0) : "v"(l0), "v"(l1));
  asm("v_cvt_pk_bf16_f32 %0, %1, %2" : "=v"(lp1) : "v"(l2), "v"(l3));
}

// ---------------------------------------------------------------------------
// Pre-split the four weight matrices into bf16 hi/lo.
// ---------------------------------------------------------------------------
__global__ __launch_bounds__(256) void presplit_w(
    const float* __restrict__ wq, const float* __restrict__ wk,
    const float* __restrict__ wv, const float* __restrict__ wo,
    unsigned short* __restrict__ Wsp)
{
  const int mat = blockIdx.x >> 7;
  const int chunk = ((blockIdx.x & 127) * 256 + threadIdx.x) * 8;
  const float* src = (mat == 0) ? wq : (mat == 1) ? wk : (mat == 2) ? wv : wo;
  unsigned short* hi = Wsp + (size_t)mat * 524288;
  unsigned short* lo = hi + 262144;
  const f32x4 a = *reinterpret_cast<const f32x4*>(&src[chunk]);
  const f32x4 b = *reinterpret_cast<const f32x4*>(&src[chunk + 4]);
  u16x8 h8, l8;
#pragma unroll
  for (int i = 0; i < 4; ++i) { unsigned short hh, ll; split2(a[i], hh, ll); h8[i] = hh; l8[i] = ll; }
#pragma unroll
  for (int i = 0; i < 4; ++i) { unsigned short hh, ll; split2(b[i], hh, ll); h8[4 + i] = hh; l8[4 + i] = ll; }
  *reinterpret_cast<u16x8*>(&hi[chunk]) = h8;
  *reinterpret_cast<u16x8*>(&lo[chunk]) = l8;
}

// ---------------------------------------------------------------------------
// Fused QKV projection. z=0: Q (scale log2e/8) -> (B,H,T,Hd) hi/lo
// z=1: K -> (B,H,T,Hd) hi/lo
// z=2: V -> (B,H,Hd,T') hi only, T' permuted per 16-group by
//      tau(p) = (p&~15) | ((p&3) + ((p>>2)&1)*8 + ((p>>3)&1)*4)
// ---------------------------------------------------------------------------
__global__ __launch_bounds__(256, 3) void qkv_proj(
    const float* __restrict__ xc, const float* __restrict__ xp,
    const unsigned short* __restrict__ Wsp,
    const float* __restrict__ bq, const float* __restrict__ bk,
    const float* __restrict__ bv,
    unsigned short* __restrict__ Qhi, unsigned short* __restrict__ Qlo,
    unsigned short* __restrict__ Khi, unsigned short* __restrict__ Klo,
    unsigned short* __restrict__ Vthi)
{
  __shared__ unsigned short Xhi[128 * 64], Xlo[128 * 64];
  __shared__ unsigned short Whi[64 * 64],  Wlo[64 * 64];

  const int z = blockIdx.z;
  const float* X = (z == 0) ? xc : xp;
  const unsigned short* Wh_g = Wsp + (size_t)z * 524288;
  const unsigned short* Wl_g = Wh_g + 262144;
  const float* Bp = (z == 0) ? bq : (z == 1) ? bk : bv;
  unsigned short* Ohi = (z == 0) ? Qhi : (z == 1) ? Khi : Vthi;
  unsigned short* Olo = (z == 0) ? Qlo : Klo;
  const float scale = (z == 0) ? QSCALE : 1.0f;

  const int tid  = threadIdx.x;
  const int lane = tid & 63;
  const int wave = tid >> 6;
  const int g = lane >> 4, j = lane & 15;
  const int wm = (wave >> 1) * 64;
  const int wn = (wave & 1) * 32;
  const int row0 = blockIdx.x * 128;
  const int col0 = blockIdx.y * 64;

  f32x4 acc[4][2];
#pragma unroll
  for (int mi = 0; mi < 4; ++mi)
#pragma unroll
    for (int ni = 0; ni < 2; ++ni) acc[mi][ni] = (f32x4)0.f;

  const int srow = tid >> 4;        // 0..15
  const int sk   = (tid & 15) * 4;  // 0..60

  const int wrow = wave * 16 + (lane >> 3);
  const int wkg  = (lane & 7) ^ ((lane >> 3) & 7);
  const unsigned short* srcWh = Wh_g + (size_t)(col0 + wrow) * FEAT + wkg * 8;
  const unsigned short* srcWl = Wl_g + (size_t)(col0 + wrow) * FEAT + wkg * 8;

  for (int kt = 0; kt < FEAT; kt += 64) {
    f32x4 xr[8];
#pragma unroll
    for (int p = 0; p < 8; ++p)
      xr[p] = *reinterpret_cast<const f32x4*>(&X[(size_t)(row0 + srow + p * 16) * FEAT + kt + sk]);
    __syncthreads();   // previous iteration's LDS reads done
    glds16(srcWh + kt,        &Whi[(wave * 16) * 64]);
    glds16(srcWh + kt + 4096, &Whi[(wave * 16 + 8) * 64]);
    glds16(srcWl + kt,        &Wlo[(wave * 16) * 64]);
    glds16(srcWl + kt + 4096, &Wlo[(wave * 16 + 8) * 64]);
#pragma unroll
    for (int p = 0; p < 8; ++p) {
      const int r = srow + p * 16;
      const int el = r * 64 + (sk ^ ((r & 7) << 3));
      unsigned int hp0, hp1, lp0, lp1;
      split4_pk(xr[p], hp0, hp1, lp0, lp1);
      *reinterpret_cast<u32x2*>(&Xhi[el]) = (u32x2){hp0, hp1};
      *reinterpret_cast<u32x2*>(&Xlo[el]) = (u32x2){lp0, lp1};
    }
    asm volatile("s_waitcnt vmcnt(0)" ::: "memory");
    __syncthreads();

#pragma unroll
    for (int c = 0; c < 2; ++c) {
      const int koff = c * 32 + g * 8;
      s16x8 ah[4], al[4], bh[2], bl[2];
#pragma unroll
      for (int mi = 0; mi < 4; ++mi) {
        const int r = wm + mi * 16 + j;
        const int el = r * 64 + (koff ^ ((r & 7) << 3));
        ah[mi] = *reinterpret_cast<const s16x8*>(&Xhi[el]);
        al[mi] = *reinterpret_cast<const s16x8*>(&Xlo[el]);
      }
#pragma unroll
      for (int ni = 0; ni < 2; ++ni) {
        const int r = wn + ni * 16 + j;
        const int el = r * 64 + (koff ^ ((r & 7) << 3));
        bh[ni] = *reinterpret_cast<const s16x8*>(&Whi[el]);
        bl[ni] = *reinterpret_cast<const s16x8*>(&Wlo[el]);
      }
#pragma unroll
      for (int mi = 0; mi < 4; ++mi)
#pragma unroll
        for (int ni = 0; ni < 2; ++ni) {
          acc[mi][ni] = __builtin_amdgcn_mfma_f32_16x16x32_bf16(ah[mi], bh[ni], acc[mi][ni], 0, 0, 0);
          acc[mi][ni] = __builtin_amdgcn_mfma_f32_16x16x32_bf16(ah[mi], bl[ni], acc[mi][ni], 0, 0, 0);
          acc[mi][ni] = __builtin_amdgcn_mfma_f32_16x16x32_bf16(al[mi], bh[ni], acc[mi][ni], 0, 0, 0);
        }
    }
  }

  if (z < 2) {
#pragma unroll
    for (int ni = 0; ni < 2; ++ni) {
      const int colc = col0 + wn + ni * 16 + j;
      const float bj = Bp[colc];
      const int h = colc >> 6, hd = colc & 63;
#pragma unroll
      for (int mi = 0; mi < 4; ++mi)
#pragma unroll
        for (int r = 0; r < 4; ++r) {
          const int rowc = row0 + wm + mi * 16 + (g << 2) + r;
          const int b = rowc >> 11, t = rowc & 2047;
          const float v = (acc[mi][ni][r] + bj) * scale;
          unsigned short hh, ll; split2(v, hh, ll);
          const size_t off = (((size_t)b * NHEADS + h) * SEQ + t) * HD + hd;
          Ohi[off] = hh; Olo[off] = ll;
        }
    }
  } else {
    // V: transpose via LDS -> (B,H,Hd,T'), hi only, T-permuted
    __syncthreads();
#pragma unroll
    for (int ni = 0; ni < 2; ++ni) {
      const int hdl = wn + ni * 16 + j;
      const float bj = Bp[col0 + hdl];
#pragma unroll
      for (int mi = 0; mi < 4; ++mi)
#pragma unroll
        for (int r = 0; r < 4; ++r) {
          const int lt = wm + mi * 16 + (g << 2) + r;
          const float v = acc[mi][ni][r] + bj;
          const int el = lt * 64 + (hdl ^ ((lt & 7) << 3));
          Xhi[el] = f2bf(v);
        }
    }
    __syncthreads();
    const int b = row0 >> 11, h = col0 >> 6;
    const int tbase = row0 & 2047;
#pragma unroll
    for (int c = 0; c < 4; ++c) {
      const int chunk = c * 256 + tid;
      const int hd = chunk >> 4;
      const int t0 = (chunk & 15) * 8;
      u16x8 vh;
#pragma unroll
      for (int i = 0; i < 8; ++i) {
        const int p = t0 + i;
        const int lt = (p & ~15) | ((p & 3) + (((p >> 2) & 1) << 3) + (((p >> 3) & 1) << 2));
        const int el = lt * 64 + (hd ^ ((lt & 7) << 3));
        vh[i] = Xhi[el];
      }
      const size_t off = (((size_t)b * NHEADS + h) * HD + hd) * SEQ + tbase + t0;
      *reinterpret_cast<u16x8*>(&Vthi[off]) = vh;
    }
  }
}

// ---------------------------------------------------------------------------
// Output projection: 100% global_load_lds staging.
// ---------------------------------------------------------------------------
__global__ __launch_bounds__(256, 3) void out_proj(
    const unsigned short* __restrict__ AOhi, const unsigned short* __restrict__ AOlo,
    const unsigned short* __restrict__ Woh,  const unsigned short* __restrict__ Wol,
    const float* __restrict__ bias, float* __restrict__ out)
{
  __shared__ unsigned short Xhi[128 * 64], Xlo[128 * 64];
  __shared__ unsigned short Whi[64 * 64],  Wlo[64 * 64];

  const int tid  = threadIdx.x;
  const int lane = tid & 63;
  const int wave = tid >> 6;
  const int g = lane >> 4, j = lane & 15;
  const int wm = (wave >> 1) * 64;
  const int wn = (wave & 1) * 32;
  const int row0 = blockIdx.x * 128;
  const int col0 = blockIdx.y * 64;

  f32x4 acc[4][2];
#pragma unroll
  for (int mi = 0; mi < 4; ++mi)
#pragma unroll
    for (int ni = 0; ni < 2; ++ni) acc[mi][ni] = (f32x4)0.f;

  const int arow = wave * 32 + (lane >> 3);
  const int akg  = (lane & 7) ^ ((lane >> 3) & 7);
  const unsigned short* srcAh = AOhi + (size_t)(row0 + arow) * FEAT + akg * 8;
  const unsigned short* srcAl = AOlo + (size_t)(row0 + arow) * FEAT + akg * 8;
  const int wrow = wave * 16 + (lane >> 3);
  const unsigned short* srcWh = Woh + (size_t)(col0 + wrow) * FEAT + akg * 8;
  const unsigned short* srcWl = Wol + (size_t)(col0 + wrow) * FEAT + akg * 8;

  for (int kt = 0; kt < FEAT; kt += 64) {
    __syncthreads();
#pragma unroll
    for (int c = 0; c < 4; ++c) {
      glds16(srcAh + kt + c * 4096, &Xhi[(wave * 32 + c * 8) * 64]);
      glds16(srcAl + kt + c * 4096, &Xlo[(wave * 32 + c * 8) * 64]);
    }
    glds16(srcWh + kt,        &Whi[(wave * 16) * 64]);
    glds16(srcWh + kt + 4096, &Whi[(wave * 16 + 8) * 64]);
    glds16(srcWl + kt,        &Wlo[(wave * 16) * 64]);
    glds16(srcWl + kt + 4096, &Wlo[(wave * 16 + 8) * 64]);
    asm volatile("s_waitcnt vmcnt(0)" ::: "memory");
    __syncthreads();

#pragma unroll
    for (int c = 0; c < 2; ++c) {
      const int koff = c * 32 + g * 8;
      s16x8 ah[4], al[4], bh[2], bl[2];
#pragma unroll
      for (int mi = 0; mi < 4; ++mi) {
        const int r = wm + mi * 16 + j;
        const int el = r * 64 + (koff ^ ((r & 7) << 3));
        ah[mi] = *reinterpret_cast<const s16x8*>(&Xhi[el]);
        al[mi] = *reinterpret_cast<const s16x8*>(&Xlo[el]);
      }
#pragma unroll
      for (int ni = 0; ni < 2; ++ni) {
        const int r = wn + ni * 16 + j;
        const int el = r * 64 + (koff ^ ((r & 7) << 3));
        bh[ni] = *reinterpret_cast<const s16x8*>(&Whi[el]);
        bl[ni] = *reinterpret_cast<const s16x8*>(&Wlo[el]);
      }
#pragma unroll
      for (int mi = 0; mi < 4; ++mi)
#pragma unroll
        for (int ni = 0; ni < 2; ++ni) {
          acc[mi][ni] = __builtin_amdgcn_mfma_f32_16x16x32_bf16(ah[mi], bh[ni], acc[mi][ni], 0, 0, 0);
          acc[mi][ni] = __builtin_amdgcn_mfma_f32_16x16x32_bf16(ah[mi], bl[ni], acc[mi][ni], 0, 0, 0);
          acc[mi][ni] = __builtin_amdgcn_mfma_f32_16x16x32_bf16(al[mi], bh[ni], acc[mi][ni], 0, 0, 0);
        }
    }
  }

#pragma unroll
  for (int ni = 0; ni < 2; ++ni) {
    const int colc = col0 + wn + ni * 16 + j;
    const float bj = bias[colc];
#pragma unroll
    for (int mi = 0; mi < 4; ++mi)
#pragma unroll
      for (int r = 0; r < 4; ++r) {
        const int rowc = row0 + wm + mi * 16 + (g << 2) + r;
        out[(size_t)rowc * FEAT + colc] = acc[mi][ni][r] + bj;
      }
  }
}

// ---------------------------------------------------------------------------
// Flash attention: 3-buffer counted-vmcnt LDS pipeline (T4: vmcnt(6), never 0
// in main loop; per-wave vmcnt before shared barrier = m201 pattern).
// KVBLK=64 (two 32-key sub-tiles), QK^T 3-MFMA split in two chains, PV
// hi-only with permuted-V, native exp2, deferred-l, conditional pm swap.
// ---------------------------------------------------------------------------
__global__ __launch_bounds__(256, 2) void attn_pipe(
    const unsigned short* __restrict__ Qhi, const unsigned short* __restrict__ Qlo,
    const unsigned short* __restrict__ Khi, const unsigned short* __restrict__ Klo,
    const unsigned short* __restrict__ Vthi,
    unsigned short* __restrict__ AOhi, unsigned short* __restrict__ AOlo)
{
  __shared__ unsigned short Kh_s[3][4096];
  __shared__ unsigned short Kl_s[3][4096];
  __shared__ unsigned short Vh_s[3][4096];
  __shared__ float bcast[4][32];

  const int tid = threadIdx.x, lane = tid & 63, wave = tid >> 6;
  const int hfl = lane >> 5;
  const int l31 = lane & 31;

  const int bid = blockIdx.x;
  const int swz = (bid & 7) * 64 + (bid >> 3);
  const int qt  = swz & 15;
  const int bh  = swz >> 4;
  const int b = bh >> 3, h = bh & 7;

  const int q0 = qt * 128 + wave * 32;
  const size_t kvbase = (size_t)bh * SEQ * HD;

  // Q B-fragments (pre-scaled by log2e/8 in proj)
  s16x8 qh[4], ql[4];
  {
    const size_t qoff = kvbase + (size_t)(q0 + l31) * HD + hfl * 8;
#pragma unroll
    for (int c = 0; c < 4; ++c) {
      qh[c] = *reinterpret_cast<const s16x8*>(&Qhi[qoff + c * 16]);
      ql[c] = *reinterpret_cast<const s16x8*>(&Qlo[qoff + c * 16]);
    }
  }

  f32x16 oacc0 = (f32x16)0.f, oacc1 = (f32x16)0.f;
  float m = -INFINITY, lsum = 0.f;

  const int ck  = tid >> 3;
  const int ksl = (tid & 7) ^ (ck & 7);
  const unsigned short* sKh = Khi + kvbase + (size_t)ck * HD + ksl * 8;
  const unsigned short* sKl = Klo + kvbase + (size_t)ck * HD + ksl * 8;
  const int vr  = tid >> 3;
  const int vsl = (tid & 7) ^ (vr & 7);
  const int vhd = vr + (vsl >> 2) * 32;
  const int vk0 = (vsl & 3) * 8;
  const unsigned short* sVh = Vthi + kvbase + (size_t)vhd * SEQ + vk0;
  const int wq = wave * 512;

  const int krow = l31 * 64;
  const int ksw  = l31 & 7;

  // stage tile tt into buffer bi (6 glds per wave)
  auto stage = [&](int tt, int bi) {
    const size_t ko = (size_t)tt * 64 * HD;
    const int    vo = tt * 64;
    glds16(sKh + ko,           &Kh_s[bi][wq]);
    glds16(sKh + ko + 32 * HD, &Kh_s[bi][2048 + wq]);
    glds16(sKl + ko,           &Kl_s[bi][wq]);
    glds16(sKl + ko + 32 * HD, &Kl_s[bi][2048 + wq]);
    glds16(sVh + vo,           &Vh_s[bi][wq]);
    glds16(sVh + vo + 32,      &Vh_s[bi][2048 + wq]);
  };

  // prologue: two tiles in flight
  stage(0, 0);
  stage(1, 1);

  const int NT = SEQ / 64;   // 32
  int cur = 0;               // buffer of tile t
  for (int t = 0; t < NT; ++t) {
    // wait for tile t's loads only (t+1's stay in flight) — every wave does
    // this before the barrier, so the barrier guarantees buf[cur] complete.
    if (t < NT - 1) {
      asm volatile("s_waitcnt vmcnt(6)" ::: "memory");
    } else {
      asm volatile("s_waitcnt vmcnt(0)" ::: "memory");
    }
    __syncthreads();
    // stage t+2 (overwrites buf of t-1; all waves finished t-1 before this
    // barrier, so safe)
    if (t + 2 < NT) {
      int nb = cur + 2; if (nb >= 3) nb -= 3;
      stage(t + 2, nb);
    }
    __builtin_amdgcn_sched_barrier(0);

#pragma unroll
    for (int sub = 0; sub < 2; ++sub) {
      const int sb = sub * 2048;

      s16x8 KH[4], KL[4];
#pragma unroll
      for (int c = 0; c < 4; ++c) {
        const int idx = sb + krow + ((((c << 1) | hfl)) ^ ksw) * 8;
        KH[c] = *reinterpret_cast<const s16x8*>(&Kh_s[cur][idx]);
        KL[c] = *reinterpret_cast<const s16x8*>(&Kl_s[cur][idx]);
      }

      // ---- S^T = K Q^T, two independent accumulator chains ----
      f32x16 stA = (f32x16)0.f, stB = (f32x16)0.f;
      __builtin_amdgcn_s_setprio(1);
#pragma unroll
      for (int c = 0; c < 2; ++c) {
        stA = __builtin_amdgcn_mfma_f32_32x32x16_bf16(KH[c], qh[c], stA, 0, 0, 0);
        stA = __builtin_amdgcn_mfma_f32_32x32x16_bf16(KH[c], ql[c], stA, 0, 0, 0);
        stA = __builtin_amdgcn_mfma_f32_32x32x16_bf16(KL[c], qh[c], stA, 0, 0, 0);
        stB = __builtin_amdgcn_mfma_f32_32x32x16_bf16(KH[2 + c], qh[2 + c], stB, 0, 0, 0);
        stB = __builtin_amdgcn_mfma_f32_32x32x16_bf16(KH[2 + c], ql[2 + c], stB, 0, 0, 0);
        stB = __builtin_amdgcn_mfma_f32_32x32x16_bf16(KL[2 + c], qh[2 + c], stB, 0, 0, 0);
      }
      __builtin_amdgcn_s_setprio(0);
      f32x16 st;
#pragma unroll
      for (int r = 0; r < 16; ++r) st[r] = stA[r] + stB[r];

      // ---- V fragments (hi only, permuted layout) ----
      s16x8 V0h[2], V1h[2];
#pragma unroll
      for (int c = 0; c < 2; ++c) {
        const int i0 = sb + krow + ((((c << 1) | hfl)) ^ ksw) * 8;
        const int i1 = sb + krow + (((4 | (c << 1) | hfl)) ^ ksw) * 8;
        V0h[c] = *reinterpret_cast<const s16x8*>(&Vh_s[cur][i0]);
        V1h[c] = *reinterpret_cast<const s16x8*>(&Vh_s[cur][i1]);
      }

      // ---- per-half tile max (max3-shaped tree) ----
      const float a0 = fmaxf(fmaxf(st[0], st[1]), st[2]);
      const float a1 = fmaxf(fmaxf(st[3], st[4]), st[5]);
      const float a2 = fmaxf(fmaxf(st[6], st[7]), st[8]);
      const float a3 = fmaxf(fmaxf(st[9], st[10]), st[11]);
      const float a4 = fmaxf(fmaxf(st[12], st[13]), st[14]);
      const float pm = fmaxf(fmaxf(fmaxf(a0, a1), a2),
                             fmaxf(fmaxf(a3, a4), st[15]));

      if (__any(pm > m + 8.f)) {
        const float pmf  = fmaxf(pm, __shfl_xor(pm, 32));
        const float mnew = fmaxf(m, pmf);
        const float corr = EX2(m - mnew);
        m = mnew; lsum *= corr;
        if (lane < 32) bcast[wave][l31] = corr;
        f32x4 c4[4];
#pragma unroll
        for (int rq = 0; rq < 4; ++rq)
          c4[rq] = *reinterpret_cast<const f32x4*>(&bcast[wave][rq * 8 + hfl * 4]);
#pragma unroll
        for (int r = 0; r < 16; ++r) {
          const float cc = c4[r >> 2][r & 3];
          oacc0[r] *= cc; oacc1[r] *= cc;
        }
      }

#pragma unroll
      for (int r = 0; r < 16; ++r) st[r] = EX2(st[r] - m);
      {
        float s0 = (st[0] + st[1]) + (st[2] + st[3]);
        float s1 = (st[4] + st[5]) + (st[6] + st[7]);
        float s2 = (st[8] + st[9]) + (st[10] + st[11]);
        float s3 = (st[12] + st[13]) + (st[14] + st[15]);
        lsum += (s0 + s1) + (s2 + s3);
      }

      // ---- pack P (lane-local order; permuted-V makes this the A-frag) ----
      unsigned int wh[8];
#pragma unroll
      for (int p = 0; p < 8; ++p)
        asm("v_cvt_pk_bf16_f32 %0, %1, %2" : "=v"(wh[p]) : "v"(st[2 * p]), "v"(st[2 * p + 1]));
      const s16x8 pa0h = __builtin_bit_cast(s16x8, (u32x4){wh[0], wh[1], wh[2], wh[3]});
      const s16x8 pa1h = __builtin_bit_cast(s16x8, (u32x4){wh[4], wh[5], wh[6], wh[7]});

      __builtin_amdgcn_s_setprio(1);
      oacc0 = __builtin_amdgcn_mfma_f32_32x32x16_bf16(pa0h, V0h[0], oacc0, 0, 0, 0);
      oacc0 = __builtin_amdgcn_mfma_f32_32x32x16_bf16(pa1h, V0h[1], oacc0, 0, 0, 0);
      oacc1 = __builtin_amdgcn_mfma_f32_32x32x16_bf16(pa0h, V1h[0], oacc1, 0, 0, 0);
      oacc1 = __builtin_amdgcn_mfma_f32_32x32x16_bf16(pa1h, V1h[1], oacc1, 0, 0, 0);
      __builtin_amdgcn_s_setprio(0);
    }

    cur += 1; if (cur >= 3) cur -= 3;
  }

  // ---- combine half-denominators, normalize, store AO as bf16 hi/lo ----
  const float lf = lsum + __shfl_xor(lsum, 32);
  if (lane < 32) bcast[wave][l31] = 1.f / lf;
  __syncthreads();
  f32x4 i4[4];
#pragma unroll
  for (int rq = 0; rq < 4; ++rq)
    i4[rq] = *reinterpret_cast<const f32x4*>(&bcast[wave][rq * 8 + hfl * 4]);

#pragma unroll
  for (int r = 0; r < 16; ++r) {
    const int q = q0 + (r & 3) + 8 * (r >> 2) + 4 * hfl;
    const float inv = i4[r >> 2][r & 3];
    const size_t idx = ((size_t)b * SEQ + q) * FEAT + h * HD + l31;
    unsigned short hh, ll;
    split2(oacc0[r] * inv, hh, ll);
    AOhi[idx] = hh; AOlo[idx] = ll;
    split2(oacc1[r] * inv, hh, ll);
    AOhi[idx + 32] = hh; AOlo[idx + 32] = ll;
  }
}

extern "C" void kernel_launch(void* const* d_in, const int* in_sizes, int n_in,
                              void* d_out, int out_size, void* d_ws, size_t ws_size,
                              hipStream_t stream) {
  const float* x_cur  = (const float*)d_in[0];
  const float* x_past = (const float*)d_in[1];
  const float* wq = (const float*)d_in[2];
  const float* bq = (const float*)d_in[3];
  const float* wk = (const float*)d_in[4];
  const float* bk = (const float*)d_in[5];
  const float* wv = (const float*)d_in[6];
  const float* bv = (const float*)d_in[7];
  const float* wo = (const float*)d_in[8];
  const float* bo = (const float*)d_in[9];
  float* out = (float*)d_out;

  const size_t n = (size_t)NROWS * FEAT;   // 4,194,304
  unsigned short* Qhi  = (unsigned short*)d_ws;
  unsigned short* Qlo  = Qhi + n;
  unsigned short* Khi  = Qhi + 2 * n;
  unsigned short* Klo  = Qhi + 3 * n;
  unsigned short* Vthi = Qhi + 4 * n;
  unsigned short* Wsp  = Qhi + 5 * n;
  unsigned short* AOhi = Qhi + 6 * n;
  unsigned short* AOlo = Qhi + 7 * n;

  dim3 block(256);
  presplit_w<<<dim3(512), block, 0, stream>>>(wq, wk, wv, wo, Wsp);

  dim3 gqkv(NROWS / 128, FEAT / 64, 3);
  qkv_proj<<<gqkv, block, 0, stream>>>(x_cur, x_past, Wsp, bq, bk, bv,
                                       Qhi, Qlo, Khi, Klo, Vthi);

  attn_pipe<<<dim3(512), block, 0, stream>>>(Qhi, Qlo, Khi, Klo, Vthi, AOhi, AOlo);

  dim3 gout(NROWS / 128, FEAT / 64);
  out_proj<<<gout, block, 0, stream>>>(AOhi, AOlo, Wsp + 3 * 524288,
                                       Wsp + 3 * 524288 + 262144, bo, out);
}

// Round 13
// 136.342 us; speedup vs baseline: 2.4010x; 1.0901x over previous
//
#include <hip/hip_runtime.h>
#include <math.h>

#define BATCH 4
#define SEQ 2048
#define FEAT 512
#define NHEADS 8
#define HD 64
#define NROWS (BATCH*SEQ)   // 8192
#define QSCALE 0.18033688011112042f   // log2(e)/8

typedef __attribute__((ext_vector_type(4)))  float f32x4;
typedef __attribute__((ext_vector_type(16))) float f32x16;
typedef __attribute__((ext_vector_type(8)))  short s16x8;
typedef __attribute__((ext_vector_type(8)))  unsigned short u16x8;
typedef __attribute__((ext_vector_type(4)))  unsigned int u32x4;
typedef __attribute__((ext_vector_type(2)))  unsigned int u32x2;

#if __has_builtin(__builtin_amdgcn_exp2f)
#define EX2(x) __builtin_amdgcn_exp2f(x)
#else
#define EX2(x) __expf((x) * 0.6931471805599453f)
#endif

static __device__ __forceinline__ unsigned short f2bf(float x) {
  unsigned int u = __builtin_bit_cast(unsigned int, x);
  unsigned int r = (u + 0x7FFFu + ((u >> 16) & 1u)) >> 16;
  return (unsigned short)r;
}
static __device__ __forceinline__ float bf2f(unsigned short h) {
  unsigned int u = ((unsigned int)h) << 16;
  return __builtin_bit_cast(float, u);
}
static __device__ __forceinline__ void split2(float x, unsigned short& h, unsigned short& l) {
  h = f2bf(x);
  l = f2bf(x - bf2f(h));
}

// async global->LDS, 16B per lane; dest = wave-uniform base + lane*16
static __device__ __forceinline__ void glds16(const unsigned short* g, unsigned short* l) {
  __builtin_amdgcn_global_load_lds(
      (const __attribute__((address_space(1))) unsigned int*)g,
      (__attribute__((address_space(3))) unsigned int*)l,
      16, 0, 0);
}

// split f32x4 -> packed hi pair / lo pair u32s (cvt_pk RNE, same math as split2)
static __device__ __forceinline__ void split4_pk(f32x4 x, unsigned int& hp0, unsigned int& hp1,
                                                 unsigned int& lp0, unsigned int& lp1) {
  asm("v_cvt_pk_bf16_f32 %0, %1, %2" : "=v"(hp0) : "v"(x.x), "v"(x.y));
  asm("v_cvt_pk_bf16_f32 %0, %1, %2" : "=v"(hp1) : "v"(x.z), "v"(x.w));
  const float l0 = x.x - __builtin_bit_cast(float, hp0 << 16);
  const float l1 = x.y - __builtin_bit_cast(float, hp0 & 0xFFFF0000u);
  const float l2 = x.z - __builtin_bit_cast(float, hp1 << 16);
  const float l3 = x.w - __builtin_bit_cast(float, hp1 & 0xFFFF0000u);
  asm("v_cvt_pk_bf16_f32 %0, %1, %2" : "=v"(lp0) : "v"(l0), "v"(l1));
  asm("v_cvt_pk_bf16_f32 %0, %1, %2" : "=v"(lp1) : "v"(l2), "v"(l3));
}

// ---------------------------------------------------------------------------
// Pre-split the four weight matrices into bf16 hi/lo.
// ---------------------------------------------------------------------------
__global__ __launch_bounds__(256) void presplit_w(
    const float* __restrict__ wq, const float* __restrict__ wk,
    const float* __restrict__ wv, const float* __restrict__ wo,
    unsigned short* __restrict__ Wsp)
{
  const int mat = blockIdx.x >> 7;
  const int chunk = ((blockIdx.x & 127) * 256 + threadIdx.x) * 8;
  const float* src = (mat == 0) ? wq : (mat == 1) ? wk : (mat == 2) ? wv : wo;
  unsigned short* hi = Wsp + (size_t)mat * 524288;
  unsigned short* lo = hi + 262144;
  const f32x4 a = *reinterpret_cast<const f32x4*>(&src[chunk]);
  const f32x4 b = *reinterpret_cast<const f32x4*>(&src[chunk + 4]);
  u16x8 h8, l8;
#pragma unroll
  for (int i = 0; i < 4; ++i) { unsigned short hh, ll; split2(a[i], hh, ll); h8[i] = hh; l8[i] = ll; }
#pragma unroll
  for (int i = 0; i < 4; ++i) { unsigned short hh, ll; split2(b[i], hh, ll); h8[4 + i] = hh; l8[4 + i] = ll; }
  *reinterpret_cast<u16x8*>(&hi[chunk]) = h8;
  *reinterpret_cast<u16x8*>(&lo[chunk]) = l8;
}

// ---------------------------------------------------------------------------
// Fused QKV projection. z=0: Q (scale log2e/8) -> (B,H,T,Hd) hi/lo
// z=1: K -> (B,H,T,Hd) hi ONLY (bf16-K QK^T)
// z=2: V -> (B,H,Hd,T') hi only, T' permuted per 16-group
// ---------------------------------------------------------------------------
__global__ __launch_bounds__(256, 3) void qkv_proj(
    const float* __restrict__ xc, const float* __restrict__ xp,
    const unsigned short* __restrict__ Wsp,
    const float* __restrict__ bq, const float* __restrict__ bk,
    const float* __restrict__ bv,
    unsigned short* __restrict__ Qhi, unsigned short* __restrict__ Qlo,
    unsigned short* __restrict__ Khi,
    unsigned short* __restrict__ Vthi)
{
  __shared__ unsigned short Xhi[128 * 64], Xlo[128 * 64];
  __shared__ unsigned short Whi[64 * 64],  Wlo[64 * 64];

  const int z = blockIdx.z;
  const float* X = (z == 0) ? xc : xp;
  const unsigned short* Wh_g = Wsp + (size_t)z * 524288;
  const unsigned short* Wl_g = Wh_g + 262144;
  const float* Bp = (z == 0) ? bq : (z == 1) ? bk : bv;
  unsigned short* Ohi = (z == 0) ? Qhi : (z == 1) ? Khi : Vthi;
  const float scale = (z == 0) ? QSCALE : 1.0f;

  const int tid  = threadIdx.x;
  const int lane = tid & 63;
  const int wave = tid >> 6;
  const int g = lane >> 4, j = lane & 15;
  const int wm = (wave >> 1) * 64;
  const int wn = (wave & 1) * 32;
  const int row0 = blockIdx.x * 128;
  const int col0 = blockIdx.y * 64;

  f32x4 acc[4][2];
#pragma unroll
  for (int mi = 0; mi < 4; ++mi)
#pragma unroll
    for (int ni = 0; ni < 2; ++ni) acc[mi][ni] = (f32x4)0.f;

  const int srow = tid >> 4;        // 0..15
  const int sk   = (tid & 15) * 4;  // 0..60

  const int wrow = wave * 16 + (lane >> 3);
  const int wkg  = (lane & 7) ^ ((lane >> 3) & 7);
  const unsigned short* srcWh = Wh_g + (size_t)(col0 + wrow) * FEAT + wkg * 8;
  const unsigned short* srcWl = Wl_g + (size_t)(col0 + wrow) * FEAT + wkg * 8;

  for (int kt = 0; kt < FEAT; kt += 64) {
    f32x4 xr[8];
#pragma unroll
    for (int p = 0; p < 8; ++p)
      xr[p] = *reinterpret_cast<const f32x4*>(&X[(size_t)(row0 + srow + p * 16) * FEAT + kt + sk]);
    __syncthreads();   // previous iteration's LDS reads done
    glds16(srcWh + kt,        &Whi[(wave * 16) * 64]);
    glds16(srcWh + kt + 4096, &Whi[(wave * 16 + 8) * 64]);
    glds16(srcWl + kt,        &Wlo[(wave * 16) * 64]);
    glds16(srcWl + kt + 4096, &Wlo[(wave * 16 + 8) * 64]);
#pragma unroll
    for (int p = 0; p < 8; ++p) {
      const int r = srow + p * 16;
      const int el = r * 64 + (sk ^ ((r & 7) << 3));
      unsigned int hp0, hp1, lp0, lp1;
      split4_pk(xr[p], hp0, hp1, lp0, lp1);
      *reinterpret_cast<u32x2*>(&Xhi[el]) = (u32x2){hp0, hp1};
      *reinterpret_cast<u32x2*>(&Xlo[el]) = (u32x2){lp0, lp1};
    }
    asm volatile("s_waitcnt vmcnt(0)" ::: "memory");
    __syncthreads();

#pragma unroll
    for (int c = 0; c < 2; ++c) {
      const int koff = c * 32 + g * 8;
      s16x8 ah[4], al[4], bh[2], bl[2];
#pragma unroll
      for (int mi = 0; mi < 4; ++mi) {
        const int r = wm + mi * 16 + j;
        const int el = r * 64 + (koff ^ ((r & 7) << 3));
        ah[mi] = *reinterpret_cast<const s16x8*>(&Xhi[el]);
        al[mi] = *reinterpret_cast<const s16x8*>(&Xlo[el]);
      }
#pragma unroll
      for (int ni = 0; ni < 2; ++ni) {
        const int r = wn + ni * 16 + j;
        const int el = r * 64 + (koff ^ ((r & 7) << 3));
        bh[ni] = *reinterpret_cast<const s16x8*>(&Whi[el]);
        bl[ni] = *reinterpret_cast<const s16x8*>(&Wlo[el]);
      }
#pragma unroll
      for (int mi = 0; mi < 4; ++mi)
#pragma unroll
        for (int ni = 0; ni < 2; ++ni) {
          acc[mi][ni] = __builtin_amdgcn_mfma_f32_16x16x32_bf16(ah[mi], bh[ni], acc[mi][ni], 0, 0, 0);
          acc[mi][ni] = __builtin_amdgcn_mfma_f32_16x16x32_bf16(ah[mi], bl[ni], acc[mi][ni], 0, 0, 0);
          acc[mi][ni] = __builtin_amdgcn_mfma_f32_16x16x32_bf16(al[mi], bh[ni], acc[mi][ni], 0, 0, 0);
        }
    }
  }

  if (z < 2) {
#pragma unroll
    for (int ni = 0; ni < 2; ++ni) {
      const int colc = col0 + wn + ni * 16 + j;
      const float bj = Bp[colc];
      const int h = colc >> 6, hd = colc & 63;
#pragma unroll
      for (int mi = 0; mi < 4; ++mi)
#pragma unroll
        for (int r = 0; r < 4; ++r) {
          const int rowc = row0 + wm + mi * 16 + (g << 2) + r;
          const int b = rowc >> 11, t = rowc & 2047;
          const float v = (acc[mi][ni][r] + bj) * scale;
          const size_t off = (((size_t)b * NHEADS + h) * SEQ + t) * HD + hd;
          if (z == 0) {
            unsigned short hh, ll; split2(v, hh, ll);
            Ohi[off] = hh; Qlo[off] = ll;
          } else {
            Ohi[off] = f2bf(v);   // K: hi only
          }
        }
    }
  } else {
    // V: transpose via LDS -> (B,H,Hd,T'), hi only, T-permuted
    __syncthreads();
#pragma unroll
    for (int ni = 0; ni < 2; ++ni) {
      const int hdl = wn + ni * 16 + j;
      const float bj = Bp[col0 + hdl];
#pragma unroll
      for (int mi = 0; mi < 4; ++mi)
#pragma unroll
        for (int r = 0; r < 4; ++r) {
          const int lt = wm + mi * 16 + (g << 2) + r;
          const float v = acc[mi][ni][r] + bj;
          const int el = lt * 64 + (hdl ^ ((lt & 7) << 3));
          Xhi[el] = f2bf(v);
        }
    }
    __syncthreads();
    const int b = row0 >> 11, h = col0 >> 6;
    const int tbase = row0 & 2047;
#pragma unroll
    for (int c = 0; c < 4; ++c) {
      const int chunk = c * 256 + tid;
      const int hd = chunk >> 4;
      const int t0 = (chunk & 15) * 8;
      u16x8 vh;
#pragma unroll
      for (int i = 0; i < 8; ++i) {
        const int p = t0 + i;
        const int lt = (p & ~15) | ((p & 3) + (((p >> 2) & 1) << 3) + (((p >> 3) & 1) << 2));
        const int el = lt * 64 + (hd ^ ((lt & 7) << 3));
        vh[i] = Xhi[el];
      }
      const size_t off = (((size_t)b * NHEADS + h) * HD + hd) * SEQ + tbase + t0;
      *reinterpret_cast<u16x8*>(&Vthi[off]) = vh;
    }
  }
}

// ---------------------------------------------------------------------------
// Output projection: 100% global_load_lds staging.
// ---------------------------------------------------------------------------
__global__ __launch_bounds__(256, 3) void out_proj(
    const unsigned short* __restrict__ AOhi, const unsigned short* __restrict__ AOlo,
    const unsigned short* __restrict__ Woh,  const unsigned short* __restrict__ Wol,
    const float* __restrict__ bias, float* __restrict__ out)
{
  __shared__ unsigned short Xhi[128 * 64], Xlo[128 * 64];
  __shared__ unsigned short Whi[64 * 64],  Wlo[64 * 64];

  const int tid  = threadIdx.x;
  const int lane = tid & 63;
  const int wave = tid >> 6;
  const int g = lane >> 4, j = lane & 15;
  const int wm = (wave >> 1) * 64;
  const int wn = (wave & 1) * 32;
  const int row0 = blockIdx.x * 128;
  const int col0 = blockIdx.y * 64;

  f32x4 acc[4][2];
#pragma unroll
  for (int mi = 0; mi < 4; ++mi)
#pragma unroll
    for (int ni = 0; ni < 2; ++ni) acc[mi][ni] = (f32x4)0.f;

  const int arow = wave * 32 + (lane >> 3);
  const int akg  = (lane & 7) ^ ((lane >> 3) & 7);
  const unsigned short* srcAh = AOhi + (size_t)(row0 + arow) * FEAT + akg * 8;
  const unsigned short* srcAl = AOlo + (size_t)(row0 + arow) * FEAT + akg * 8;
  const int wrow = wave * 16 + (lane >> 3);
  const unsigned short* srcWh = Woh + (size_t)(col0 + wrow) * FEAT + akg * 8;
  const unsigned short* srcWl = Wol + (size_t)(col0 + wrow) * FEAT + akg * 8;

  for (int kt = 0; kt < FEAT; kt += 64) {
    __syncthreads();
#pragma unroll
    for (int c = 0; c < 4; ++c) {
      glds16(srcAh + kt + c * 4096, &Xhi[(wave * 32 + c * 8) * 64]);
      glds16(srcAl + kt + c * 4096, &Xlo[(wave * 32 + c * 8) * 64]);
    }
    glds16(srcWh + kt,        &Whi[(wave * 16) * 64]);
    glds16(srcWh + kt + 4096, &Whi[(wave * 16 + 8) * 64]);
    glds16(srcWl + kt,        &Wlo[(wave * 16) * 64]);
    glds16(srcWl + kt + 4096, &Wlo[(wave * 16 + 8) * 64]);
    asm volatile("s_waitcnt vmcnt(0)" ::: "memory");
    __syncthreads();

#pragma unroll
    for (int c = 0; c < 2; ++c) {
      const int koff = c * 32 + g * 8;
      s16x8 ah[4], al[4], bh[2], bl[2];
#pragma unroll
      for (int mi = 0; mi < 4; ++mi) {
        const int r = wm + mi * 16 + j;
        const int el = r * 64 + (koff ^ ((r & 7) << 3));
        ah[mi] = *reinterpret_cast<const s16x8*>(&Xhi[el]);
        al[mi] = *reinterpret_cast<const s16x8*>(&Xlo[el]);
      }
#pragma unroll
      for (int ni = 0; ni < 2; ++ni) {
        const int r = wn + ni * 16 + j;
        const int el = r * 64 + (koff ^ ((r & 7) << 3));
        bh[ni] = *reinterpret_cast<const s16x8*>(&Whi[el]);
        bl[ni] = *reinterpret_cast<const s16x8*>(&Wlo[el]);
      }
#pragma unroll
      for (int mi = 0; mi < 4; ++mi)
#pragma unroll
        for (int ni = 0; ni < 2; ++ni) {
          acc[mi][ni] = __builtin_amdgcn_mfma_f32_16x16x32_bf16(ah[mi], bh[ni], acc[mi][ni], 0, 0, 0);
          acc[mi][ni] = __builtin_amdgcn_mfma_f32_16x16x32_bf16(ah[mi], bl[ni], acc[mi][ni], 0, 0, 0);
          acc[mi][ni] = __builtin_amdgcn_mfma_f32_16x16x32_bf16(al[mi], bh[ni], acc[mi][ni], 0, 0, 0);
        }
    }
  }

#pragma unroll
  for (int ni = 0; ni < 2; ++ni) {
    const int colc = col0 + wn + ni * 16 + j;
    const float bj = bias[colc];
#pragma unroll
    for (int mi = 0; mi < 4; ++mi)
#pragma unroll
      for (int r = 0; r < 4; ++r) {
        const int rowc = row0 + wm + mi * 16 + (g << 2) + r;
        out[(size_t)rowc * FEAT + colc] = acc[mi][ni][r] + bj;
      }
  }
}

// ---------------------------------------------------------------------------
// Flash attention: 3-buffer counted-vmcnt LDS pipeline, KVBLK=64.
// QK^T = bf16-K x split-Q (2 MFMA/chunk: KH*qh + KH*ql); PV hi-only with
// permuted-V. LDS 48.5KB -> 3 blocks/CU. Native exp2, deferred-l,
// conditional pm swap.
// ---------------------------------------------------------------------------
__global__ __launch_bounds__(256, 3) void attn_pipe(
    const unsigned short* __restrict__ Qhi, const unsigned short* __restrict__ Qlo,
    const unsigned short* __restrict__ Khi,
    const unsigned short* __restrict__ Vthi,
    unsigned short* __restrict__ AOhi, unsigned short* __restrict__ AOlo)
{
  __shared__ unsigned short Kh_s[3][4096];
  __shared__ unsigned short Vh_s[3][4096];
  __shared__ float bcast[4][32];

  const int tid = threadIdx.x, lane = tid & 63, wave = tid >> 6;
  const int hfl = lane >> 5;
  const int l31 = lane & 31;

  const int bid = blockIdx.x;
  const int swz = (bid & 7) * 64 + (bid >> 3);
  const int qt  = swz & 15;
  const int bh  = swz >> 4;
  const int b = bh >> 3, h = bh & 7;

  const int q0 = qt * 128 + wave * 32;
  const size_t kvbase = (size_t)bh * SEQ * HD;

  // Q B-fragments (pre-scaled by log2e/8 in proj)
  s16x8 qh[4], ql[4];
  {
    const size_t qoff = kvbase + (size_t)(q0 + l31) * HD + hfl * 8;
#pragma unroll
    for (int c = 0; c < 4; ++c) {
      qh[c] = *reinterpret_cast<const s16x8*>(&Qhi[qoff + c * 16]);
      ql[c] = *reinterpret_cast<const s16x8*>(&Qlo[qoff + c * 16]);
    }
  }

  f32x16 oacc0 = (f32x16)0.f, oacc1 = (f32x16)0.f;
  float m = -INFINITY, lsum = 0.f;

  const int ck  = tid >> 3;
  const int ksl = (tid & 7) ^ (ck & 7);
  const unsigned short* sKh = Khi + kvbase + (size_t)ck * HD + ksl * 8;
  const int vr  = tid >> 3;
  const int vsl = (tid & 7) ^ (vr & 7);
  const int vhd = vr + (vsl >> 2) * 32;
  const int vk0 = (vsl & 3) * 8;
  const unsigned short* sVh = Vthi + kvbase + (size_t)vhd * SEQ + vk0;
  const int wq = wave * 512;

  const int krow = l31 * 64;
  const int ksw  = l31 & 7;

  // stage tile tt into buffer bi (4 glds per wave)
  auto stage = [&](int tt, int bi) {
    const size_t ko = (size_t)tt * 64 * HD;
    const int    vo = tt * 64;
    glds16(sKh + ko,           &Kh_s[bi][wq]);
    glds16(sKh + ko + 32 * HD, &Kh_s[bi][2048 + wq]);
    glds16(sVh + vo,           &Vh_s[bi][wq]);
    glds16(sVh + vo + 32,      &Vh_s[bi][2048 + wq]);
  };

  // prologue: two tiles in flight
  stage(0, 0);
  stage(1, 1);

  const int NT = SEQ / 64;   // 32
  int cur = 0;
  for (int t = 0; t < NT; ++t) {
    if (t < NT - 1) {
      asm volatile("s_waitcnt vmcnt(4)" ::: "memory");
    } else {
      asm volatile("s_waitcnt vmcnt(0)" ::: "memory");
    }
    __syncthreads();
    if (t + 2 < NT) {
      int nb = cur + 2; if (nb >= 3) nb -= 3;
      stage(t + 2, nb);
    }
    __builtin_amdgcn_sched_barrier(0);

#pragma unroll
    for (int sub = 0; sub < 2; ++sub) {
      const int sb = sub * 2048;

      s16x8 KH[4];
#pragma unroll
      for (int c = 0; c < 4; ++c) {
        const int idx = sb + krow + ((((c << 1) | hfl)) ^ ksw) * 8;
        KH[c] = *reinterpret_cast<const s16x8*>(&Kh_s[cur][idx]);
      }

      // ---- S^T = K(bf16) Q(split)^T, two independent chains ----
      f32x16 stA = (f32x16)0.f, stB = (f32x16)0.f;
      __builtin_amdgcn_s_setprio(1);
#pragma unroll
      for (int c = 0; c < 2; ++c) {
        stA = __builtin_amdgcn_mfma_f32_32x32x16_bf16(KH[c], qh[c], stA, 0, 0, 0);
        stA = __builtin_amdgcn_mfma_f32_32x32x16_bf16(KH[c], ql[c], stA, 0, 0, 0);
        stB = __builtin_amdgcn_mfma_f32_32x32x16_bf16(KH[2 + c], qh[2 + c], stB, 0, 0, 0);
        stB = __builtin_amdgcn_mfma_f32_32x32x16_bf16(KH[2 + c], ql[2 + c], stB, 0, 0, 0);
      }
      __builtin_amdgcn_s_setprio(0);
      f32x16 st;
#pragma unroll
      for (int r = 0; r < 16; ++r) st[r] = stA[r] + stB[r];

      // ---- V fragments (hi only, permuted layout) ----
      s16x8 V0h[2], V1h[2];
#pragma unroll
      for (int c = 0; c < 2; ++c) {
        const int i0 = sb + krow + ((((c << 1) | hfl)) ^ ksw) * 8;
        const int i1 = sb + krow + (((4 | (c << 1) | hfl)) ^ ksw) * 8;
        V0h[c] = *reinterpret_cast<const s16x8*>(&Vh_s[cur][i0]);
        V1h[c] = *reinterpret_cast<const s16x8*>(&Vh_s[cur][i1]);
      }

      // ---- per-half tile max (max3-shaped tree) ----
      const float a0 = fmaxf(fmaxf(st[0], st[1]), st[2]);
      const float a1 = fmaxf(fmaxf(st[3], st[4]), st[5]);
      const float a2 = fmaxf(fmaxf(st[6], st[7]), st[8]);
      const float a3 = fmaxf(fmaxf(st[9], st[10]), st[11]);
      const float a4 = fmaxf(fmaxf(st[12], st[13]), st[14]);
      const float pm = fmaxf(fmaxf(fmaxf(a0, a1), a2),
                             fmaxf(fmaxf(a3, a4), st[15]));

      if (__any(pm > m + 8.f)) {
        const float pmf  = fmaxf(pm, __shfl_xor(pm, 32));
        const float mnew = fmaxf(m, pmf);
        const float corr = EX2(m - mnew);
        m = mnew; lsum *= corr;
        if (lane < 32) bcast[wave][l31] = corr;
        f32x4 c4[4];
#pragma unroll
        for (int rq = 0; rq < 4; ++rq)
          c4[rq] = *reinterpret_cast<const f32x4*>(&bcast[wave][rq * 8 + hfl * 4]);
#pragma unroll
        for (int r = 0; r < 16; ++r) {
          const float cc = c4[r >> 2][r & 3];
          oacc0[r] *= cc; oacc1[r] *= cc;
        }
      }

#pragma unroll
      for (int r = 0; r < 16; ++r) st[r] = EX2(st[r] - m);
      {
        float s0 = (st[0] + st[1]) + (st[2] + st[3]);
        float s1 = (st[4] + st[5]) + (st[6] + st[7]);
        float s2 = (st[8] + st[9]) + (st[10] + st[11]);
        float s3 = (st[12] + st[13]) + (st[14] + st[15]);
        lsum += (s0 + s1) + (s2 + s3);
      }

      // ---- pack P (lane-local order; permuted-V makes this the A-frag) ----
      unsigned int wh[8];
#pragma unroll
      for (int p = 0; p < 8; ++p)
        asm("v_cvt_pk_bf16_f32 %0, %1, %2" : "=v"(wh[p]) : "v"(st[2 * p]), "v"(st[2 * p + 1]));
      const s16x8 pa0h = __builtin_bit_cast(s16x8, (u32x4){wh[0], wh[1], wh[2], wh[3]});
      const s16x8 pa1h = __builtin_bit_cast(s16x8, (u32x4){wh[4], wh[5], wh[6], wh[7]});

      __builtin_amdgcn_s_setprio(1);
      oacc0 = __builtin_amdgcn_mfma_f32_32x32x16_bf16(pa0h, V0h[0], oacc0, 0, 0, 0);
      oacc0 = __builtin_amdgcn_mfma_f32_32x32x16_bf16(pa1h, V0h[1], oacc0, 0, 0, 0);
      oacc1 = __builtin_amdgcn_mfma_f32_32x32x16_bf16(pa0h, V1h[0], oacc1, 0, 0, 0);
      oacc1 = __builtin_amdgcn_mfma_f32_32x32x16_bf16(pa1h, V1h[1], oacc1, 0, 0, 0);
      __builtin_amdgcn_s_setprio(0);
    }

    cur += 1; if (cur >= 3) cur -= 3;
  }

  // ---- combine half-denominators, normalize, store AO as bf16 hi/lo ----
  const float lf = lsum + __shfl_xor(lsum, 32);
  if (lane < 32) bcast[wave][l31] = 1.f / lf;
  __syncthreads();
  f32x4 i4[4];
#pragma unroll
  for (int rq = 0; rq < 4; ++rq)
    i4[rq] = *reinterpret_cast<const f32x4*>(&bcast[wave][rq * 8 + hfl * 4]);

#pragma unroll
  for (int r = 0; r < 16; ++r) {
    const int q = q0 + (r & 3) + 8 * (r >> 2) + 4 * hfl;
    const float inv = i4[r >> 2][r & 3];
    const size_t idx = ((size_t)b * SEQ + q) * FEAT + h * HD + l31;
    unsigned short hh, ll;
    split2(oacc0[r] * inv, hh, ll);
    AOhi[idx] = hh; AOlo[idx] = ll;
    split2(oacc1[r] * inv, hh, ll);
    AOhi[idx + 32] = hh; AOlo[idx + 32] = ll;
  }
}

extern "C" void kernel_launch(void* const* d_in, const int* in_sizes, int n_in,
                              void* d_out, int out_size, void* d_ws, size_t ws_size,
                              hipStream_t stream) {
  const float* x_cur  = (const float*)d_in[0];
  const float* x_past = (const float*)d_in[1];
  const float* wq = (const float*)d_in[2];
  const float* bq = (const float*)d_in[3];
  const float* wk = (const float*)d_in[4];
  const float* bk = (const float*)d_in[5];
  const float* wv = (const float*)d_in[6];
  const float* bv = (const float*)d_in[7];
  const float* wo = (const float*)d_in[8];
  const float* bo = (const float*)d_in[9];
  float* out = (float*)d_out;

  const size_t n = (size_t)NROWS * FEAT;   // 4,194,304
  unsigned short* Qhi  = (unsigned short*)d_ws;
  unsigned short* Qlo  = Qhi + n;
  unsigned short* Khi  = Qhi + 2 * n;
  unsigned short* Vthi = Qhi + 4 * n;
  unsigned short* Wsp  = Qhi + 5 * n;
  unsigned short* AOhi = Qhi + 6 * n;
  unsigned short* AOlo = Qhi + 7 * n;

  dim3 block(256);
  presplit_w<<<dim3(512), block, 0, stream>>>(wq, wk, wv, wo, Wsp);

  dim3 gqkv(NROWS / 128, FEAT / 64, 3);
  qkv_proj<<<gqkv, block, 0, stream>>>(x_cur, x_past, Wsp, bq, bk, bv,
                                       Qhi, Qlo, Khi, Vthi);

  attn_pipe<<<dim3(512), block, 0, stream>>>(Qhi, Qlo, Khi, Vthi, AOhi, AOlo);

  dim3 gout(NROWS / 128, FEAT / 64);
  out_proj<<<gout, block, 0, stream>>>(AOhi, AOlo, Wsp + 3 * 524288,
                                       Wsp + 3 * 524288 + 262144, bo, out);
}

// Round 15
// 135.667 us; speedup vs baseline: 2.4130x; 1.0050x over previous
//
#include <hip/hip_runtime.h>
#include <math.h>

#define BATCH 4
#define SEQ 2048
#define FEAT 512
#define NHEADS 8
#define HD 64
#define NROWS (BATCH*SEQ)   // 8192
#define QSCALE 0.18033688011112042f   // log2(e)/8

typedef __attribute__((ext_vector_type(4)))  float f32x4;
typedef __attribute__((ext_vector_type(16))) float f32x16;
typedef __attribute__((ext_vector_type(8)))  short s16x8;
typedef __attribute__((ext_vector_type(8)))  unsigned short u16x8;
typedef __attribute__((ext_vector_type(4)))  unsigned int u32x4;
typedef __attribute__((ext_vector_type(2)))  unsigned int u32x2;

#if __has_builtin(__builtin_amdgcn_exp2f)
#define EX2(x) __builtin_amdgcn_exp2f(x)
#else
#define EX2(x) __expf((x) * 0.6931471805599453f)
#endif

static __device__ __forceinline__ unsigned short f2bf(float x) {
  unsigned int u = __builtin_bit_cast(unsigned int, x);
  unsigned int r = (u + 0x7FFFu + ((u >> 16) & 1u)) >> 16;
  return (unsigned short)r;
}
static __device__ __forceinline__ float bf2f(unsigned short h) {
  unsigned int u = ((unsigned int)h) << 16;
  return __builtin_bit_cast(float, u);
}
static __device__ __forceinline__ void split2(float x, unsigned short& h, unsigned short& l) {
  h = f2bf(x);
  l = f2bf(x - bf2f(h));
}

// async global->LDS, 16B per lane; dest = wave-uniform base + lane*16
static __device__ __forceinline__ void glds16(const unsigned short* g, unsigned short* l) {
  __builtin_amdgcn_global_load_lds(
      (const __attribute__((address_space(1))) unsigned int*)g,
      (__attribute__((address_space(3))) unsigned int*)l,
      16, 0, 0);
}

// split f32x4 -> packed hi pair / lo pair u32s (cvt_pk RNE, same math as split2)
static __device__ __forceinline__ void split4_pk(f32x4 x, unsigned int& hp0, unsigned int& hp1,
                                                 unsigned int& lp0, unsigned int& lp1) {
  asm("v_cvt_pk_bf16_f32 %0, %1, %2" : "=v"(hp0) : "v"(x.x), "v"(x.y));
  asm("v_cvt_pk_bf16_f32 %0, %1, %2" : "=v"(hp1) : "v"(x.z), "v"(x.w));
  const float l0 = x.x - __builtin_bit_cast(float, hp0 << 16);
  const float l1 = x.y - __builtin_bit_cast(float, hp0 & 0xFFFF0000u);
  const float l2 = x.z - __builtin_bit_cast(float, hp1 << 16);
  const float l3 = x.w - __builtin_bit_cast(float, hp1 & 0xFFFF0000u);
  asm("v_cvt_pk_bf16_f32 %0, %1, %2" : "=v"(lp0) : "v"(l0), "v"(l1));
  asm("v_cvt_pk_bf16_f32 %0, %1, %2" : "=v"(lp1) : "v"(l2), "v"(l3));
}

// ---------------------------------------------------------------------------
// Pre-split the four weight matrices into bf16 hi/lo.
// ---------------------------------------------------------------------------
__global__ __launch_bounds__(256) void presplit_w(
    const float* __restrict__ wq, const float* __restrict__ wk,
    const float* __restrict__ wv, const float* __restrict__ wo,
    unsigned short* __restrict__ Wsp)
{
  const int mat = blockIdx.x >> 7;
  const int chunk = ((blockIdx.x & 127) * 256 + threadIdx.x) * 8;
  const float* src = (mat == 0) ? wq : (mat == 1) ? wk : (mat == 2) ? wv : wo;
  unsigned short* hi = Wsp + (size_t)mat * 524288;
  unsigned short* lo = hi + 262144;
  const f32x4 a = *reinterpret_cast<const f32x4*>(&src[chunk]);
  const f32x4 b = *reinterpret_cast<const f32x4*>(&src[chunk + 4]);
  u16x8 h8, l8;
#pragma unroll
  for (int i = 0; i < 4; ++i) { unsigned short hh, ll; split2(a[i], hh, ll); h8[i] = hh; l8[i] = ll; }
#pragma unroll
  for (int i = 0; i < 4; ++i) { unsigned short hh, ll; split2(b[i], hh, ll); h8[4 + i] = hh; l8[4 + i] = ll; }
  *reinterpret_cast<u16x8*>(&hi[chunk]) = h8;
  *reinterpret_cast<u16x8*>(&lo[chunk]) = l8;
}

// ---------------------------------------------------------------------------
// Fused QKV projection. z=0: Q (scale log2e/8) -> (B,H,T,Hd) hi/lo
// z=1: K -> (B,H,T,Hd) hi ONLY
// z=2: V -> (B,H,Hd,T') hi only, T' permuted per 16-group
// ---------------------------------------------------------------------------
__global__ __launch_bounds__(256, 3) void qkv_proj(
    const float* __restrict__ xc, const float* __restrict__ xp,
    const unsigned short* __restrict__ Wsp,
    const float* __restrict__ bq, const float* __restrict__ bk,
    const float* __restrict__ bv,
    unsigned short* __restrict__ Qhi, unsigned short* __restrict__ Qlo,
    unsigned short* __restrict__ Khi,
    unsigned short* __restrict__ Vthi)
{
  __shared__ unsigned short Xhi[128 * 64], Xlo[128 * 64];
  __shared__ unsigned short Whi[64 * 64],  Wlo[64 * 64];

  const int z = blockIdx.z;
  const float* X = (z == 0) ? xc : xp;
  const unsigned short* Wh_g = Wsp + (size_t)z * 524288;
  const unsigned short* Wl_g = Wh_g + 262144;
  const float* Bp = (z == 0) ? bq : (z == 1) ? bk : bv;
  unsigned short* Ohi = (z == 0) ? Qhi : (z == 1) ? Khi : Vthi;
  const float scale = (z == 0) ? QSCALE : 1.0f;

  const int tid  = threadIdx.x;
  const int lane = tid & 63;
  const int wave = tid >> 6;
  const int g = lane >> 4, j = lane & 15;
  const int wm = (wave >> 1) * 64;
  const int wn = (wave & 1) * 32;
  const int row0 = blockIdx.x * 128;
  const int col0 = blockIdx.y * 64;

  f32x4 acc[4][2];
#pragma unroll
  for (int mi = 0; mi < 4; ++mi)
#pragma unroll
    for (int ni = 0; ni < 2; ++ni) acc[mi][ni] = (f32x4)0.f;

  const int srow = tid >> 4;        // 0..15
  const int sk   = (tid & 15) * 4;  // 0..60

  const int wrow = wave * 16 + (lane >> 3);
  const int wkg  = (lane & 7) ^ ((lane >> 3) & 7);
  const unsigned short* srcWh = Wh_g + (size_t)(col0 + wrow) * FEAT + wkg * 8;
  const unsigned short* srcWl = Wl_g + (size_t)(col0 + wrow) * FEAT + wkg * 8;

  for (int kt = 0; kt < FEAT; kt += 64) {
    f32x4 xr[8];
#pragma unroll
    for (int p = 0; p < 8; ++p)
      xr[p] = *reinterpret_cast<const f32x4*>(&X[(size_t)(row0 + srow + p * 16) * FEAT + kt + sk]);
    __syncthreads();   // previous iteration's LDS reads done
    glds16(srcWh + kt,        &Whi[(wave * 16) * 64]);
    glds16(srcWh + kt + 4096, &Whi[(wave * 16 + 8) * 64]);
    glds16(srcWl + kt,        &Wlo[(wave * 16) * 64]);
    glds16(srcWl + kt + 4096, &Wlo[(wave * 16 + 8) * 64]);
#pragma unroll
    for (int p = 0; p < 8; ++p) {
      const int r = srow + p * 16;
      const int el = r * 64 + (sk ^ ((r & 7) << 3));
      unsigned int hp0, hp1, lp0, lp1;
      split4_pk(xr[p], hp0, hp1, lp0, lp1);
      *reinterpret_cast<u32x2*>(&Xhi[el]) = (u32x2){hp0, hp1};
      *reinterpret_cast<u32x2*>(&Xlo[el]) = (u32x2){lp0, lp1};
    }
    asm volatile("s_waitcnt vmcnt(0)" ::: "memory");
    __syncthreads();

#pragma unroll
    for (int c = 0; c < 2; ++c) {
      const int koff = c * 32 + g * 8;
      s16x8 ah[4], al[4], bh[2], bl[2];
#pragma unroll
      for (int mi = 0; mi < 4; ++mi) {
        const int r = wm + mi * 16 + j;
        const int el = r * 64 + (koff ^ ((r & 7) << 3));
        ah[mi] = *reinterpret_cast<const s16x8*>(&Xhi[el]);
        al[mi] = *reinterpret_cast<const s16x8*>(&Xlo[el]);
      }
#pragma unroll
      for (int ni = 0; ni < 2; ++ni) {
        const int r = wn + ni * 16 + j;
        const int el = r * 64 + (koff ^ ((r & 7) << 3));
        bh[ni] = *reinterpret_cast<const s16x8*>(&Whi[el]);
        bl[ni] = *reinterpret_cast<const s16x8*>(&Wlo[el]);
      }
#pragma unroll
      for (int mi = 0; mi < 4; ++mi)
#pragma unroll
        for (int ni = 0; ni < 2; ++ni) {
          acc[mi][ni] = __builtin_amdgcn_mfma_f32_16x16x32_bf16(ah[mi], bh[ni], acc[mi][ni], 0, 0, 0);
          acc[mi][ni] = __builtin_amdgcn_mfma_f32_16x16x32_bf16(ah[mi], bl[ni], acc[mi][ni], 0, 0, 0);
          acc[mi][ni] = __builtin_amdgcn_mfma_f32_16x16x32_bf16(al[mi], bh[ni], acc[mi][ni], 0, 0, 0);
        }
    }
  }

  if (z < 2) {
#pragma unroll
    for (int ni = 0; ni < 2; ++ni) {
      const int colc = col0 + wn + ni * 16 + j;
      const float bj = Bp[colc];
      const int h = colc >> 6, hd = colc & 63;
#pragma unroll
      for (int mi = 0; mi < 4; ++mi)
#pragma unroll
        for (int r = 0; r < 4; ++r) {
          const int rowc = row0 + wm + mi * 16 + (g << 2) + r;
          const int b = rowc >> 11, t = rowc & 2047;
          const float v = (acc[mi][ni][r] + bj) * scale;
          const size_t off = (((size_t)b * NHEADS + h) * SEQ + t) * HD + hd;
          if (z == 0) {
            unsigned short hh, ll; split2(v, hh, ll);
            Ohi[off] = hh; Qlo[off] = ll;
          } else {
            Ohi[off] = f2bf(v);   // K: hi only
          }
        }
    }
  } else {
    // V: transpose via LDS -> (B,H,Hd,T'), hi only, T-permuted
    __syncthreads();
#pragma unroll
    for (int ni = 0; ni < 2; ++ni) {
      const int hdl = wn + ni * 16 + j;
      const float bj = Bp[col0 + hdl];
#pragma unroll
      for (int mi = 0; mi < 4; ++mi)
#pragma unroll
        for (int r = 0; r < 4; ++r) {
          const int lt = wm + mi * 16 + (g << 2) + r;
          const float v = acc[mi][ni][r] + bj;
          const int el = lt * 64 + (hdl ^ ((lt & 7) << 3));
          Xhi[el] = f2bf(v);
        }
    }
    __syncthreads();
    const int b = row0 >> 11, h = col0 >> 6;
    const int tbase = row0 & 2047;
#pragma unroll
    for (int c = 0; c < 4; ++c) {
      const int chunk = c * 256 + tid;
      const int hd = chunk >> 4;
      const int t0 = (chunk & 15) * 8;
      u16x8 vh;
#pragma unroll
      for (int i = 0; i < 8; ++i) {
        const int p = t0 + i;
        const int lt = (p & ~15) | ((p & 3) + (((p >> 2) & 1) << 3) + (((p >> 3) & 1) << 2));
        const int el = lt * 64 + (hd ^ ((lt & 7) << 3));
        vh[i] = Xhi[el];
      }
      const size_t off = (((size_t)b * NHEADS + h) * HD + hd) * SEQ + tbase + t0;
      *reinterpret_cast<u16x8*>(&Vthi[off]) = vh;
    }
  }
}

// ---------------------------------------------------------------------------
// Output projection: 64-row tiles -> 1024 blocks (4 blocks/CU). 100%
// global_load_lds staging.
// ---------------------------------------------------------------------------
__global__ __launch_bounds__(256, 4) void out_proj(
    const unsigned short* __restrict__ AOhi, const unsigned short* __restrict__ AOlo,
    const unsigned short* __restrict__ Woh,  const unsigned short* __restrict__ Wol,
    const float* __restrict__ bias, float* __restrict__ out)
{
  __shared__ unsigned short Xhi[64 * 64], Xlo[64 * 64];
  __shared__ unsigned short Whi[64 * 64], Wlo[64 * 64];

  const int tid  = threadIdx.x;
  const int lane = tid & 63;
  const int wave = tid >> 6;
  const int g = lane >> 4, j = lane & 15;
  const int wm = (wave >> 1) * 32;
  const int wn = (wave & 1) * 32;
  const int row0 = blockIdx.x * 64;
  const int col0 = blockIdx.y * 64;

  f32x4 acc[2][2];
#pragma unroll
  for (int mi = 0; mi < 2; ++mi)
#pragma unroll
    for (int ni = 0; ni < 2; ++ni) acc[mi][ni] = (f32x4)0.f;

  const int arow = wave * 16 + (lane >> 3);
  const int akg  = (lane & 7) ^ ((lane >> 3) & 7);
  const unsigned short* srcAh = AOhi + (size_t)(row0 + arow) * FEAT + akg * 8;
  const unsigned short* srcAl = AOlo + (size_t)(row0 + arow) * FEAT + akg * 8;
  const unsigned short* srcWh = Woh + (size_t)(col0 + arow) * FEAT + akg * 8;
  const unsigned short* srcWl = Wol + (size_t)(col0 + arow) * FEAT + akg * 8;

  for (int kt = 0; kt < FEAT; kt += 64) {
    __syncthreads();
    glds16(srcAh + kt,        &Xhi[(wave * 16) * 64]);
    glds16(srcAh + kt + 4096, &Xhi[(wave * 16 + 8) * 64]);
    glds16(srcAl + kt,        &Xlo[(wave * 16) * 64]);
    glds16(srcAl + kt + 4096, &Xlo[(wave * 16 + 8) * 64]);
    glds16(srcWh + kt,        &Whi[(wave * 16) * 64]);
    glds16(srcWh + kt + 4096, &Whi[(wave * 16 + 8) * 64]);
    glds16(srcWl + kt,        &Wlo[(wave * 16) * 64]);
    glds16(srcWl + kt + 4096, &Wlo[(wave * 16 + 8) * 64]);
    asm volatile("s_waitcnt vmcnt(0)" ::: "memory");
    __syncthreads();

#pragma unroll
    for (int c = 0; c < 2; ++c) {
      const int koff = c * 32 + g * 8;
      s16x8 ah[2], al[2], bh[2], bl[2];
#pragma unroll
      for (int mi = 0; mi < 2; ++mi) {
        const int r = wm + mi * 16 + j;
        const int el = r * 64 + (koff ^ ((r & 7) << 3));
        ah[mi] = *reinterpret_cast<const s16x8*>(&Xhi[el]);
        al[mi] = *reinterpret_cast<const s16x8*>(&Xlo[el]);
      }
#pragma unroll
      for (int ni = 0; ni < 2; ++ni) {
        const int r = wn + ni * 16 + j;
        const int el = r * 64 + (koff ^ ((r & 7) << 3));
        bh[ni] = *reinterpret_cast<const s16x8*>(&Whi[el]);
        bl[ni] = *reinterpret_cast<const s16x8*>(&Wlo[el]);
      }
#pragma unroll
      for (int mi = 0; mi < 2; ++mi)
#pragma unroll
        for (int ni = 0; ni < 2; ++ni) {
          acc[mi][ni] = __builtin_amdgcn_mfma_f32_16x16x32_bf16(ah[mi], bh[ni], acc[mi][ni], 0, 0, 0);
          acc[mi][ni] = __builtin_amdgcn_mfma_f32_16x16x32_bf16(ah[mi], bl[ni], acc[mi][ni], 0, 0, 0);
          acc[mi][ni] = __builtin_amdgcn_mfma_f32_16x16x32_bf16(al[mi], bh[ni], acc[mi][ni], 0, 0, 0);
        }
    }
  }

#pragma unroll
  for (int ni = 0; ni < 2; ++ni) {
    const int colc = col0 + wn + ni * 16 + j;
    const float bj = bias[colc];
#pragma unroll
    for (int mi = 0; mi < 2; ++mi)
#pragma unroll
      for (int r = 0; r < 4; ++r) {
        const int rowc = row0 + wm + mi * 16 + (g << 2) + r;
        out[(size_t)rowc * FEAT + colc] = acc[mi][ni][r] + bj;
      }
  }
}

// ---------------------------------------------------------------------------
// Flash attention (EXACT round-13 body — known-good): 3-buffer counted-vmcnt
// LDS pipeline, KVBLK=64 (two 32-key sub-tiles), QK^T bf16-K x split-Q in
// two chains, PV hi-only with permuted-V, native exp2, deferred-l,
// conditional pm swap.
// ---------------------------------------------------------------------------
__global__ __launch_bounds__(256, 3) void attn_pipe(
    const unsigned short* __restrict__ Qhi, const unsigned short* __restrict__ Qlo,
    const unsigned short* __restrict__ Khi,
    const unsigned short* __restrict__ Vthi,
    unsigned short* __restrict__ AOhi, unsigned short* __restrict__ AOlo)
{
  __shared__ unsigned short Kh_s[3][4096];
  __shared__ unsigned short Vh_s[3][4096];
  __shared__ float bcast[4][32];

  const int tid = threadIdx.x, lane = tid & 63, wave = tid >> 6;
  const int hfl = lane >> 5;
  const int l31 = lane & 31;

  const int bid = blockIdx.x;
  const int swz = (bid & 7) * 64 + (bid >> 3);
  const int qt  = swz & 15;
  const int bh  = swz >> 4;
  const int b = bh >> 3, h = bh & 7;

  const int q0 = qt * 128 + wave * 32;
  const size_t kvbase = (size_t)bh * SEQ * HD;

  // Q B-fragments (pre-scaled by log2e/8 in proj)
  s16x8 qh[4], ql[4];
  {
    const size_t qoff = kvbase + (size_t)(q0 + l31) * HD + hfl * 8;
#pragma unroll
    for (int c = 0; c < 4; ++c) {
      qh[c] = *reinterpret_cast<const s16x8*>(&Qhi[qoff + c * 16]);
      ql[c] = *reinterpret_cast<const s16x8*>(&Qlo[qoff + c * 16]);
    }
  }

  f32x16 oacc0 = (f32x16)0.f, oacc1 = (f32x16)0.f;
  float m = -INFINITY, lsum = 0.f;

  const int ck  = tid >> 3;
  const int ksl = (tid & 7) ^ (ck & 7);
  const unsigned short* sKh = Khi + kvbase + (size_t)ck * HD + ksl * 8;
  const int vr  = tid >> 3;
  const int vsl = (tid & 7) ^ (vr & 7);
  const int vhd = vr + (vsl >> 2) * 32;
  const int vk0 = (vsl & 3) * 8;
  const unsigned short* sVh = Vthi + kvbase + (size_t)vhd * SEQ + vk0;
  const int wq = wave * 512;

  const int krow = l31 * 64;
  const int ksw  = l31 & 7;

  // stage tile tt into buffer bi (4 glds per wave)
  auto stage = [&](int tt, int bi) {
    const size_t ko = (size_t)tt * 64 * HD;
    const int    vo = tt * 64;
    glds16(sKh + ko,           &Kh_s[bi][wq]);
    glds16(sKh + ko + 32 * HD, &Kh_s[bi][2048 + wq]);
    glds16(sVh + vo,           &Vh_s[bi][wq]);
    glds16(sVh + vo + 32,      &Vh_s[bi][2048 + wq]);
  };

  // prologue: two tiles in flight
  stage(0, 0);
  stage(1, 1);

  const int NT = SEQ / 64;   // 32
  int cur = 0;
  for (int t = 0; t < NT; ++t) {
    if (t < NT - 1) {
      asm volatile("s_waitcnt vmcnt(4)" ::: "memory");
    } else {
      asm volatile("s_waitcnt vmcnt(0)" ::: "memory");
    }
    __syncthreads();
    if (t + 2 < NT) {
      int nb = cur + 2; if (nb >= 3) nb -= 3;
      stage(t + 2, nb);
    }
    __builtin_amdgcn_sched_barrier(0);

#pragma unroll
    for (int sub = 0; sub < 2; ++sub) {
      const int sb = sub * 2048;

      s16x8 KH[4];
#pragma unroll
      for (int c = 0; c < 4; ++c) {
        const int idx = sb + krow + ((((c << 1) | hfl)) ^ ksw) * 8;
        KH[c] = *reinterpret_cast<const s16x8*>(&Kh_s[cur][idx]);
      }

      // ---- S^T = K(bf16) Q(split)^T, two independent chains ----
      f32x16 stA = (f32x16)0.f, stB = (f32x16)0.f;
      __builtin_amdgcn_s_setprio(1);
#pragma unroll
      for (int c = 0; c < 2; ++c) {
        stA = __builtin_amdgcn_mfma_f32_32x32x16_bf16(KH[c], qh[c], stA, 0, 0, 0);
        stA = __builtin_amdgcn_mfma_f32_32x32x16_bf16(KH[c], ql[c], stA, 0, 0, 0);
        stB = __builtin_amdgcn_mfma_f32_32x32x16_bf16(KH[2 + c], qh[2 + c], stB, 0, 0, 0);
        stB = __builtin_amdgcn_mfma_f32_32x32x16_bf16(KH[2 + c], ql[2 + c], stB, 0, 0, 0);
      }
      __builtin_amdgcn_s_setprio(0);
      f32x16 st;
#pragma unroll
      for (int r = 0; r < 16; ++r) st[r] = stA[r] + stB[r];

      // ---- V fragments (hi only, permuted layout) ----
      s16x8 V0h[2], V1h[2];
#pragma unroll
      for (int c = 0; c < 2; ++c) {
        const int i0 = sb + krow + ((((c << 1) | hfl)) ^ ksw) * 8;
        const int i1 = sb + krow + (((4 | (c << 1) | hfl)) ^ ksw) * 8;
        V0h[c] = *reinterpret_cast<const s16x8*>(&Vh_s[cur][i0]);
        V1h[c] = *reinterpret_cast<const s16x8*>(&Vh_s[cur][i1]);
      }

      // ---- per-half tile max (max3-shaped tree) ----
      const float a0 = fmaxf(fmaxf(st[0], st[1]), st[2]);
      const float a1 = fmaxf(fmaxf(st[3], st[4]), st[5]);
      const float a2 = fmaxf(fmaxf(st[6], st[7]), st[8]);
      const float a3 = fmaxf(fmaxf(st[9], st[10]), st[11]);
      const float a4 = fmaxf(fmaxf(st[12], st[13]), st[14]);
      const float pm = fmaxf(fmaxf(fmaxf(a0, a1), a2),
                             fmaxf(fmaxf(a3, a4), st[15]));

      if (__any(pm > m + 8.f)) {
        const float pmf  = fmaxf(pm, __shfl_xor(pm, 32));
        const float mnew = fmaxf(m, pmf);
        const float corr = EX2(m - mnew);
        m = mnew; lsum *= corr;
        if (lane < 32) bcast[wave][l31] = corr;
        f32x4 c4[4];
#pragma unroll
        for (int rq = 0; rq < 4; ++rq)
          c4[rq] = *reinterpret_cast<const f32x4*>(&bcast[wave][rq * 8 + hfl * 4]);
#pragma unroll
        for (int r = 0; r < 16; ++r) {
          const float cc = c4[r >> 2][r & 3];
          oacc0[r] *= cc; oacc1[r] *= cc;
        }
      }

#pragma unroll
      for (int r = 0; r < 16; ++r) st[r] = EX2(st[r] - m);
      {
        float s0 = (st[0] + st[1]) + (st[2] + st[3]);
        float s1 = (st[4] + st[5]) + (st[6] + st[7]);
        float s2 = (st[8] + st[9]) + (st[10] + st[11]);
        float s3 = (st[12] + st[13]) + (st[14] + st[15]);
        lsum += (s0 + s1) + (s2 + s3);
      }

      // ---- pack P (lane-local order; permuted-V makes this the A-frag) ----
      unsigned int wh[8];
#pragma unroll
      for (int p = 0; p < 8; ++p)
        asm("v_cvt_pk_bf16_f32 %0, %1, %2" : "=v"(wh[p]) : "v"(st[2 * p]), "v"(st[2 * p + 1]));
      const s16x8 pa0h = __builtin_bit_cast(s16x8, (u32x4){wh[0], wh[1], wh[2], wh[3]});
      const s16x8 pa1h = __builtin_bit_cast(s16x8, (u32x4){wh[4], wh[5], wh[6], wh[7]});

      __builtin_amdgcn_s_setprio(1);
      oacc0 = __builtin_amdgcn_mfma_f32_32x32x16_bf16(pa0h, V0h[0], oacc0, 0, 0, 0);
      oacc0 = __builtin_amdgcn_mfma_f32_32x32x16_bf16(pa1h, V0h[1], oacc0, 0, 0, 0);
      oacc1 = __builtin_amdgcn_mfma_f32_32x32x16_bf16(pa0h, V1h[0], oacc1, 0, 0, 0);
      oacc1 = __builtin_amdgcn_mfma_f32_32x32x16_bf16(pa1h, V1h[1], oacc1, 0, 0, 0);
      __builtin_amdgcn_s_setprio(0);
    }

    cur += 1; if (cur >= 3) cur -= 3;
  }

  // ---- combine half-denominators, normalize, store AO as bf16 hi/lo ----
  const float lf = lsum + __shfl_xor(lsum, 32);
  if (lane < 32) bcast[wave][l31] = 1.f / lf;
  __syncthreads();
  f32x4 i4[4];
#pragma unroll
  for (int rq = 0; rq < 4; ++rq)
    i4[rq] = *reinterpret_cast<const f32x4*>(&bcast[wave][rq * 8 + hfl * 4]);

#pragma unroll
  for (int r = 0; r < 16; ++r) {
    const int q = q0 + (r & 3) + 8 * (r >> 2) + 4 * hfl;
    const float inv = i4[r >> 2][r & 3];
    const size_t idx = ((size_t)b * SEQ + q) * FEAT + h * HD + l31;
    unsigned short hh, ll;
    split2(oacc0[r] * inv, hh, ll);
    AOhi[idx] = hh; AOlo[idx] = ll;
    split2(oacc1[r] * inv, hh, ll);
    AOhi[idx + 32] = hh; AOlo[idx + 32] = ll;
  }
}

extern "C" void kernel_launch(void* const* d_in, const int* in_sizes, int n_in,
                              void* d_out, int out_size, void* d_ws, size_t ws_size,
                              hipStream_t stream) {
  const float* x_cur  = (const float*)d_in[0];
  const float* x_past = (const float*)d_in[1];
  const float* wq = (const float*)d_in[2];
  const float* bq = (const float*)d_in[3];
  const float* wk = (const float*)d_in[4];
  const float* bk = (const float*)d_in[5];
  const float* wv = (const float*)d_in[6];
  const float* bv = (const float*)d_in[7];
  const float* wo = (const float*)d_in[8];
  const float* bo = (const float*)d_in[9];
  float* out = (float*)d_out;

  const size_t n = (size_t)NROWS * FEAT;   // 4,194,304
  unsigned short* Qhi  = (unsigned short*)d_ws;
  unsigned short* Qlo  = Qhi + n;
  unsigned short* Khi  = Qhi + 2 * n;
  unsigned short* Vthi = Qhi + 4 * n;
  unsigned short* Wsp  = Qhi + 5 * n;
  unsigned short* AOhi = Qhi + 6 * n;
  unsigned short* AOlo = Qhi + 7 * n;

  dim3 block(256);
  presplit_w<<<dim3(512), block, 0, stream>>>(wq, wk, wv, wo, Wsp);

  dim3 gqkv(NROWS / 128, FEAT / 64, 3);
  qkv_proj<<<gqkv, block, 0, stream>>>(x_cur, x_past, Wsp, bq, bk, bv,
                                       Qhi, Qlo, Khi, Vthi);

  attn_pipe<<<dim3(512), block, 0, stream>>>(Qhi, Qlo, Khi, Vthi, AOhi, AOlo);

  dim3 gout(NROWS / 64, FEAT / 64);
  out_proj<<<gout, block, 0, stream>>>(AOhi, AOlo, Wsp + 3 * 524288,
                                       Wsp + 3 * 524288 + 262144, bo, out);
}

// Round 16
// 132.541 us; speedup vs baseline: 2.4699x; 1.0236x over previous
//
#include <hip/hip_runtime.h>
#include <math.h>

#define BATCH 4
#define SEQ 2048
#define FEAT 512
#define NHEADS 8
#define HD 64
#define NROWS (BATCH*SEQ)   // 8192
#define QSCALE 0.18033688011112042f   // log2(e)/8

typedef __attribute__((ext_vector_type(4)))  float f32x4;
typedef __attribute__((ext_vector_type(16))) float f32x16;
typedef __attribute__((ext_vector_type(8)))  short s16x8;
typedef __attribute__((ext_vector_type(8)))  unsigned short u16x8;
typedef __attribute__((ext_vector_type(4)))  unsigned int u32x4;
typedef __attribute__((ext_vector_type(2)))  unsigned int u32x2;

#if __has_builtin(__builtin_amdgcn_exp2f)
#define EX2(x) __builtin_amdgcn_exp2f(x)
#else
#define EX2(x) __expf((x) * 0.6931471805599453f)
#endif

static __device__ __forceinline__ unsigned short f2bf(float x) {
  unsigned int u = __builtin_bit_cast(unsigned int, x);
  unsigned int r = (u + 0x7FFFu + ((u >> 16) & 1u)) >> 16;
  return (unsigned short)r;
}
static __device__ __forceinline__ float bf2f(unsigned short h) {
  unsigned int u = ((unsigned int)h) << 16;
  return __builtin_bit_cast(float, u);
}
static __device__ __forceinline__ void split2(float x, unsigned short& h, unsigned short& l) {
  h = f2bf(x);
  l = f2bf(x - bf2f(h));
}

// async global->LDS, 16B per lane; dest = wave-uniform base + lane*16
static __device__ __forceinline__ void glds16(const unsigned short* g, unsigned short* l) {
  __builtin_amdgcn_global_load_lds(
      (const __attribute__((address_space(1))) unsigned int*)g,
      (__attribute__((address_space(3))) unsigned int*)l,
      16, 0, 0);
}

// split f32x4 -> packed hi pair / lo pair u32s (cvt_pk RNE, same math as split2)
static __device__ __forceinline__ void split4_pk(f32x4 x, unsigned int& hp0, unsigned int& hp1,
                                                 unsigned int& lp0, unsigned int& lp1) {
  asm("v_cvt_pk_bf16_f32 %0, %1, %2" : "=v"(hp0) : "v"(x.x), "v"(x.y));
  asm("v_cvt_pk_bf16_f32 %0, %1, %2" : "=v"(hp1) : "v"(x.z), "v"(x.w));
  const float l0 = x.x - __builtin_bit_cast(float, hp0 << 16);
  const float l1 = x.y - __builtin_bit_cast(float, hp0 & 0xFFFF0000u);
  const float l2 = x.z - __builtin_bit_cast(float, hp1 << 16);
  const float l3 = x.w - __builtin_bit_cast(float, hp1 & 0xFFFF0000u);
  asm("v_cvt_pk_bf16_f32 %0, %1, %2" : "=v"(lp0) : "v"(l0), "v"(l1));
  asm("v_cvt_pk_bf16_f32 %0, %1, %2" : "=v"(lp1) : "v"(l2), "v"(l3));
}

// ---------------------------------------------------------------------------
// Pre-split the four weight matrices into bf16 hi/lo.
// ---------------------------------------------------------------------------
__global__ __launch_bounds__(256) void presplit_w(
    const float* __restrict__ wq, const float* __restrict__ wk,
    const float* __restrict__ wv, const float* __restrict__ wo,
    unsigned short* __restrict__ Wsp)
{
  const int mat = blockIdx.x >> 7;
  const int chunk = ((blockIdx.x & 127) * 256 + threadIdx.x) * 8;
  const float* src = (mat == 0) ? wq : (mat == 1) ? wk : (mat == 2) ? wv : wo;
  unsigned short* hi = Wsp + (size_t)mat * 524288;
  unsigned short* lo = hi + 262144;
  const f32x4 a = *reinterpret_cast<const f32x4*>(&src[chunk]);
  const f32x4 b = *reinterpret_cast<const f32x4*>(&src[chunk + 4]);
  u16x8 h8, l8;
#pragma unroll
  for (int i = 0; i < 4; ++i) { unsigned short hh, ll; split2(a[i], hh, ll); h8[i] = hh; l8[i] = ll; }
#pragma unroll
  for (int i = 0; i < 4; ++i) { unsigned short hh, ll; split2(b[i], hh, ll); h8[4 + i] = hh; l8[4 + i] = ll; }
  *reinterpret_cast<u16x8*>(&hi[chunk]) = h8;
  *reinterpret_cast<u16x8*>(&lo[chunk]) = l8;
}

// ---------------------------------------------------------------------------
// Pre-round x_past to bf16 (hi only) — feeds K and V projections, whose
// outputs are bf16-rounded anyway.
// ---------------------------------------------------------------------------
__global__ __launch_bounds__(256) void presplit_x(
    const float* __restrict__ xp, unsigned short* __restrict__ Xphi)
{
  const int chunk = (blockIdx.x * 256 + threadIdx.x) * 8;
  const f32x4 a = *reinterpret_cast<const f32x4*>(&xp[chunk]);
  const f32x4 b = *reinterpret_cast<const f32x4*>(&xp[chunk + 4]);
  u16x8 h8;
#pragma unroll
  for (int i = 0; i < 4; ++i) h8[i] = f2bf(a[i]);
#pragma unroll
  for (int i = 0; i < 4; ++i) h8[4 + i] = f2bf(b[i]);
  *reinterpret_cast<u16x8*>(&Xphi[chunk]) = h8;
}

// ---------------------------------------------------------------------------
// Q projection (x_current, full split precision). scale log2e/8.
// Output (B,H,T,Hd) hi/lo.
// ---------------------------------------------------------------------------
__global__ __launch_bounds__(256, 3) void q_proj(
    const float* __restrict__ X, const unsigned short* __restrict__ Wsp,
    const float* __restrict__ bq,
    unsigned short* __restrict__ Qhi, unsigned short* __restrict__ Qlo)
{
  __shared__ unsigned short Xhi[128 * 64], Xlo[128 * 64];
  __shared__ unsigned short Whi[64 * 64],  Wlo[64 * 64];

  const unsigned short* Wh_g = Wsp;
  const unsigned short* Wl_g = Wh_g + 262144;

  const int tid  = threadIdx.x;
  const int lane = tid & 63;
  const int wave = tid >> 6;
  const int g = lane >> 4, j = lane & 15;
  const int wm = (wave >> 1) * 64;
  const int wn = (wave & 1) * 32;
  const int row0 = blockIdx.x * 128;
  const int col0 = blockIdx.y * 64;

  f32x4 acc[4][2];
#pragma unroll
  for (int mi = 0; mi < 4; ++mi)
#pragma unroll
    for (int ni = 0; ni < 2; ++ni) acc[mi][ni] = (f32x4)0.f;

  const int srow = tid >> 4;        // 0..15
  const int sk   = (tid & 15) * 4;  // 0..60

  const int wrow = wave * 16 + (lane >> 3);
  const int wkg  = (lane & 7) ^ ((lane >> 3) & 7);
  const unsigned short* srcWh = Wh_g + (size_t)(col0 + wrow) * FEAT + wkg * 8;
  const unsigned short* srcWl = Wl_g + (size_t)(col0 + wrow) * FEAT + wkg * 8;

  for (int kt = 0; kt < FEAT; kt += 64) {
    f32x4 xr[8];
#pragma unroll
    for (int p = 0; p < 8; ++p)
      xr[p] = *reinterpret_cast<const f32x4*>(&X[(size_t)(row0 + srow + p * 16) * FEAT + kt + sk]);
    __syncthreads();   // previous iteration's LDS reads done
    glds16(srcWh + kt,        &Whi[(wave * 16) * 64]);
    glds16(srcWh + kt + 4096, &Whi[(wave * 16 + 8) * 64]);
    glds16(srcWl + kt,        &Wlo[(wave * 16) * 64]);
    glds16(srcWl + kt + 4096, &Wlo[(wave * 16 + 8) * 64]);
#pragma unroll
    for (int p = 0; p < 8; ++p) {
      const int r = srow + p * 16;
      const int el = r * 64 + (sk ^ ((r & 7) << 3));
      unsigned int hp0, hp1, lp0, lp1;
      split4_pk(xr[p], hp0, hp1, lp0, lp1);
      *reinterpret_cast<u32x2*>(&Xhi[el]) = (u32x2){hp0, hp1};
      *reinterpret_cast<u32x2*>(&Xlo[el]) = (u32x2){lp0, lp1};
    }
    asm volatile("s_waitcnt vmcnt(0)" ::: "memory");
    __syncthreads();

#pragma unroll
    for (int c = 0; c < 2; ++c) {
      const int koff = c * 32 + g * 8;
      s16x8 ah[4], al[4], bh[2], bl[2];
#pragma unroll
      for (int mi = 0; mi < 4; ++mi) {
        const int r = wm + mi * 16 + j;
        const int el = r * 64 + (koff ^ ((r & 7) << 3));
        ah[mi] = *reinterpret_cast<const s16x8*>(&Xhi[el]);
        al[mi] = *reinterpret_cast<const s16x8*>(&Xlo[el]);
      }
#pragma unroll
      for (int ni = 0; ni < 2; ++ni) {
        const int r = wn + ni * 16 + j;
        const int el = r * 64 + (koff ^ ((r & 7) << 3));
        bh[ni] = *reinterpret_cast<const s16x8*>(&Whi[el]);
        bl[ni] = *reinterpret_cast<const s16x8*>(&Wlo[el]);
      }
#pragma unroll
      for (int mi = 0; mi < 4; ++mi)
#pragma unroll
        for (int ni = 0; ni < 2; ++ni) {
          acc[mi][ni] = __builtin_amdgcn_mfma_f32_16x16x32_bf16(ah[mi], bh[ni], acc[mi][ni], 0, 0, 0);
          acc[mi][ni] = __builtin_amdgcn_mfma_f32_16x16x32_bf16(ah[mi], bl[ni], acc[mi][ni], 0, 0, 0);
          acc[mi][ni] = __builtin_amdgcn_mfma_f32_16x16x32_bf16(al[mi], bh[ni], acc[mi][ni], 0, 0, 0);
        }
    }
  }

#pragma unroll
  for (int ni = 0; ni < 2; ++ni) {
    const int colc = col0 + wn + ni * 16 + j;
    const float bj = bq[colc];
    const int h = colc >> 6, hd = colc & 63;
#pragma unroll
    for (int mi = 0; mi < 4; ++mi)
#pragma unroll
      for (int r = 0; r < 4; ++r) {
        const int rowc = row0 + wm + mi * 16 + (g << 2) + r;
        const int b = rowc >> 11, t = rowc & 2047;
        const float v = (acc[mi][ni][r] + bj) * QSCALE;
        unsigned short hh, ll; split2(v, hh, ll);
        const size_t off = (((size_t)b * NHEADS + h) * SEQ + t) * HD + hd;
        Qhi[off] = hh; Qlo[off] = ll;
      }
  }
}

// ---------------------------------------------------------------------------
// K/V projection from bf16 x_past (hi only). 100% global_load_lds staging,
// 2 MFMA per acc (X-lo term gone). z=0: K -> (B,H,T,Hd) hi.
// z=1: V -> (B,H,Hd,T') hi, T' permuted per 16-group.
// LDS 32KB -> 4 blocks/CU.
// ---------------------------------------------------------------------------
__global__ __launch_bounds__(256, 4) void kv_proj(
    const unsigned short* __restrict__ Xphi, const unsigned short* __restrict__ Wsp,
    const float* __restrict__ bk, const float* __restrict__ bv,
    unsigned short* __restrict__ Khi, unsigned short* __restrict__ Vthi)
{
  __shared__ unsigned short Xh[128 * 64];                 // 16KB
  __shared__ unsigned short Whi[64 * 64], Wlo[64 * 64];   // 16KB

  const int z = blockIdx.z;   // 0=K, 1=V
  const unsigned short* Wh_g = Wsp + (size_t)(z + 1) * 524288;
  const unsigned short* Wl_g = Wh_g + 262144;
  const float* Bp = (z == 0) ? bk : bv;

  const int tid  = threadIdx.x;
  const int lane = tid & 63;
  const int wave = tid >> 6;
  const int g = lane >> 4, j = lane & 15;
  const int wm = (wave >> 1) * 64;
  const int wn = (wave & 1) * 32;
  const int row0 = blockIdx.x * 128;
  const int col0 = blockIdx.y * 64;

  f32x4 acc[4][2];
#pragma unroll
  for (int mi = 0; mi < 4; ++mi)
#pragma unroll
    for (int ni = 0; ni < 2; ++ni) acc[mi][ni] = (f32x4)0.f;

  // A staging: rows wave*32..+32, inverse-swizzled source
  const int xrow = wave * 32 + (lane >> 3);
  const int xkg  = (lane & 7) ^ ((lane >> 3) & 7);
  const unsigned short* srcX = Xphi + (size_t)(row0 + xrow) * FEAT + xkg * 8;
  const int wrow = wave * 16 + (lane >> 3);
  const unsigned short* srcWh = Wh_g + (size_t)(col0 + wrow) * FEAT + xkg * 8;
  const unsigned short* srcWl = Wl_g + (size_t)(col0 + wrow) * FEAT + xkg * 8;

  for (int kt = 0; kt < FEAT; kt += 64) {
    __syncthreads();
#pragma unroll
    for (int c = 0; c < 4; ++c)
      glds16(srcX + kt + c * 4096, &Xh[(wave * 32 + c * 8) * 64]);
    glds16(srcWh + kt,        &Whi[(wave * 16) * 64]);
    glds16(srcWh + kt + 4096, &Whi[(wave * 16 + 8) * 64]);
    glds16(srcWl + kt,        &Wlo[(wave * 16) * 64]);
    glds16(srcWl + kt + 4096, &Wlo[(wave * 16 + 8) * 64]);
    asm volatile("s_waitcnt vmcnt(0)" ::: "memory");
    __syncthreads();

#pragma unroll
    for (int c = 0; c < 2; ++c) {
      const int koff = c * 32 + g * 8;
      s16x8 ah[4], bh[2], bl[2];
#pragma unroll
      for (int mi = 0; mi < 4; ++mi) {
        const int r = wm + mi * 16 + j;
        const int el = r * 64 + (koff ^ ((r & 7) << 3));
        ah[mi] = *reinterpret_cast<const s16x8*>(&Xh[el]);
      }
#pragma unroll
      for (int ni = 0; ni < 2; ++ni) {
        const int r = wn + ni * 16 + j;
        const int el = r * 64 + (koff ^ ((r & 7) << 3));
        bh[ni] = *reinterpret_cast<const s16x8*>(&Whi[el]);
        bl[ni] = *reinterpret_cast<const s16x8*>(&Wlo[el]);
      }
#pragma unroll
      for (int mi = 0; mi < 4; ++mi)
#pragma unroll
        for (int ni = 0; ni < 2; ++ni) {
          acc[mi][ni] = __builtin_amdgcn_mfma_f32_16x16x32_bf16(ah[mi], bh[ni], acc[mi][ni], 0, 0, 0);
          acc[mi][ni] = __builtin_amdgcn_mfma_f32_16x16x32_bf16(ah[mi], bl[ni], acc[mi][ni], 0, 0, 0);
        }
    }
  }

  if (z == 0) {
    // K: store hi only to (B,H,T,Hd)
#pragma unroll
    for (int ni = 0; ni < 2; ++ni) {
      const int colc = col0 + wn + ni * 16 + j;
      const float bj = Bp[colc];
      const int h = colc >> 6, hd = colc & 63;
#pragma unroll
      for (int mi = 0; mi < 4; ++mi)
#pragma unroll
        for (int r = 0; r < 4; ++r) {
          const int rowc = row0 + wm + mi * 16 + (g << 2) + r;
          const int b = rowc >> 11, t = rowc & 2047;
          const float v = acc[mi][ni][r] + bj;
          Khi[(((size_t)b * NHEADS + h) * SEQ + t) * HD + hd] = f2bf(v);
        }
    }
  } else {
    // V: transpose via LDS -> (B,H,Hd,T'), hi only, T-permuted
    __syncthreads();
#pragma unroll
    for (int ni = 0; ni < 2; ++ni) {
      const int hdl = wn + ni * 16 + j;
      const float bj = Bp[col0 + hdl];
#pragma unroll
      for (int mi = 0; mi < 4; ++mi)
#pragma unroll
        for (int r = 0; r < 4; ++r) {
          const int lt = wm + mi * 16 + (g << 2) + r;
          const float v = acc[mi][ni][r] + bj;
          const int el = lt * 64 + (hdl ^ ((lt & 7) << 3));
          Xh[el] = f2bf(v);
        }
    }
    __syncthreads();
    const int b = row0 >> 11, h = col0 >> 6;
    const int tbase = row0 & 2047;
#pragma unroll
    for (int c = 0; c < 4; ++c) {
      const int chunk = c * 256 + tid;
      const int hd = chunk >> 4;
      const int t0 = (chunk & 15) * 8;
      u16x8 vh;
#pragma unroll
      for (int i = 0; i < 8; ++i) {
        const int p = t0 + i;
        const int lt = (p & ~15) | ((p & 3) + (((p >> 2) & 1) << 3) + (((p >> 3) & 1) << 2));
        const int el = lt * 64 + (hd ^ ((lt & 7) << 3));
        vh[i] = Xh[el];
      }
      const size_t off = (((size_t)b * NHEADS + h) * HD + hd) * SEQ + tbase + t0;
      *reinterpret_cast<u16x8*>(&Vthi[off]) = vh;
    }
  }
}

// ---------------------------------------------------------------------------
// Output projection: 64-row tiles -> 1024 blocks (4 blocks/CU). 100%
// global_load_lds staging. (r15 body, unchanged.)
// ---------------------------------------------------------------------------
__global__ __launch_bounds__(256, 4) void out_proj(
    const unsigned short* __restrict__ AOhi, const unsigned short* __restrict__ AOlo,
    const unsigned short* __restrict__ Woh,  const unsigned short* __restrict__ Wol,
    const float* __restrict__ bias, float* __restrict__ out)
{
  __shared__ unsigned short Xhi[64 * 64], Xlo[64 * 64];
  __shared__ unsigned short Whi[64 * 64], Wlo[64 * 64];

  const int tid  = threadIdx.x;
  const int lane = tid & 63;
  const int wave = tid >> 6;
  const int g = lane >> 4, j = lane & 15;
  const int wm = (wave >> 1) * 32;
  const int wn = (wave & 1) * 32;
  const int row0 = blockIdx.x * 64;
  const int col0 = blockIdx.y * 64;

  f32x4 acc[2][2];
#pragma unroll
  for (int mi = 0; mi < 2; ++mi)
#pragma unroll
    for (int ni = 0; ni < 2; ++ni) acc[mi][ni] = (f32x4)0.f;

  const int arow = wave * 16 + (lane >> 3);
  const int akg  = (lane & 7) ^ ((lane >> 3) & 7);
  const unsigned short* srcAh = AOhi + (size_t)(row0 + arow) * FEAT + akg * 8;
  const unsigned short* srcAl = AOlo + (size_t)(row0 + arow) * FEAT + akg * 8;
  const unsigned short* srcWh = Woh + (size_t)(col0 + arow) * FEAT + akg * 8;
  const unsigned short* srcWl = Wol + (size_t)(col0 + arow) * FEAT + akg * 8;

  for (int kt = 0; kt < FEAT; kt += 64) {
    __syncthreads();
    glds16(srcAh + kt,        &Xhi[(wave * 16) * 64]);
    glds16(srcAh + kt + 4096, &Xhi[(wave * 16 + 8) * 64]);
    glds16(srcAl + kt,        &Xlo[(wave * 16) * 64]);
    glds16(srcAl + kt + 4096, &Xlo[(wave * 16 + 8) * 64]);
    glds16(srcWh + kt,        &Whi[(wave * 16) * 64]);
    glds16(srcWh + kt + 4096, &Whi[(wave * 16 + 8) * 64]);
    glds16(srcWl + kt,        &Wlo[(wave * 16) * 64]);
    glds16(srcWl + kt + 4096, &Wlo[(wave * 16 + 8) * 64]);
    asm volatile("s_waitcnt vmcnt(0)" ::: "memory");
    __syncthreads();

#pragma unroll
    for (int c = 0; c < 2; ++c) {
      const int koff = c * 32 + g * 8;
      s16x8 ah[2], al[2], bh[2], bl[2];
#pragma unroll
      for (int mi = 0; mi < 2; ++mi) {
        const int r = wm + mi * 16 + j;
        const int el = r * 64 + (koff ^ ((r & 7) << 3));
        ah[mi] = *reinterpret_cast<const s16x8*>(&Xhi[el]);
        al[mi] = *reinterpret_cast<const s16x8*>(&Xlo[el]);
      }
#pragma unroll
      for (int ni = 0; ni < 2; ++ni) {
        const int r = wn + ni * 16 + j;
        const int el = r * 64 + (koff ^ ((r & 7) << 3));
        bh[ni] = *reinterpret_cast<const s16x8*>(&Whi[el]);
        bl[ni] = *reinterpret_cast<const s16x8*>(&Wlo[el]);
      }
#pragma unroll
      for (int mi = 0; mi < 2; ++mi)
#pragma unroll
        for (int ni = 0; ni < 2; ++ni) {
          acc[mi][ni] = __builtin_amdgcn_mfma_f32_16x16x32_bf16(ah[mi], bh[ni], acc[mi][ni], 0, 0, 0);
          acc[mi][ni] = __builtin_amdgcn_mfma_f32_16x16x32_bf16(ah[mi], bl[ni], acc[mi][ni], 0, 0, 0);
          acc[mi][ni] = __builtin_amdgcn_mfma_f32_16x16x32_bf16(al[mi], bh[ni], acc[mi][ni], 0, 0, 0);
        }
    }
  }

#pragma unroll
  for (int ni = 0; ni < 2; ++ni) {
    const int colc = col0 + wn + ni * 16 + j;
    const float bj = bias[colc];
#pragma unroll
    for (int mi = 0; mi < 2; ++mi)
#pragma unroll
      for (int r = 0; r < 4; ++r) {
        const int rowc = row0 + wm + mi * 16 + (g << 2) + r;
        out[(size_t)rowc * FEAT + colc] = acc[mi][ni][r] + bj;
      }
  }
}

// ---------------------------------------------------------------------------
// Flash attention (r13/r15 body, known-good): 3-buffer counted-vmcnt LDS
// pipeline, KVBLK=64, QK^T bf16-K x split-Q in two chains, PV hi-only with
// permuted-V, native exp2, deferred-l, conditional pm swap.
// ---------------------------------------------------------------------------
__global__ __launch_bounds__(256, 3) void attn_pipe(
    const unsigned short* __restrict__ Qhi, const unsigned short* __restrict__ Qlo,
    const unsigned short* __restrict__ Khi,
    const unsigned short* __restrict__ Vthi,
    unsigned short* __restrict__ AOhi, unsigned short* __restrict__ AOlo)
{
  __shared__ unsigned short Kh_s[3][4096];
  __shared__ unsigned short Vh_s[3][4096];
  __shared__ float bcast[4][32];

  const int tid = threadIdx.x, lane = tid & 63, wave = tid >> 6;
  const int hfl = lane >> 5;
  const int l31 = lane & 31;

  const int bid = blockIdx.x;
  const int swz = (bid & 7) * 64 + (bid >> 3);
  const int qt  = swz & 15;
  const int bh  = swz >> 4;
  const int b = bh >> 3, h = bh & 7;

  const int q0 = qt * 128 + wave * 32;
  const size_t kvbase = (size_t)bh * SEQ * HD;

  s16x8 qh[4], ql[4];
  {
    const size_t qoff = kvbase + (size_t)(q0 + l31) * HD + hfl * 8;
#pragma unroll
    for (int c = 0; c < 4; ++c) {
      qh[c] = *reinterpret_cast<const s16x8*>(&Qhi[qoff + c * 16]);
      ql[c] = *reinterpret_cast<const s16x8*>(&Qlo[qoff + c * 16]);
    }
  }

  f32x16 oacc0 = (f32x16)0.f, oacc1 = (f32x16)0.f;
  float m = -INFINITY, lsum = 0.f;

  const int ck  = tid >> 3;
  const int ksl = (tid & 7) ^ (ck & 7);
  const unsigned short* sKh = Khi + kvbase + (size_t)ck * HD + ksl * 8;
  const int vr  = tid >> 3;
  const int vsl = (tid & 7) ^ (vr & 7);
  const int vhd = vr + (vsl >> 2) * 32;
  const int vk0 = (vsl & 3) * 8;
  const unsigned short* sVh = Vthi + kvbase + (size_t)vhd * SEQ + vk0;
  const int wq = wave * 512;

  const int krow = l31 * 64;
  const int ksw  = l31 & 7;

  auto stage = [&](int tt, int bi) {
    const size_t ko = (size_t)tt * 64 * HD;
    const int    vo = tt * 64;
    glds16(sKh + ko,           &Kh_s[bi][wq]);
    glds16(sKh + ko + 32 * HD, &Kh_s[bi][2048 + wq]);
    glds16(sVh + vo,           &Vh_s[bi][wq]);
    glds16(sVh + vo + 32,      &Vh_s[bi][2048 + wq]);
  };

  stage(0, 0);
  stage(1, 1);

  const int NT = SEQ / 64;   // 32
  int cur = 0;
  for (int t = 0; t < NT; ++t) {
    if (t < NT - 1) {
      asm volatile("s_waitcnt vmcnt(4)" ::: "memory");
    } else {
      asm volatile("s_waitcnt vmcnt(0)" ::: "memory");
    }
    __syncthreads();
    if (t + 2 < NT) {
      int nb = cur + 2; if (nb >= 3) nb -= 3;
      stage(t + 2, nb);
    }
    __builtin_amdgcn_sched_barrier(0);

#pragma unroll
    for (int sub = 0; sub < 2; ++sub) {
      const int sb = sub * 2048;

      s16x8 KH[4];
#pragma unroll
      for (int c = 0; c < 4; ++c) {
        const int idx = sb + krow + ((((c << 1) | hfl)) ^ ksw) * 8;
        KH[c] = *reinterpret_cast<const s16x8*>(&Kh_s[cur][idx]);
      }

      f32x16 stA = (f32x16)0.f, stB = (f32x16)0.f;
      __builtin_amdgcn_s_setprio(1);
#pragma unroll
      for (int c = 0; c < 2; ++c) {
        stA = __builtin_amdgcn_mfma_f32_32x32x16_bf16(KH[c], qh[c], stA, 0, 0, 0);
        stA = __builtin_amdgcn_mfma_f32_32x32x16_bf16(KH[c], ql[c], stA, 0, 0, 0);
        stB = __builtin_amdgcn_mfma_f32_32x32x16_bf16(KH[2 + c], qh[2 + c], stB, 0, 0, 0);
        stB = __builtin_amdgcn_mfma_f32_32x32x16_bf16(KH[2 + c], ql[2 + c], stB, 0, 0, 0);
      }
      __builtin_amdgcn_s_setprio(0);
      f32x16 st;
#pragma unroll
      for (int r = 0; r < 16; ++r) st[r] = stA[r] + stB[r];

      s16x8 V0h[2], V1h[2];
#pragma unroll
      for (int c = 0; c < 2; ++c) {
        const int i0 = sb + krow + ((((c << 1) | hfl)) ^ ksw) * 8;
        const int i1 = sb + krow + (((4 | (c << 1) | hfl)) ^ ksw) * 8;
        V0h[c] = *reinterpret_cast<const s16x8*>(&Vh_s[cur][i0]);
        V1h[c] = *reinterpret_cast<const s16x8*>(&Vh_s[cur][i1]);
      }

      const float a0 = fmaxf(fmaxf(st[0], st[1]), st[2]);
      const float a1 = fmaxf(fmaxf(st[3], st[4]), st[5]);
      const float a2 = fmaxf(fmaxf(st[6], st[7]), st[8]);
      const float a3 = fmaxf(fmaxf(st[9], st[10]), st[11]);
      const float a4 = fmaxf(fmaxf(st[12], st[13]), st[14]);
      const float pm = fmaxf(fmaxf(fmaxf(a0, a1), a2),
                             fmaxf(fmaxf(a3, a4), st[15]));

      if (__any(pm > m + 8.f)) {
        const float pmf  = fmaxf(pm, __shfl_xor(pm, 32));
        const float mnew = fmaxf(m, pmf);
        const float corr = EX2(m - mnew);
        m = mnew; lsum *= corr;
        if (lane < 32) bcast[wave][l31] = corr;
        f32x4 c4[4];
#pragma unroll
        for (int rq = 0; rq < 4; ++rq)
          c4[rq] = *reinterpret_cast<const f32x4*>(&bcast[wave][rq * 8 + hfl * 4]);
#pragma unroll
        for (int r = 0; r < 16; ++r) {
          const float cc = c4[r >> 2][r & 3];
          oacc0[r] *= cc; oacc1[r] *= cc;
        }
      }

#pragma unroll
      for (int r = 0; r < 16; ++r) st[r] = EX2(st[r] - m);
      {
        float s0 = (st[0] + st[1]) + (st[2] + st[3]);
        float s1 = (st[4] + st[5]) + (st[6] + st[7]);
        float s2 = (st[8] + st[9]) + (st[10] + st[11]);
        float s3 = (st[12] + st[13]) + (st[14] + st[15]);
        lsum += (s0 + s1) + (s2 + s3);
      }

      unsigned int wh[8];
#pragma unroll
      for (int p = 0; p < 8; ++p)
        asm("v_cvt_pk_bf16_f32 %0, %1, %2" : "=v"(wh[p]) : "v"(st[2 * p]), "v"(st[2 * p + 1]));
      const s16x8 pa0h = __builtin_bit_cast(s16x8, (u32x4){wh[0], wh[1], wh[2], wh[3]});
      const s16x8 pa1h = __builtin_bit_cast(s16x8, (u32x4){wh[4], wh[5], wh[6], wh[7]});

      __builtin_amdgcn_s_setprio(1);
      oacc0 = __builtin_amdgcn_mfma_f32_32x32x16_bf16(pa0h, V0h[0], oacc0, 0, 0, 0);
      oacc0 = __builtin_amdgcn_mfma_f32_32x32x16_bf16(pa1h, V0h[1], oacc0, 0, 0, 0);
      oacc1 = __builtin_amdgcn_mfma_f32_32x32x16_bf16(pa0h, V1h[0], oacc1, 0, 0, 0);
      oacc1 = __builtin_amdgcn_mfma_f32_32x32x16_bf16(pa1h, V1h[1], oacc1, 0, 0, 0);
      __builtin_amdgcn_s_setprio(0);
    }

    cur += 1; if (cur >= 3) cur -= 3;
  }

  const float lf = lsum + __shfl_xor(lsum, 32);
  if (lane < 32) bcast[wave][l31] = 1.f / lf;
  __syncthreads();
  f32x4 i4[4];
#pragma unroll
  for (int rq = 0; rq < 4; ++rq)
    i4[rq] = *reinterpret_cast<const f32x4*>(&bcast[wave][rq * 8 + hfl * 4]);

#pragma unroll
  for (int r = 0; r < 16; ++r) {
    const int q = q0 + (r & 3) + 8 * (r >> 2) + 4 * hfl;
    const float inv = i4[r >> 2][r & 3];
    const size_t idx = ((size_t)b * SEQ + q) * FEAT + h * HD + l31;
    unsigned short hh, ll;
    split2(oacc0[r] * inv, hh, ll);
    AOhi[idx] = hh; AOlo[idx] = ll;
    split2(oacc1[r] * inv, hh, ll);
    AOhi[idx + 32] = hh; AOlo[idx + 32] = ll;
  }
}

extern "C" void kernel_launch(void* const* d_in, const int* in_sizes, int n_in,
                              void* d_out, int out_size, void* d_ws, size_t ws_size,
                              hipStream_t stream) {
  const float* x_cur  = (const float*)d_in[0];
  const float* x_past = (const float*)d_in[1];
  const float* wq = (const float*)d_in[2];
  const float* bq = (const float*)d_in[3];
  const float* wk = (const float*)d_in[4];
  const float* bk = (const float*)d_in[5];
  const float* wv = (const float*)d_in[6];
  const float* bv = (const float*)d_in[7];
  const float* wo = (const float*)d_in[8];
  const float* bo = (const float*)d_in[9];
  float* out = (float*)d_out;

  const size_t n = (size_t)NROWS * FEAT;   // 4,194,304
  unsigned short* Qhi  = (unsigned short*)d_ws;
  unsigned short* Qlo  = Qhi + n;
  unsigned short* Khi  = Qhi + 2 * n;
  unsigned short* Xphi = Qhi + 3 * n;      // old Klo slot (free since r13)
  unsigned short* Vthi = Qhi + 4 * n;
  unsigned short* Wsp  = Qhi + 5 * n;
  unsigned short* AOhi = Qhi + 6 * n;
  unsigned short* AOlo = Qhi + 7 * n;

  dim3 block(256);
  presplit_w<<<dim3(512), block, 0, stream>>>(wq, wk, wv, wo, Wsp);
  presplit_x<<<dim3(NROWS * FEAT / 2048), block, 0, stream>>>(x_past, Xphi);

  q_proj<<<dim3(NROWS / 128, FEAT / 64), block, 0, stream>>>(x_cur, Wsp, bq, Qhi, Qlo);
  kv_proj<<<dim3(NROWS / 128, FEAT / 64, 2), block, 0, stream>>>(Xphi, Wsp, bk, bv, Khi, Vthi);

  attn_pipe<<<dim3(512), block, 0, stream>>>(Qhi, Qlo, Khi, Vthi, AOhi, AOlo);

  dim3 gout(NROWS / 64, FEAT / 64);
  out_proj<<<gout, block, 0, stream>>>(AOhi, AOlo, Wsp + 3 * 524288,
                                       Wsp + 3 * 524288 + 262144, bo, out);
}

// Round 17
// 111.440 us; speedup vs baseline: 2.9376x; 1.1893x over previous
//
#include <hip/hip_runtime.h>
#include <math.h>

#define BATCH 4
#define SEQ 2048
#define FEAT 512
#define NHEADS 8
#define HD 64
#define NROWS (BATCH*SEQ)   // 8192
#define QSCALE 0.18033688011112042f   // log2(e)/8

typedef __attribute__((ext_vector_type(4)))  float f32x4;
typedef __attribute__((ext_vector_type(16))) float f32x16;
typedef __attribute__((ext_vector_type(8)))  short s16x8;
typedef __attribute__((ext_vector_type(8)))  unsigned short u16x8;
typedef __attribute__((ext_vector_type(4)))  unsigned int u32x4;
typedef __attribute__((ext_vector_type(2)))  unsigned int u32x2;

#if __has_builtin(__builtin_amdgcn_exp2f)
#define EX2(x) __builtin_amdgcn_exp2f(x)
#else
#define EX2(x) __expf((x) * 0.6931471805599453f)
#endif

static __device__ __forceinline__ unsigned short f2bf(float x) {
  unsigned int u = __builtin_bit_cast(unsigned int, x);
  unsigned int r = (u + 0x7FFFu + ((u >> 16) & 1u)) >> 16;
  return (unsigned short)r;
}
static __device__ __forceinline__ float bf2f(unsigned short h) {
  unsigned int u = ((unsigned int)h) << 16;
  return __builtin_bit_cast(float, u);
}
static __device__ __forceinline__ void split2(float x, unsigned short& h, unsigned short& l) {
  h = f2bf(x);
  l = f2bf(x - bf2f(h));
}

// async global->LDS, 16B per lane; dest = wave-uniform base + lane*16
static __device__ __forceinline__ void glds16(const unsigned short* g, unsigned short* l) {
  __builtin_amdgcn_global_load_lds(
      (const __attribute__((address_space(1))) unsigned int*)g,
      (__attribute__((address_space(3))) unsigned int*)l,
      16, 0, 0);
}

// ---------------------------------------------------------------------------
// Pre-split the four weight matrices into bf16 hi/lo.
// ---------------------------------------------------------------------------
__global__ __launch_bounds__(256) void presplit_w(
    const float* __restrict__ wq, const float* __restrict__ wk,
    const float* __restrict__ wv, const float* __restrict__ wo,
    unsigned short* __restrict__ Wsp)
{
  const int mat = blockIdx.x >> 7;
  const int chunk = ((blockIdx.x & 127) * 256 + threadIdx.x) * 8;
  const float* src = (mat == 0) ? wq : (mat == 1) ? wk : (mat == 2) ? wv : wo;
  unsigned short* hi = Wsp + (size_t)mat * 524288;
  unsigned short* lo = hi + 262144;
  const f32x4 a = *reinterpret_cast<const f32x4*>(&src[chunk]);
  const f32x4 b = *reinterpret_cast<const f32x4*>(&src[chunk + 4]);
  u16x8 h8, l8;
#pragma unroll
  for (int i = 0; i < 4; ++i) { unsigned short hh, ll; split2(a[i], hh, ll); h8[i] = hh; l8[i] = ll; }
#pragma unroll
  for (int i = 0; i < 4; ++i) { unsigned short hh, ll; split2(b[i], hh, ll); h8[4 + i] = hh; l8[4 + i] = ll; }
  *reinterpret_cast<u16x8*>(&hi[chunk]) = h8;
  *reinterpret_cast<u16x8*>(&lo[chunk]) = l8;
}

// ---------------------------------------------------------------------------
// Pre-round x_current and x_past to bf16 (hi only).
// ---------------------------------------------------------------------------
__global__ __launch_bounds__(256) void presplit_x2(
    const float* __restrict__ xc, const float* __restrict__ xp,
    unsigned short* __restrict__ Xchi, unsigned short* __restrict__ Xphi)
{
  const float* src = blockIdx.y ? xp : xc;
  unsigned short* dst = blockIdx.y ? Xphi : Xchi;
  const int chunk = (blockIdx.x * 256 + threadIdx.x) * 8;
  const f32x4 a = *reinterpret_cast<const f32x4*>(&src[chunk]);
  const f32x4 b = *reinterpret_cast<const f32x4*>(&src[chunk + 4]);
  u16x8 h8;
#pragma unroll
  for (int i = 0; i < 4; ++i) h8[i] = f2bf(a[i]);
#pragma unroll
  for (int i = 0; i < 4; ++i) h8[4 + i] = f2bf(b[i]);
  *reinterpret_cast<u16x8*>(&dst[chunk]) = h8;
}

// ---------------------------------------------------------------------------
// Unified QKV projection from bf16 X (hi only). 100% global_load_lds staging,
// 2 MFMA per acc. z=0: Q (scale log2e/8) -> (B,H,T,Hd) hi.
// z=1: K -> (B,H,T,Hd) hi. z=2: V -> (B,H,Hd,T') hi, T' permuted per
// 16-group. LDS 32KB -> 4 blocks/CU.
// ---------------------------------------------------------------------------
__global__ __launch_bounds__(256, 4) void qkv_proj(
    const unsigned short* __restrict__ Xchi, const unsigned short* __restrict__ Xphi,
    const unsigned short* __restrict__ Wsp,
    const float* __restrict__ bq, const float* __restrict__ bk,
    const float* __restrict__ bv,
    unsigned short* __restrict__ Qhi, unsigned short* __restrict__ Khi,
    unsigned short* __restrict__ Vthi)
{
  __shared__ unsigned short Xh[128 * 64];                 // 16KB
  __shared__ unsigned short Whi[64 * 64], Wlo[64 * 64];   // 16KB

  const int z = blockIdx.z;   // 0=Q, 1=K, 2=V
  const unsigned short* Xsrc = (z == 0) ? Xchi : Xphi;
  const unsigned short* Wh_g = Wsp + (size_t)z * 524288;
  const unsigned short* Wl_g = Wh_g + 262144;
  const float* Bp = (z == 0) ? bq : (z == 1) ? bk : bv;
  const float scale = (z == 0) ? QSCALE : 1.0f;

  const int tid  = threadIdx.x;
  const int lane = tid & 63;
  const int wave = tid >> 6;
  const int g = lane >> 4, j = lane & 15;
  const int wm = (wave >> 1) * 64;
  const int wn = (wave & 1) * 32;
  const int row0 = blockIdx.x * 128;
  const int col0 = blockIdx.y * 64;

  f32x4 acc[4][2];
#pragma unroll
  for (int mi = 0; mi < 4; ++mi)
#pragma unroll
    for (int ni = 0; ni < 2; ++ni) acc[mi][ni] = (f32x4)0.f;

  const int xrow = wave * 32 + (lane >> 3);
  const int xkg  = (lane & 7) ^ ((lane >> 3) & 7);
  const unsigned short* srcX = Xsrc + (size_t)(row0 + xrow) * FEAT + xkg * 8;
  const int wrow = wave * 16 + (lane >> 3);
  const unsigned short* srcWh = Wh_g + (size_t)(col0 + wrow) * FEAT + xkg * 8;
  const unsigned short* srcWl = Wl_g + (size_t)(col0 + wrow) * FEAT + xkg * 8;

  for (int kt = 0; kt < FEAT; kt += 64) {
    __syncthreads();
#pragma unroll
    for (int c = 0; c < 4; ++c)
      glds16(srcX + kt + c * 4096, &Xh[(wave * 32 + c * 8) * 64]);
    glds16(srcWh + kt,        &Whi[(wave * 16) * 64]);
    glds16(srcWh + kt + 4096, &Whi[(wave * 16 + 8) * 64]);
    glds16(srcWl + kt,        &Wlo[(wave * 16) * 64]);
    glds16(srcWl + kt + 4096, &Wlo[(wave * 16 + 8) * 64]);
    asm volatile("s_waitcnt vmcnt(0)" ::: "memory");
    __syncthreads();

#pragma unroll
    for (int c = 0; c < 2; ++c) {
      const int koff = c * 32 + g * 8;
      s16x8 ah[4], bh[2], bl[2];
#pragma unroll
      for (int mi = 0; mi < 4; ++mi) {
        const int r = wm + mi * 16 + j;
        const int el = r * 64 + (koff ^ ((r & 7) << 3));
        ah[mi] = *reinterpret_cast<const s16x8*>(&Xh[el]);
      }
#pragma unroll
      for (int ni = 0; ni < 2; ++ni) {
        const int r = wn + ni * 16 + j;
        const int el = r * 64 + (koff ^ ((r & 7) << 3));
        bh[ni] = *reinterpret_cast<const s16x8*>(&Whi[el]);
        bl[ni] = *reinterpret_cast<const s16x8*>(&Wlo[el]);
      }
#pragma unroll
      for (int mi = 0; mi < 4; ++mi)
#pragma unroll
        for (int ni = 0; ni < 2; ++ni) {
          acc[mi][ni] = __builtin_amdgcn_mfma_f32_16x16x32_bf16(ah[mi], bh[ni], acc[mi][ni], 0, 0, 0);
          acc[mi][ni] = __builtin_amdgcn_mfma_f32_16x16x32_bf16(ah[mi], bl[ni], acc[mi][ni], 0, 0, 0);
        }
    }
  }

  if (z < 2) {
    // Q or K: store hi only to (B,H,T,Hd)
    unsigned short* Out = (z == 0) ? Qhi : Khi;
#pragma unroll
    for (int ni = 0; ni < 2; ++ni) {
      const int colc = col0 + wn + ni * 16 + j;
      const float bj = Bp[colc];
      const int h = colc >> 6, hd = colc & 63;
#pragma unroll
      for (int mi = 0; mi < 4; ++mi)
#pragma unroll
        for (int r = 0; r < 4; ++r) {
          const int rowc = row0 + wm + mi * 16 + (g << 2) + r;
          const int b = rowc >> 11, t = rowc & 2047;
          const float v = (acc[mi][ni][r] + bj) * scale;
          Out[(((size_t)b * NHEADS + h) * SEQ + t) * HD + hd] = f2bf(v);
        }
    }
  } else {
    // V: transpose via LDS -> (B,H,Hd,T'), hi only, T-permuted
    __syncthreads();
#pragma unroll
    for (int ni = 0; ni < 2; ++ni) {
      const int hdl = wn + ni * 16 + j;
      const float bj = Bp[col0 + hdl];
#pragma unroll
      for (int mi = 0; mi < 4; ++mi)
#pragma unroll
        for (int r = 0; r < 4; ++r) {
          const int lt = wm + mi * 16 + (g << 2) + r;
          const float v = acc[mi][ni][r] + bj;
          const int el = lt * 64 + (hdl ^ ((lt & 7) << 3));
          Xh[el] = f2bf(v);
        }
    }
    __syncthreads();
    const int b = row0 >> 11, h = col0 >> 6;
    const int tbase = row0 & 2047;
#pragma unroll
    for (int c = 0; c < 4; ++c) {
      const int chunk = c * 256 + tid;
      const int hd = chunk >> 4;
      const int t0 = (chunk & 15) * 8;
      u16x8 vh;
#pragma unroll
      for (int i = 0; i < 8; ++i) {
        const int p = t0 + i;
        const int lt = (p & ~15) | ((p & 3) + (((p >> 2) & 1) << 3) + (((p >> 3) & 1) << 2));
        const int el = lt * 64 + (hd ^ ((lt & 7) << 3));
        vh[i] = Xh[el];
      }
      const size_t off = (((size_t)b * NHEADS + h) * HD + hd) * SEQ + tbase + t0;
      *reinterpret_cast<u16x8*>(&Vthi[off]) = vh;
    }
  }
}

// ---------------------------------------------------------------------------
// Output projection: 64-row tiles -> 1024 blocks (4 blocks/CU). 100%
// global_load_lds staging. 3-MFMA split (precision kept).
// ---------------------------------------------------------------------------
__global__ __launch_bounds__(256, 4) void out_proj(
    const unsigned short* __restrict__ AOhi, const unsigned short* __restrict__ AOlo,
    const unsigned short* __restrict__ Woh,  const unsigned short* __restrict__ Wol,
    const float* __restrict__ bias, float* __restrict__ out)
{
  __shared__ unsigned short Xhi[64 * 64], Xlo[64 * 64];
  __shared__ unsigned short Whi[64 * 64], Wlo[64 * 64];

  const int tid  = threadIdx.x;
  const int lane = tid & 63;
  const int wave = tid >> 6;
  const int g = lane >> 4, j = lane & 15;
  const int wm = (wave >> 1) * 32;
  const int wn = (wave & 1) * 32;
  const int row0 = blockIdx.x * 64;
  const int col0 = blockIdx.y * 64;

  f32x4 acc[2][2];
#pragma unroll
  for (int mi = 0; mi < 2; ++mi)
#pragma unroll
    for (int ni = 0; ni < 2; ++ni) acc[mi][ni] = (f32x4)0.f;

  const int arow = wave * 16 + (lane >> 3);
  const int akg  = (lane & 7) ^ ((lane >> 3) & 7);
  const unsigned short* srcAh = AOhi + (size_t)(row0 + arow) * FEAT + akg * 8;
  const unsigned short* srcAl = AOlo + (size_t)(row0 + arow) * FEAT + akg * 8;
  const unsigned short* srcWh = Woh + (size_t)(col0 + arow) * FEAT + akg * 8;
  const unsigned short* srcWl = Wol + (size_t)(col0 + arow) * FEAT + akg * 8;

  for (int kt = 0; kt < FEAT; kt += 64) {
    __syncthreads();
    glds16(srcAh + kt,        &Xhi[(wave * 16) * 64]);
    glds16(srcAh + kt + 4096, &Xhi[(wave * 16 + 8) * 64]);
    glds16(srcAl + kt,        &Xlo[(wave * 16) * 64]);
    glds16(srcAl + kt + 4096, &Xlo[(wave * 16 + 8) * 64]);
    glds16(srcWh + kt,        &Whi[(wave * 16) * 64]);
    glds16(srcWh + kt + 4096, &Whi[(wave * 16 + 8) * 64]);
    glds16(srcWl + kt,        &Wlo[(wave * 16) * 64]);
    glds16(srcWl + kt + 4096, &Wlo[(wave * 16 + 8) * 64]);
    asm volatile("s_waitcnt vmcnt(0)" ::: "memory");
    __syncthreads();

#pragma unroll
    for (int c = 0; c < 2; ++c) {
      const int koff = c * 32 + g * 8;
      s16x8 ah[2], al[2], bh[2], bl[2];
#pragma unroll
      for (int mi = 0; mi < 2; ++mi) {
        const int r = wm + mi * 16 + j;
        const int el = r * 64 + (koff ^ ((r & 7) << 3));
        ah[mi] = *reinterpret_cast<const s16x8*>(&Xhi[el]);
        al[mi] = *reinterpret_cast<const s16x8*>(&Xlo[el]);
      }
#pragma unroll
      for (int ni = 0; ni < 2; ++ni) {
        const int r = wn + ni * 16 + j;
        const int el = r * 64 + (koff ^ ((r & 7) << 3));
        bh[ni] = *reinterpret_cast<const s16x8*>(&Whi[el]);
        bl[ni] = *reinterpret_cast<const s16x8*>(&Wlo[el]);
      }
#pragma unroll
      for (int mi = 0; mi < 2; ++mi)
#pragma unroll
        for (int ni = 0; ni < 2; ++ni) {
          acc[mi][ni] = __builtin_amdgcn_mfma_f32_16x16x32_bf16(ah[mi], bh[ni], acc[mi][ni], 0, 0, 0);
          acc[mi][ni] = __builtin_amdgcn_mfma_f32_16x16x32_bf16(ah[mi], bl[ni], acc[mi][ni], 0, 0, 0);
          acc[mi][ni] = __builtin_amdgcn_mfma_f32_16x16x32_bf16(al[mi], bh[ni], acc[mi][ni], 0, 0, 0);
        }
    }
  }

#pragma unroll
  for (int ni = 0; ni < 2; ++ni) {
    const int colc = col0 + wn + ni * 16 + j;
    const float bj = bias[colc];
#pragma unroll
    for (int mi = 0; mi < 2; ++mi)
#pragma unroll
      for (int r = 0; r < 4; ++r) {
        const int rowc = row0 + wm + mi * 16 + (g << 2) + r;
        out[(size_t)rowc * FEAT + colc] = acc[mi][ni][r] + bj;
      }
  }
}

// ---------------------------------------------------------------------------
// Flash attention (r13 structure; QK^T now pure-bf16 4-MFMA single chain):
// 3-buffer counted-vmcnt LDS pipeline, KVBLK=64, PV hi-only with permuted-V,
// native exp2, deferred-l, conditional pm swap.
// ---------------------------------------------------------------------------
__global__ __launch_bounds__(256, 3) void attn_pipe(
    const unsigned short* __restrict__ Qhi,
    const unsigned short* __restrict__ Khi,
    const unsigned short* __restrict__ Vthi,
    unsigned short* __restrict__ AOhi, unsigned short* __restrict__ AOlo)
{
  __shared__ unsigned short Kh_s[3][4096];
  __shared__ unsigned short Vh_s[3][4096];
  __shared__ float bcast[4][32];

  const int tid = threadIdx.x, lane = tid & 63, wave = tid >> 6;
  const int hfl = lane >> 5;
  const int l31 = lane & 31;

  const int bid = blockIdx.x;
  const int swz = (bid & 7) * 64 + (bid >> 3);
  const int qt  = swz & 15;
  const int bh  = swz >> 4;
  const int b = bh >> 3, h = bh & 7;

  const int q0 = qt * 128 + wave * 32;
  const size_t kvbase = (size_t)bh * SEQ * HD;

  // Q B-fragments (bf16, pre-scaled by log2e/8 in proj)
  s16x8 qh[4];
  {
    const size_t qoff = kvbase + (size_t)(q0 + l31) * HD + hfl * 8;
#pragma unroll
    for (int c = 0; c < 4; ++c)
      qh[c] = *reinterpret_cast<const s16x8*>(&Qhi[qoff + c * 16]);
  }

  f32x16 oacc0 = (f32x16)0.f, oacc1 = (f32x16)0.f;
  float m = -INFINITY, lsum = 0.f;

  const int ck  = tid >> 3;
  const int ksl = (tid & 7) ^ (ck & 7);
  const unsigned short* sKh = Khi + kvbase + (size_t)ck * HD + ksl * 8;
  const int vr  = tid >> 3;
  const int vsl = (tid & 7) ^ (vr & 7);
  const int vhd = vr + (vsl >> 2) * 32;
  const int vk0 = (vsl & 3) * 8;
  const unsigned short* sVh = Vthi + kvbase + (size_t)vhd * SEQ + vk0;
  const int wq = wave * 512;

  const int krow = l31 * 64;
  const int ksw  = l31 & 7;

  auto stage = [&](int tt, int bi) {
    const size_t ko = (size_t)tt * 64 * HD;
    const int    vo = tt * 64;
    glds16(sKh + ko,           &Kh_s[bi][wq]);
    glds16(sKh + ko + 32 * HD, &Kh_s[bi][2048 + wq]);
    glds16(sVh + vo,           &Vh_s[bi][wq]);
    glds16(sVh + vo + 32,      &Vh_s[bi][2048 + wq]);
  };

  stage(0, 0);
  stage(1, 1);

  const int NT = SEQ / 64;   // 32
  int cur = 0;
  for (int t = 0; t < NT; ++t) {
    if (t < NT - 1) {
      asm volatile("s_waitcnt vmcnt(4)" ::: "memory");
    } else {
      asm volatile("s_waitcnt vmcnt(0)" ::: "memory");
    }
    __syncthreads();
    if (t + 2 < NT) {
      int nb = cur + 2; if (nb >= 3) nb -= 3;
      stage(t + 2, nb);
    }
    __builtin_amdgcn_sched_barrier(0);

#pragma unroll
    for (int sub = 0; sub < 2; ++sub) {
      const int sb = sub * 2048;

      s16x8 KH[4];
#pragma unroll
      for (int c = 0; c < 4; ++c) {
        const int idx = sb + krow + ((((c << 1) | hfl)) ^ ksw) * 8;
        KH[c] = *reinterpret_cast<const s16x8*>(&Kh_s[cur][idx]);
      }

      // ---- S^T = K(bf16) Q(bf16)^T, single 4-chain ----
      f32x16 st = (f32x16)0.f;
      __builtin_amdgcn_s_setprio(1);
#pragma unroll
      for (int c = 0; c < 4; ++c)
        st = __builtin_amdgcn_mfma_f32_32x32x16_bf16(KH[c], qh[c], st, 0, 0, 0);
      __builtin_amdgcn_s_setprio(0);

      s16x8 V0h[2], V1h[2];
#pragma unroll
      for (int c = 0; c < 2; ++c) {
        const int i0 = sb + krow + ((((c << 1) | hfl)) ^ ksw) * 8;
        const int i1 = sb + krow + (((4 | (c << 1) | hfl)) ^ ksw) * 8;
        V0h[c] = *reinterpret_cast<const s16x8*>(&Vh_s[cur][i0]);
        V1h[c] = *reinterpret_cast<const s16x8*>(&Vh_s[cur][i1]);
      }

      const float a0 = fmaxf(fmaxf(st[0], st[1]), st[2]);
      const float a1 = fmaxf(fmaxf(st[3], st[4]), st[5]);
      const float a2 = fmaxf(fmaxf(st[6], st[7]), st[8]);
      const float a3 = fmaxf(fmaxf(st[9], st[10]), st[11]);
      const float a4 = fmaxf(fmaxf(st[12], st[13]), st[14]);
      const float pm = fmaxf(fmaxf(fmaxf(a0, a1), a2),
                             fmaxf(fmaxf(a3, a4), st[15]));

      if (__any(pm > m + 8.f)) {
        const float pmf  = fmaxf(pm, __shfl_xor(pm, 32));
        const float mnew = fmaxf(m, pmf);
        const float corr = EX2(m - mnew);
        m = mnew; lsum *= corr;
        if (lane < 32) bcast[wave][l31] = corr;
        f32x4 c4[4];
#pragma unroll
        for (int rq = 0; rq < 4; ++rq)
          c4[rq] = *reinterpret_cast<const f32x4*>(&bcast[wave][rq * 8 + hfl * 4]);
#pragma unroll
        for (int r = 0; r < 16; ++r) {
          const float cc = c4[r >> 2][r & 3];
          oacc0[r] *= cc; oacc1[r] *= cc;
        }
      }

#pragma unroll
      for (int r = 0; r < 16; ++r) st[r] = EX2(st[r] - m);
      {
        float s0 = (st[0] + st[1]) + (st[2] + st[3]);
        float s1 = (st[4] + st[5]) + (st[6] + st[7]);
        float s2 = (st[8] + st[9]) + (st[10] + st[11]);
        float s3 = (st[12] + st[13]) + (st[14] + st[15]);
        lsum += (s0 + s1) + (s2 + s3);
      }

      unsigned int wh[8];
#pragma unroll
      for (int p = 0; p < 8; ++p)
        asm("v_cvt_pk_bf16_f32 %0, %1, %2" : "=v"(wh[p]) : "v"(st[2 * p]), "v"(st[2 * p + 1]));
      const s16x8 pa0h = __builtin_bit_cast(s16x8, (u32x4){wh[0], wh[1], wh[2], wh[3]});
      const s16x8 pa1h = __builtin_bit_cast(s16x8, (u32x4){wh[4], wh[5], wh[6], wh[7]});

      __builtin_amdgcn_s_setprio(1);
      oacc0 = __builtin_amdgcn_mfma_f32_32x32x16_bf16(pa0h, V0h[0], oacc0, 0, 0, 0);
      oacc0 = __builtin_amdgcn_mfma_f32_32x32x16_bf16(pa1h, V0h[1], oacc0, 0, 0, 0);
      oacc1 = __builtin_amdgcn_mfma_f32_32x32x16_bf16(pa0h, V1h[0], oacc1, 0, 0, 0);
      oacc1 = __builtin_amdgcn_mfma_f32_32x32x16_bf16(pa1h, V1h[1], oacc1, 0, 0, 0);
      __builtin_amdgcn_s_setprio(0);
    }

    cur += 1; if (cur >= 3) cur -= 3;
  }

  const float lf = lsum + __shfl_xor(lsum, 32);
  if (lane < 32) bcast[wave][l31] = 1.f / lf;
  __syncthreads();
  f32x4 i4[4];
#pragma unroll
  for (int rq = 0; rq < 4; ++rq)
    i4[rq] = *reinterpret_cast<const f32x4*>(&bcast[wave][rq * 8 + hfl * 4]);

#pragma unroll
  for (int r = 0; r < 16; ++r) {
    const int q = q0 + (r & 3) + 8 * (r >> 2) + 4 * hfl;
    const float inv = i4[r >> 2][r & 3];
    const size_t idx = ((size_t)b * SEQ + q) * FEAT + h * HD + l31;
    unsigned short hh, ll;
    split2(oacc0[r] * inv, hh, ll);
    AOhi[idx] = hh; AOlo[idx] = ll;
    split2(oacc1[r] * inv, hh, ll);
    AOhi[idx + 32] = hh; AOlo[idx + 32] = ll;
  }
}

extern "C" void kernel_launch(void* const* d_in, const int* in_sizes, int n_in,
                              void* d_out, int out_size, void* d_ws, size_t ws_size,
                              hipStream_t stream) {
  const float* x_cur  = (const float*)d_in[0];
  const float* x_past = (const float*)d_in[1];
  const float* wq = (const float*)d_in[2];
  const float* bq = (const float*)d_in[3];
  const float* wk = (const float*)d_in[4];
  const float* bk = (const float*)d_in[5];
  const float* wv = (const float*)d_in[6];
  const float* bv = (const float*)d_in[7];
  const float* wo = (const float*)d_in[8];
  const float* bo = (const float*)d_in[9];
  float* out = (float*)d_out;

  const size_t n = (size_t)NROWS * FEAT;   // 4,194,304
  unsigned short* Qhi  = (unsigned short*)d_ws;
  unsigned short* Xchi = Qhi + n;          // old Qlo slot
  unsigned short* Khi  = Qhi + 2 * n;
  unsigned short* Xphi = Qhi + 3 * n;
  unsigned short* Vthi = Qhi + 4 * n;
  unsigned short* Wsp  = Qhi + 5 * n;
  unsigned short* AOhi = Qhi + 6 * n;
  unsigned short* AOlo = Qhi + 7 * n;

  dim3 block(256);
  presplit_w<<<dim3(512), block, 0, stream>>>(wq, wk, wv, wo, Wsp);
  presplit_x2<<<dim3(NROWS * FEAT / 2048, 2), block, 0, stream>>>(x_cur, x_past, Xchi, Xphi);

  qkv_proj<<<dim3(NROWS / 128, FEAT / 64, 3), block, 0, stream>>>(
      Xchi, Xphi, Wsp, bq, bk, bv, Qhi, Khi, Vthi);

  attn_pipe<<<dim3(512), block, 0, stream>>>(Qhi, Khi, Vthi, AOhi, AOlo);

  dim3 gout(NROWS / 64, FEAT / 64);
  out_proj<<<gout, block, 0, stream>>>(AOhi, AOlo, Wsp + 3 * 524288,
                                       Wsp + 3 * 524288 + 262144, bo, out);
}

// Round 18
// 102.503 us; speedup vs baseline: 3.1937x; 1.0872x over previous
//
#include <hip/hip_runtime.h>
#include <math.h>

#define BATCH 4
#define SEQ 2048
#define FEAT 512
#define NHEADS 8
#define HD 64
#define NROWS (BATCH*SEQ)   // 8192
#define QSCALE 0.18033688011112042f   // log2(e)/8

typedef __attribute__((ext_vector_type(4)))  float f32x4;
typedef __attribute__((ext_vector_type(16))) float f32x16;
typedef __attribute__((ext_vector_type(8)))  short s16x8;
typedef __attribute__((ext_vector_type(8)))  unsigned short u16x8;
typedef __attribute__((ext_vector_type(4)))  unsigned int u32x4;

#if __has_builtin(__builtin_amdgcn_exp2f)
#define EX2(x) __builtin_amdgcn_exp2f(x)
#else
#define EX2(x) __expf((x) * 0.6931471805599453f)
#endif

static __device__ __forceinline__ unsigned short f2bf(float x) {
  unsigned int u = __builtin_bit_cast(unsigned int, x);
  unsigned int r = (u + 0x7FFFu + ((u >> 16) & 1u)) >> 16;
  return (unsigned short)r;
}
static __device__ __forceinline__ float bf2f(unsigned short h) {
  unsigned int u = ((unsigned int)h) << 16;
  return __builtin_bit_cast(float, u);
}
static __device__ __forceinline__ void split2(float x, unsigned short& h, unsigned short& l) {
  h = f2bf(x);
  l = f2bf(x - bf2f(h));
}

// async global->LDS, 16B per lane; dest = wave-uniform base + lane*16
static __device__ __forceinline__ void glds16(const unsigned short* g, unsigned short* l) {
  __builtin_amdgcn_global_load_lds(
      (const __attribute__((address_space(1))) unsigned int*)g,
      (__attribute__((address_space(3))) unsigned int*)l,
      16, 0, 0);
}

// ---------------------------------------------------------------------------
// Merged pre-split: blocks 0..511 split the 4 weight matrices (hi/lo);
// blocks 512..4607 round x_cur / x_past to bf16 hi.
// ---------------------------------------------------------------------------
__global__ __launch_bounds__(256) void presplit(
    const float* __restrict__ wq, const float* __restrict__ wk,
    const float* __restrict__ wv, const float* __restrict__ wo,
    const float* __restrict__ xc, const float* __restrict__ xp,
    unsigned short* __restrict__ Wsp,
    unsigned short* __restrict__ Xchi, unsigned short* __restrict__ Xphi)
{
  const int bid = blockIdx.x;
  if (bid < 512) {
    const int mat = bid >> 7;
    const int chunk = ((bid & 127) * 256 + threadIdx.x) * 8;
    const float* src = (mat == 0) ? wq : (mat == 1) ? wk : (mat == 2) ? wv : wo;
    unsigned short* hi = Wsp + (size_t)mat * 524288;
    unsigned short* lo = hi + 262144;
    const f32x4 a = *reinterpret_cast<const f32x4*>(&src[chunk]);
    const f32x4 b = *reinterpret_cast<const f32x4*>(&src[chunk + 4]);
    u16x8 h8, l8;
#pragma unroll
    for (int i = 0; i < 4; ++i) { unsigned short hh, ll; split2(a[i], hh, ll); h8[i] = hh; l8[i] = ll; }
#pragma unroll
    for (int i = 0; i < 4; ++i) { unsigned short hh, ll; split2(b[i], hh, ll); h8[4 + i] = hh; l8[4 + i] = ll; }
    *reinterpret_cast<u16x8*>(&hi[chunk]) = h8;
    *reinterpret_cast<u16x8*>(&lo[chunk]) = l8;
  } else {
    const int i = bid - 512;              // 0..4095
    const int half = i >> 11;             // 0 = xc, 1 = xp
    const int ib = i & 2047;
    const float* src = half ? xp : xc;
    unsigned short* dst = half ? Xphi : Xchi;
    const int chunk = (ib * 256 + threadIdx.x) * 8;
    const f32x4 a = *reinterpret_cast<const f32x4*>(&src[chunk]);
    const f32x4 b = *reinterpret_cast<const f32x4*>(&src[chunk + 4]);
    u16x8 h8;
#pragma unroll
    for (int ii = 0; ii < 4; ++ii) h8[ii] = f2bf(a[ii]);
#pragma unroll
    for (int ii = 0; ii < 4; ++ii) h8[4 + ii] = f2bf(b[ii]);
    *reinterpret_cast<u16x8*>(&dst[chunk]) = h8;
  }
}

// ---------------------------------------------------------------------------
// Unified QKV projection from bf16 X (hi only). 100% global_load_lds staging,
// 2 MFMA per acc. z=0: Q (scale log2e/8) -> (B,H,T,Hd) hi.
// z=1: K -> (B,H,T,Hd) hi. z=2: V -> (B,H,Hd,T') hi, T' permuted per
// 16-group. (r17 body, unchanged.)
// ---------------------------------------------------------------------------
__global__ __launch_bounds__(256, 4) void qkv_proj(
    const unsigned short* __restrict__ Xchi, const unsigned short* __restrict__ Xphi,
    const unsigned short* __restrict__ Wsp,
    const float* __restrict__ bq, const float* __restrict__ bk,
    const float* __restrict__ bv,
    unsigned short* __restrict__ Qhi, unsigned short* __restrict__ Khi,
    unsigned short* __restrict__ Vthi)
{
  __shared__ unsigned short Xh[128 * 64];
  __shared__ unsigned short Whi[64 * 64], Wlo[64 * 64];

  const int z = blockIdx.z;
  const unsigned short* Xsrc = (z == 0) ? Xchi : Xphi;
  const unsigned short* Wh_g = Wsp + (size_t)z * 524288;
  const unsigned short* Wl_g = Wh_g + 262144;
  const float* Bp = (z == 0) ? bq : (z == 1) ? bk : bv;
  const float scale = (z == 0) ? QSCALE : 1.0f;

  const int tid  = threadIdx.x;
  const int lane = tid & 63;
  const int wave = tid >> 6;
  const int g = lane >> 4, j = lane & 15;
  const int wm = (wave >> 1) * 64;
  const int wn = (wave & 1) * 32;
  const int row0 = blockIdx.x * 128;
  const int col0 = blockIdx.y * 64;

  f32x4 acc[4][2];
#pragma unroll
  for (int mi = 0; mi < 4; ++mi)
#pragma unroll
    for (int ni = 0; ni < 2; ++ni) acc[mi][ni] = (f32x4)0.f;

  const int xrow = wave * 32 + (lane >> 3);
  const int xkg  = (lane & 7) ^ ((lane >> 3) & 7);
  const unsigned short* srcX = Xsrc + (size_t)(row0 + xrow) * FEAT + xkg * 8;
  const int wrow = wave * 16 + (lane >> 3);
  const unsigned short* srcWh = Wh_g + (size_t)(col0 + wrow) * FEAT + xkg * 8;
  const unsigned short* srcWl = Wl_g + (size_t)(col0 + wrow) * FEAT + xkg * 8;

  for (int kt = 0; kt < FEAT; kt += 64) {
    __syncthreads();
#pragma unroll
    for (int c = 0; c < 4; ++c)
      glds16(srcX + kt + c * 4096, &Xh[(wave * 32 + c * 8) * 64]);
    glds16(srcWh + kt,        &Whi[(wave * 16) * 64]);
    glds16(srcWh + kt + 4096, &Whi[(wave * 16 + 8) * 64]);
    glds16(srcWl + kt,        &Wlo[(wave * 16) * 64]);
    glds16(srcWl + kt + 4096, &Wlo[(wave * 16 + 8) * 64]);
    asm volatile("s_waitcnt vmcnt(0)" ::: "memory");
    __syncthreads();

#pragma unroll
    for (int c = 0; c < 2; ++c) {
      const int koff = c * 32 + g * 8;
      s16x8 ah[4], bh[2], bl[2];
#pragma unroll
      for (int mi = 0; mi < 4; ++mi) {
        const int r = wm + mi * 16 + j;
        const int el = r * 64 + (koff ^ ((r & 7) << 3));
        ah[mi] = *reinterpret_cast<const s16x8*>(&Xh[el]);
      }
#pragma unroll
      for (int ni = 0; ni < 2; ++ni) {
        const int r = wn + ni * 16 + j;
        const int el = r * 64 + (koff ^ ((r & 7) << 3));
        bh[ni] = *reinterpret_cast<const s16x8*>(&Whi[el]);
        bl[ni] = *reinterpret_cast<const s16x8*>(&Wlo[el]);
      }
#pragma unroll
      for (int mi = 0; mi < 4; ++mi)
#pragma unroll
        for (int ni = 0; ni < 2; ++ni) {
          acc[mi][ni] = __builtin_amdgcn_mfma_f32_16x16x32_bf16(ah[mi], bh[ni], acc[mi][ni], 0, 0, 0);
          acc[mi][ni] = __builtin_amdgcn_mfma_f32_16x16x32_bf16(ah[mi], bl[ni], acc[mi][ni], 0, 0, 0);
        }
    }
  }

  if (z < 2) {
    unsigned short* Out = (z == 0) ? Qhi : Khi;
#pragma unroll
    for (int ni = 0; ni < 2; ++ni) {
      const int colc = col0 + wn + ni * 16 + j;
      const float bj = Bp[colc];
      const int h = colc >> 6, hd = colc & 63;
#pragma unroll
      for (int mi = 0; mi < 4; ++mi)
#pragma unroll
        for (int r = 0; r < 4; ++r) {
          const int rowc = row0 + wm + mi * 16 + (g << 2) + r;
          const int b = rowc >> 11, t = rowc & 2047;
          const float v = (acc[mi][ni][r] + bj) * scale;
          Out[(((size_t)b * NHEADS + h) * SEQ + t) * HD + hd] = f2bf(v);
        }
    }
  } else {
    __syncthreads();
#pragma unroll
    for (int ni = 0; ni < 2; ++ni) {
      const int hdl = wn + ni * 16 + j;
      const float bj = Bp[col0 + hdl];
#pragma unroll
      for (int mi = 0; mi < 4; ++mi)
#pragma unroll
        for (int r = 0; r < 4; ++r) {
          const int lt = wm + mi * 16 + (g << 2) + r;
          const float v = acc[mi][ni][r] + bj;
          const int el = lt * 64 + (hdl ^ ((lt & 7) << 3));
          Xh[el] = f2bf(v);
        }
    }
    __syncthreads();
    const int b = row0 >> 11, h = col0 >> 6;
    const int tbase = row0 & 2047;
#pragma unroll
    for (int c = 0; c < 4; ++c) {
      const int chunk = c * 256 + tid;
      const int hd = chunk >> 4;
      const int t0 = (chunk & 15) * 8;
      u16x8 vh;
#pragma unroll
      for (int i = 0; i < 8; ++i) {
        const int p = t0 + i;
        const int lt = (p & ~15) | ((p & 3) + (((p >> 2) & 1) << 3) + (((p >> 3) & 1) << 2));
        const int el = lt * 64 + (hd ^ ((lt & 7) << 3));
        vh[i] = Xh[el];
      }
      const size_t off = (((size_t)b * NHEADS + h) * HD + hd) * SEQ + tbase + t0;
      *reinterpret_cast<u16x8*>(&Vthi[off]) = vh;
    }
  }
}

// ---------------------------------------------------------------------------
// Output projection from bf16-hi AO: 2 MFMA per acc (AO-lo dropped).
// 64-row tiles -> 1024 blocks, 24KB LDS.
// ---------------------------------------------------------------------------
__global__ __launch_bounds__(256, 4) void out_proj(
    const unsigned short* __restrict__ AOhi,
    const unsigned short* __restrict__ Woh,  const unsigned short* __restrict__ Wol,
    const float* __restrict__ bias, float* __restrict__ out)
{
  __shared__ unsigned short Xh[64 * 64];
  __shared__ unsigned short Whi[64 * 64], Wlo[64 * 64];

  const int tid  = threadIdx.x;
  const int lane = tid & 63;
  const int wave = tid >> 6;
  const int g = lane >> 4, j = lane & 15;
  const int wm = (wave >> 1) * 32;
  const int wn = (wave & 1) * 32;
  const int row0 = blockIdx.x * 64;
  const int col0 = blockIdx.y * 64;

  f32x4 acc[2][2];
#pragma unroll
  for (int mi = 0; mi < 2; ++mi)
#pragma unroll
    for (int ni = 0; ni < 2; ++ni) acc[mi][ni] = (f32x4)0.f;

  const int arow = wave * 16 + (lane >> 3);
  const int akg  = (lane & 7) ^ ((lane >> 3) & 7);
  const unsigned short* srcA  = AOhi + (size_t)(row0 + arow) * FEAT + akg * 8;
  const unsigned short* srcWh = Woh + (size_t)(col0 + arow) * FEAT + akg * 8;
  const unsigned short* srcWl = Wol + (size_t)(col0 + arow) * FEAT + akg * 8;

  for (int kt = 0; kt < FEAT; kt += 64) {
    __syncthreads();
    glds16(srcA + kt,         &Xh[(wave * 16) * 64]);
    glds16(srcA + kt + 4096,  &Xh[(wave * 16 + 8) * 64]);
    glds16(srcWh + kt,        &Whi[(wave * 16) * 64]);
    glds16(srcWh + kt + 4096, &Whi[(wave * 16 + 8) * 64]);
    glds16(srcWl + kt,        &Wlo[(wave * 16) * 64]);
    glds16(srcWl + kt + 4096, &Wlo[(wave * 16 + 8) * 64]);
    asm volatile("s_waitcnt vmcnt(0)" ::: "memory");
    __syncthreads();

#pragma unroll
    for (int c = 0; c < 2; ++c) {
      const int koff = c * 32 + g * 8;
      s16x8 ah[2], bh[2], bl[2];
#pragma unroll
      for (int mi = 0; mi < 2; ++mi) {
        const int r = wm + mi * 16 + j;
        const int el = r * 64 + (koff ^ ((r & 7) << 3));
        ah[mi] = *reinterpret_cast<const s16x8*>(&Xh[el]);
      }
#pragma unroll
      for (int ni = 0; ni < 2; ++ni) {
        const int r = wn + ni * 16 + j;
        const int el = r * 64 + (koff ^ ((r & 7) << 3));
        bh[ni] = *reinterpret_cast<const s16x8*>(&Whi[el]);
        bl[ni] = *reinterpret_cast<const s16x8*>(&Wlo[el]);
      }
#pragma unroll
      for (int mi = 0; mi < 2; ++mi)
#pragma unroll
        for (int ni = 0; ni < 2; ++ni) {
          acc[mi][ni] = __builtin_amdgcn_mfma_f32_16x16x32_bf16(ah[mi], bh[ni], acc[mi][ni], 0, 0, 0);
          acc[mi][ni] = __builtin_amdgcn_mfma_f32_16x16x32_bf16(ah[mi], bl[ni], acc[mi][ni], 0, 0, 0);
        }
    }
  }

#pragma unroll
  for (int ni = 0; ni < 2; ++ni) {
    const int colc = col0 + wn + ni * 16 + j;
    const float bj = bias[colc];
#pragma unroll
    for (int mi = 0; mi < 2; ++mi)
#pragma unroll
      for (int r = 0; r < 4; ++r) {
        const int rowc = row0 + wm + mi * 16 + (g << 2) + r;
        out[(size_t)rowc * FEAT + colc] = acc[mi][ni][r] + bj;
      }
  }
}

// ---------------------------------------------------------------------------
// Flash attention (r17 body; epilogue stores AO hi only): 3-buffer
// counted-vmcnt LDS pipeline, KVBLK=64, pure-bf16 4-MFMA QK^T, PV hi-only
// with permuted-V, native exp2, deferred-l, conditional pm swap.
// ---------------------------------------------------------------------------
__global__ __launch_bounds__(256, 3) void attn_pipe(
    const unsigned short* __restrict__ Qhi,
    const unsigned short* __restrict__ Khi,
    const unsigned short* __restrict__ Vthi,
    unsigned short* __restrict__ AOhi)
{
  __shared__ unsigned short Kh_s[3][4096];
  __shared__ unsigned short Vh_s[3][4096];
  __shared__ float bcast[4][32];

  const int tid = threadIdx.x, lane = tid & 63, wave = tid >> 6;
  const int hfl = lane >> 5;
  const int l31 = lane & 31;

  const int bid = blockIdx.x;
  const int swz = (bid & 7) * 64 + (bid >> 3);
  const int qt  = swz & 15;
  const int bh  = swz >> 4;
  const int b = bh >> 3, h = bh & 7;

  const int q0 = qt * 128 + wave * 32;
  const size_t kvbase = (size_t)bh * SEQ * HD;

  s16x8 qh[4];
  {
    const size_t qoff = kvbase + (size_t)(q0 + l31) * HD + hfl * 8;
#pragma unroll
    for (int c = 0; c < 4; ++c)
      qh[c] = *reinterpret_cast<const s16x8*>(&Qhi[qoff + c * 16]);
  }

  f32x16 oacc0 = (f32x16)0.f, oacc1 = (f32x16)0.f;
  float m = -INFINITY, lsum = 0.f;

  const int ck  = tid >> 3;
  const int ksl = (tid & 7) ^ (ck & 7);
  const unsigned short* sKh = Khi + kvbase + (size_t)ck * HD + ksl * 8;
  const int vr  = tid >> 3;
  const int vsl = (tid & 7) ^ (vr & 7);
  const int vhd = vr + (vsl >> 2) * 32;
  const int vk0 = (vsl & 3) * 8;
  const unsigned short* sVh = Vthi + kvbase + (size_t)vhd * SEQ + vk0;
  const int wq = wave * 512;

  const int krow = l31 * 64;
  const int ksw  = l31 & 7;

  auto stage = [&](int tt, int bi) {
    const size_t ko = (size_t)tt * 64 * HD;
    const int    vo = tt * 64;
    glds16(sKh + ko,           &Kh_s[bi][wq]);
    glds16(sKh + ko + 32 * HD, &Kh_s[bi][2048 + wq]);
    glds16(sVh + vo,           &Vh_s[bi][wq]);
    glds16(sVh + vo + 32,      &Vh_s[bi][2048 + wq]);
  };

  stage(0, 0);
  stage(1, 1);

  const int NT = SEQ / 64;   // 32
  int cur = 0;
  for (int t = 0; t < NT; ++t) {
    if (t < NT - 1) {
      asm volatile("s_waitcnt vmcnt(4)" ::: "memory");
    } else {
      asm volatile("s_waitcnt vmcnt(0)" ::: "memory");
    }
    __syncthreads();
    if (t + 2 < NT) {
      int nb = cur + 2; if (nb >= 3) nb -= 3;
      stage(t + 2, nb);
    }
    __builtin_amdgcn_sched_barrier(0);

#pragma unroll
    for (int sub = 0; sub < 2; ++sub) {
      const int sb = sub * 2048;

      s16x8 KH[4];
#pragma unroll
      for (int c = 0; c < 4; ++c) {
        const int idx = sb + krow + ((((c << 1) | hfl)) ^ ksw) * 8;
        KH[c] = *reinterpret_cast<const s16x8*>(&Kh_s[cur][idx]);
      }

      f32x16 st = (f32x16)0.f;
      __builtin_amdgcn_s_setprio(1);
#pragma unroll
      for (int c = 0; c < 4; ++c)
        st = __builtin_amdgcn_mfma_f32_32x32x16_bf16(KH[c], qh[c], st, 0, 0, 0);
      __builtin_amdgcn_s_setprio(0);

      s16x8 V0h[2], V1h[2];
#pragma unroll
      for (int c = 0; c < 2; ++c) {
        const int i0 = sb + krow + ((((c << 1) | hfl)) ^ ksw) * 8;
        const int i1 = sb + krow + (((4 | (c << 1) | hfl)) ^ ksw) * 8;
        V0h[c] = *reinterpret_cast<const s16x8*>(&Vh_s[cur][i0]);
        V1h[c] = *reinterpret_cast<const s16x8*>(&Vh_s[cur][i1]);
      }

      const float a0 = fmaxf(fmaxf(st[0], st[1]), st[2]);
      const float a1 = fmaxf(fmaxf(st[3], st[4]), st[5]);
      const float a2 = fmaxf(fmaxf(st[6], st[7]), st[8]);
      const float a3 = fmaxf(fmaxf(st[9], st[10]), st[11]);
      const float a4 = fmaxf(fmaxf(st[12], st[13]), st[14]);
      const float pm = fmaxf(fmaxf(fmaxf(a0, a1), a2),
                             fmaxf(fmaxf(a3, a4), st[15]));

      if (__any(pm > m + 8.f)) {
        const float pmf  = fmaxf(pm, __shfl_xor(pm, 32));
        const float mnew = fmaxf(m, pmf);
        const float corr = EX2(m - mnew);
        m = mnew; lsum *= corr;
        if (lane < 32) bcast[wave][l31] = corr;
        f32x4 c4[4];
#pragma unroll
        for (int rq = 0; rq < 4; ++rq)
          c4[rq] = *reinterpret_cast<const f32x4*>(&bcast[wave][rq * 8 + hfl * 4]);
#pragma unroll
        for (int r = 0; r < 16; ++r) {
          const float cc = c4[r >> 2][r & 3];
          oacc0[r] *= cc; oacc1[r] *= cc;
        }
      }

#pragma unroll
      for (int r = 0; r < 16; ++r) st[r] = EX2(st[r] - m);
      {
        float s0 = (st[0] + st[1]) + (st[2] + st[3]);
        float s1 = (st[4] + st[5]) + (st[6] + st[7]);
        float s2 = (st[8] + st[9]) + (st[10] + st[11]);
        float s3 = (st[12] + st[13]) + (st[14] + st[15]);
        lsum += (s0 + s1) + (s2 + s3);
      }

      unsigned int wh[8];
#pragma unroll
      for (int p = 0; p < 8; ++p)
        asm("v_cvt_pk_bf16_f32 %0, %1, %2" : "=v"(wh[p]) : "v"(st[2 * p]), "v"(st[2 * p + 1]));
      const s16x8 pa0h = __builtin_bit_cast(s16x8, (u32x4){wh[0], wh[1], wh[2], wh[3]});
      const s16x8 pa1h = __builtin_bit_cast(s16x8, (u32x4){wh[4], wh[5], wh[6], wh[7]});

      __builtin_amdgcn_s_setprio(1);
      oacc0 = __builtin_amdgcn_mfma_f32_32x32x16_bf16(pa0h, V0h[0], oacc0, 0, 0, 0);
      oacc0 = __builtin_amdgcn_mfma_f32_32x32x16_bf16(pa1h, V0h[1], oacc0, 0, 0, 0);
      oacc1 = __builtin_amdgcn_mfma_f32_32x32x16_bf16(pa0h, V1h[0], oacc1, 0, 0, 0);
      oacc1 = __builtin_amdgcn_mfma_f32_32x32x16_bf16(pa1h, V1h[1], oacc1, 0, 0, 0);
      __builtin_amdgcn_s_setprio(0);
    }

    cur += 1; if (cur >= 3) cur -= 3;
  }

  const float lf = lsum + __shfl_xor(lsum, 32);
  if (lane < 32) bcast[wave][l31] = 1.f / lf;
  __syncthreads();
  f32x4 i4[4];
#pragma unroll
  for (int rq = 0; rq < 4; ++rq)
    i4[rq] = *reinterpret_cast<const f32x4*>(&bcast[wave][rq * 8 + hfl * 4]);

#pragma unroll
  for (int r = 0; r < 16; ++r) {
    const int q = q0 + (r & 3) + 8 * (r >> 2) + 4 * hfl;
    const float inv = i4[r >> 2][r & 3];
    const size_t idx = ((size_t)b * SEQ + q) * FEAT + h * HD + l31;
    AOhi[idx]      = f2bf(oacc0[r] * inv);
    AOhi[idx + 32] = f2bf(oacc1[r] * inv);
  }
}

extern "C" void kernel_launch(void* const* d_in, const int* in_sizes, int n_in,
                              void* d_out, int out_size, void* d_ws, size_t ws_size,
                              hipStream_t stream) {
  const float* x_cur  = (const float*)d_in[0];
  const float* x_past = (const float*)d_in[1];
  const float* wq = (const float*)d_in[2];
  const float* bq = (const float*)d_in[3];
  const float* wk = (const float*)d_in[4];
  const float* bk = (const float*)d_in[5];
  const float* wv = (const float*)d_in[6];
  const float* bv = (const float*)d_in[7];
  const float* wo = (const float*)d_in[8];
  const float* bo = (const float*)d_in[9];
  float* out = (float*)d_out;

  const size_t n = (size_t)NROWS * FEAT;   // 4,194,304
  unsigned short* Qhi  = (unsigned short*)d_ws;
  unsigned short* Xchi = Qhi + n;
  unsigned short* Khi  = Qhi + 2 * n;
  unsigned short* Xphi = Qhi + 3 * n;
  unsigned short* Vthi = Qhi + 4 * n;
  unsigned short* Wsp  = Qhi + 5 * n;
  unsigned short* AOhi = Qhi + 6 * n;

  dim3 block(256);
  presplit<<<dim3(4608), block, 0, stream>>>(wq, wk, wv, wo, x_cur, x_past,
                                             Wsp, Xchi, Xphi);

  qkv_proj<<<dim3(NROWS / 128, FEAT / 64, 3), block, 0, stream>>>(
      Xchi, Xphi, Wsp, bq, bk, bv, Qhi, Khi, Vthi);

  attn_pipe<<<dim3(512), block, 0, stream>>>(Qhi, Khi, Vthi, AOhi);

  dim3 gout(NROWS / 64, FEAT / 64);
  out_proj<<<gout, block, 0, stream>>>(AOhi, Wsp + 3 * 524288,
                                       Wsp + 3 * 524288 + 262144, bo, out);
}